// Round 5
// baseline (1373.430 us; speedup 1.0000x reference)
//
#include <hip/hip_runtime.h>
#include <math.h>

// ---------------------------------------------------------------------------
// LowToHighMultiLevelReconstruction — round 5.
// Change vs round 4: attention kernel LDS diet (106KB -> 51.5KB) for
// 2 blocks/CU: sim computed in two d-halves (Q/K staged per half, acc in
// regs — bitwise-identical), PV in two j-halves (attn retained packed-bf16
// in regs between phases). Conflict repad (133/261/129). launch_bounds(512,4).
// GEMMs (bf16-split MFMA) unchanged from round 4.
// ---------------------------------------------------------------------------

#define GS   128
#define WIN  256        // 2*GS
#define DQK  64
#define DV   64
#define DIMC 512
#define NTOK 8192

typedef unsigned long long u64;
typedef unsigned short u16;
typedef __attribute__((ext_vector_type(8))) short bf16x8;
typedef __attribute__((ext_vector_type(4))) float f32x4;

__device__ __forceinline__ u16 f2b(float f) {     // f32 -> bf16 RNE
  unsigned u = __float_as_uint(f);
  u = (u + 0x7fffu + ((u >> 16) & 1u)) >> 16;
  return (u16)u;
}
__device__ __forceinline__ float b2f(u16 h) { return __uint_as_float(((unsigned)h) << 16); }
__device__ __forceinline__ float b2f_lo(unsigned u) { return __uint_as_float(u << 16); }
__device__ __forceinline__ float b2f_hi(unsigned u) { return __uint_as_float(u & 0xffff0000u); }

__device__ __forceinline__ float wave_max64(float v) {
#pragma unroll
  for (int m = 1; m < 64; m <<= 1) v = fmaxf(v, __shfl_xor(v, m, 64));
  return v;
}
__device__ __forceinline__ float wave_sum64(float v) {
#pragma unroll
  for (int m = 1; m < 64; m <<= 1) v += __shfl_xor(v, m, 64);
  return v;
}

// ---------------------------------------------------------------- pooling ---
__global__ void pool_feat_kernel(const float* __restrict__ x,
                                 const float* __restrict__ scores,
                                 float* __restrict__ xl, float* __restrict__ sl,
                                 int n, int scale) {
  int npool = n / scale;
  int total = 2 * npool * (DIMC / 4);
  int tid = blockIdx.x * blockDim.x + threadIdx.x;
  if (tid >= total) return;
  int c4 = tid & 127;
  int g  = (tid >> 7) % npool;
  int b  = (tid >> 7) / npool;
  const float* xp = x + ((size_t)b * n + (size_t)g * scale) * DIMC + c4 * 4;
  float ax = 0.f, ay = 0.f, az = 0.f, aw = 0.f, wsum = 0.f, ssum = 0.f;
  for (int s = 0; s < scale; ++s) {
    float sc = scores[(size_t)b * n + (size_t)g * scale + s];
    float w  = fmaxf(sc, 1e-6f);
    float4 xv = *reinterpret_cast<const float4*>(xp + (size_t)s * DIMC);
    ax += xv.x * w; ay += xv.y * w; az += xv.z * w; aw += xv.w * w;
    wsum += w; ssum += sc;
  }
  float4 o = { ax / wsum, ay / wsum, az / wsum, aw / wsum };
  *reinterpret_cast<float4*>(xl + ((size_t)b * npool + g) * DIMC + c4 * 4) = o;
  if (c4 == 0) sl[(size_t)b * npool + g] = ssum / (float)scale;
}

__global__ void pool_label_kernel(const int* __restrict__ labels,
                                  const float* __restrict__ scores,
                                  int* __restrict__ ll, int n, int scale) {
  int npool = n / scale;
  int tid = blockIdx.x * blockDim.x + threadIdx.x;
  if (tid >= 2 * npool) return;
  int b = tid / npool, g = tid % npool;
  float counts[4] = {0.f, 0.f, 0.f, 0.f};
  float ssum[4]   = {0.f, 0.f, 0.f, 0.f};
  int firstp[4];
  for (int c = 0; c < 4; ++c) firstp[c] = scale;
  for (int s = 0; s < scale; ++s) {
    int   L = labels[(size_t)b * n + (size_t)g * scale + s];
    float S = scores[(size_t)b * n + (size_t)g * scale + s];
    counts[L] += 1.0f;
    ssum[L]   += S;
    if (s < firstp[L]) firstp[L] = s;
  }
  float cmax = fmaxf(fmaxf(counts[0], counts[1]), fmaxf(counts[2], counts[3]));
  float s2[4];
  for (int c = 0; c < 4; ++c) s2[c] = (counts[c] == cmax) ? ssum[c] : -1e9f;
  float smax = fmaxf(fmaxf(s2[0], s2[1]), fmaxf(s2[2], s2[3]));
  int fp[4];
  for (int c = 0; c < 4; ++c) fp[c] = (s2[c] == smax) ? firstp[c] : scale;
  int best = 0, bv = fp[0];
  for (int c = 1; c < 4; ++c) if (fp[c] < bv) { bv = fp[c]; best = c; }
  ll[(size_t)b * npool + g] = best;
}

// ------------------------------------------------------------ keep (focus) --
__global__ void keep_kernel(const int* __restrict__ ll, const float* __restrict__ sl,
                            int* __restrict__ keep, int total) {
  int tid = blockIdx.x * blockDim.x + threadIdx.x;
  if (tid >= total) return;
  const int*   lp = ll + (size_t)tid * GS;
  const float* sp = sl + (size_t)tid * GS;
  float counts[4] = {0.f, 0.f, 0.f, 0.f};
  for (int i = 0; i < GS; ++i) counts[lp[i]] += 1.f;
  int mode = 0; float bv = counts[0];
  for (int c = 1; c < 4; ++c) if (counts[c] > bv) { bv = counts[c]; mode = c; }
  float pm = 0.f, mean = 0.f;
  for (int i = 0; i < GS; ++i) { pm += (lp[i] == mode) ? 1.f : 0.f; mean += sp[i]; }
  float purity = pm / (float)GS;
  mean /= (float)GS;
  float var = 0.f;
  for (int i = 0; i < GS; ++i) { float d = sp[i] - mean; var += d * d; }
  var /= (float)GS;
  float focus = 0.5f + 0.25f * purity - 0.25f * var;
  focus = fminf(fmaxf(focus, 0.25f), 0.75f);
  keep[tid] = (int)ceilf(focus * (float)WIN);
}

// ------------------------------------------- weight transpose + bf16 split --
// W f32 [512][512] (k,n) -> Bt hi/lo bf16 [512][512] (n,k). lo may be null.
__global__ __launch_bounds__(256) void wsplitT_kernel(const float* __restrict__ W,
                                                      u16* __restrict__ bthi,
                                                      u16* __restrict__ btlo) {
  __shared__ float tile[32][33];
  int bx = blockIdx.x & 15;        // n block
  int by = blockIdx.x >> 4;        // k block
  int tx = threadIdx.x & 31;
  int ty = threadIdx.x >> 5;       // 0..7
#pragma unroll
  for (int i = 0; i < 4; ++i) {
    int kk = ty + i * 8;
    tile[kk][tx] = W[(size_t)(by * 32 + kk) * 512 + bx * 32 + tx];
  }
  __syncthreads();
#pragma unroll
  for (int i = 0; i < 4; ++i) {
    int nn = ty + i * 8;
    float v = tile[tx][nn];        // = W[by*32+tx][bx*32+nn]
    u16 h = f2b(v);
    size_t o = (size_t)(bx * 32 + nn) * 512 + by * 32 + tx;
    bthi[o] = h;
    if (btlo) btlo[o] = f2b(v - b2f(h));
  }
}

// ------------------------------------------------------- MFMA split GEMM ----
// C(MxN=512) = A(Mx512 f32) @ W(512x512), K=N=512.
// SPLIT=1: 3-product split (q,k). SPLIT=0: hi-only (v, wp).
// EMODE 0: f32 store C. 1: bf16 store Cb. 2: scatter via idx. 3: scatter +=.
template<int SPLIT, int EMODE>
__global__ __launch_bounds__(256) void mgemm_kernel(
    const float* __restrict__ Af,
    const u16* __restrict__ Bthi, const u16* __restrict__ Btlo,
    float* __restrict__ C, u16* __restrict__ Cb, const int* __restrict__ idx,
    int M, int scale, int n_l) {
  __shared__ u16 smem[SPLIT ? 4 * 5120 : 2 * 5120];   // [128][40] tiles
  u16* sAhi = smem;
  u16* sBhi = smem + 5120;
  u16* sAlo = SPLIT ? smem + 2 * 5120 : smem;
  u16* sBlo = SPLIT ? smem + 3 * 5120 : smem;

  int t = threadIdx.x, lane = t & 63, wave = t >> 6;
  int wr = wave >> 1, wc = wave & 1;
  int row0 = blockIdx.y * 128, col0 = blockIdx.x * 128;

  const f32x4 zero = { 0.f, 0.f, 0.f, 0.f };
  f32x4 acc[4][4];
#pragma unroll
  for (int i = 0; i < 4; ++i)
#pragma unroll
    for (int j = 0; j < 4; ++j) acc[i][j] = zero;

  for (int k0 = 0; k0 < 512; k0 += 32) {
#pragma unroll
    for (int it = 0; it < 4; ++it) {
      int c = it * 256 + t;
      int r = c >> 3, s = c & 7;
      float4 v = *reinterpret_cast<const float4*>(Af + (size_t)(row0 + r) * 512 + k0 + s * 4);
      ushort4 h, l;
      h.x = f2b(v.x); h.y = f2b(v.y); h.z = f2b(v.z); h.w = f2b(v.w);
      *reinterpret_cast<ushort4*>(&sAhi[r * 40 + s * 4]) = h;
      if (SPLIT) {
        l.x = f2b(v.x - b2f(h.x)); l.y = f2b(v.y - b2f(h.y));
        l.z = f2b(v.z - b2f(h.z)); l.w = f2b(v.w - b2f(h.w));
        *reinterpret_cast<ushort4*>(&sAlo[r * 40 + s * 4]) = l;
      }
    }
#pragma unroll
    for (int it = 0; it < 2; ++it) {
      int c = it * 256 + t;
      int r = c >> 2, s = c & 3;
      uint4 vb = *reinterpret_cast<const uint4*>(Bthi + (size_t)(col0 + r) * 512 + k0 + s * 8);
      *reinterpret_cast<uint4*>(&sBhi[r * 40 + s * 8]) = vb;
      if (SPLIT) {
        uint4 vl = *reinterpret_cast<const uint4*>(Btlo + (size_t)(col0 + r) * 512 + k0 + s * 8);
        *reinterpret_cast<uint4*>(&sBlo[r * 40 + s * 8]) = vl;
      }
    }
    __syncthreads();

    int fr = lane & 15;
    int kf = (lane >> 4) * 8;
    bf16x8 ah[4], bh[4], al[4], bl[4];
#pragma unroll
    for (int i = 0; i < 4; ++i) {
      ah[i] = *reinterpret_cast<const bf16x8*>(&sAhi[(wr * 64 + i * 16 + fr) * 40 + kf]);
      bh[i] = *reinterpret_cast<const bf16x8*>(&sBhi[(wc * 64 + i * 16 + fr) * 40 + kf]);
      if (SPLIT) {
        al[i] = *reinterpret_cast<const bf16x8*>(&sAlo[(wr * 64 + i * 16 + fr) * 40 + kf]);
        bl[i] = *reinterpret_cast<const bf16x8*>(&sBlo[(wc * 64 + i * 16 + fr) * 40 + kf]);
      }
    }
#pragma unroll
    for (int i = 0; i < 4; ++i)
#pragma unroll
      for (int j = 0; j < 4; ++j) {
        acc[i][j] = __builtin_amdgcn_mfma_f32_16x16x32_bf16(ah[i], bh[j], acc[i][j], 0, 0, 0);
        if (SPLIT) {
          acc[i][j] = __builtin_amdgcn_mfma_f32_16x16x32_bf16(ah[i], bl[j], acc[i][j], 0, 0, 0);
          acc[i][j] = __builtin_amdgcn_mfma_f32_16x16x32_bf16(al[i], bh[j], acc[i][j], 0, 0, 0);
        }
      }
    __syncthreads();
  }

  int ccol = col0 + wc * 64 + (lane & 15);
  int crow = row0 + wr * 64 + (lane >> 4) * 4;
#pragma unroll
  for (int i = 0; i < 4; ++i) {
#pragma unroll
    for (int r = 0; r < 4; ++r) {
      int gr = crow + i * 16 + r;
      if (EMODE == 0) {
#pragma unroll
        for (int j = 0; j < 4; ++j)
          C[(size_t)gr * 512 + ccol + j * 16] = acc[i][j][r];
      } else if (EMODE == 1) {
#pragma unroll
        for (int j = 0; j < 4; ++j)
          Cb[(size_t)gr * 512 + ccol + j * 16] = f2b(acc[i][j][r]);
      } else {
        int bb = gr / n_l, rr = gr - bb * n_l;
        for (int s = 0; s < scale; ++s) {
          int dst = idx[(size_t)bb * NTOK + (size_t)rr * scale + s];
          float* p = C + ((size_t)bb * NTOK + dst) * 512 + ccol;
          if (EMODE == 3) {
#pragma unroll
            for (int j = 0; j < 4; ++j) p[j * 16] += acc[i][j][r];
          } else {
#pragma unroll
            for (int j = 0; j < 4; ++j) p[j * 16] = acc[i][j][r];
          }
        }
      }
    }
  }
}

// ----------------------------------------------- fused windowed attention ---
// One block (512 thr, 8 waves) per (b,g,h). LDS <= 51.5KB -> 2 blocks/CU.
//   Phase A (x2 d-halves): stage qT[32][133], kT[32][261] f32; sim acc in regs.
//   Rank/softmax/prior: pure reg+ballot, attn retained packed bf16 (atp).
//   Phase B (x2 j-halves): aT[128][129] + vsh[128][72] bf16; PV acc in regs.
__global__ __launch_bounds__(512, 4) void attn_fused_kernel(
    const float* __restrict__ q, const float* __restrict__ k,
    const u16* __restrict__ vbf, const int* __restrict__ keepArr,
    const u16* __restrict__ prevA, u16* __restrict__ curA,
    const float* __restrict__ betaL, float* __restrict__ outp,
    int lvl, int n_l, int ng, int prev_ng) {
  __shared__ u64 smem8[6432];             // 51456 B
  float* qT  = (float*)smem8;             // [32][133]
  float* kT  = qT + 32 * 133;             // [32][261]
  u16*   aT  = (u16*)smem8;               // [128][129]  (j-half, transposed attn)
  u16*   vsh = aT + 128 * 129;            // [128][72]   (j-half V)

  int t = threadIdx.x;
  int lane = t & 63, wave = t >> 6;
  int bid = blockIdx.x;
  int h = bid & 7;
  int g = (bid >> 3) % ng;
  int b = (bid >> 3) / ng;

  const float* qbase = q + ((size_t)b * n_l + (size_t)g * GS) * DIMC + h * DQK;
  const float* kbase = k + (size_t)b * n_l * DIMC + h * DQK;

  // ---- sim over two d-halves; acc identical to full-d accumulation ----
  float acc[16][4] = {};
#pragma unroll
  for (int dp = 0; dp < 2; ++dp) {
    int d0 = dp * 32;
    // stage qT: 128 qi x 8 d4 chunks
#pragma unroll
    for (int it = 0; it < 2; ++it) {
      int idx = it * 512 + t;
      int qi = idx >> 3, d4 = idx & 7;
      float4 vv = *reinterpret_cast<const float4*>(qbase + (size_t)qi * DIMC + d0 + d4 * 4);
      qT[(d4 * 4 + 0) * 133 + qi] = vv.x;
      qT[(d4 * 4 + 1) * 133 + qi] = vv.y;
      qT[(d4 * 4 + 2) * 133 + qi] = vv.z;
      qT[(d4 * 4 + 3) * 133 + qi] = vv.w;
    }
    // stage kT: 256 j x 8 d4 chunks (tail-reflected window)
#pragma unroll
    for (int it = 0; it < 4; ++it) {
      int idx = it * 512 + t;
      int j = idx >> 3, d4 = idx & 7;
      int p = g * GS + j;
      int src = (p < n_l) ? p : (2 * n_l - 1 - p);
      float4 vv = *reinterpret_cast<const float4*>(kbase + (size_t)src * DIMC + d0 + d4 * 4);
      kT[(d4 * 4 + 0) * 261 + j] = vv.x;
      kT[(d4 * 4 + 1) * 261 + j] = vv.y;
      kT[(d4 * 4 + 2) * 261 + j] = vv.z;
      kT[(d4 * 4 + 3) * 261 + j] = vv.w;
    }
    __syncthreads();
#pragma unroll 2
    for (int d = 0; d < 32; ++d) {
      float ra[16], rb4[4];
      *reinterpret_cast<float4*>(&ra[0])  = *reinterpret_cast<const float4*>(&qT[d * 133 + wave * 16 + 0]);
      *reinterpret_cast<float4*>(&ra[4])  = *reinterpret_cast<const float4*>(&qT[d * 133 + wave * 16 + 4]);
      *reinterpret_cast<float4*>(&ra[8])  = *reinterpret_cast<const float4*>(&qT[d * 133 + wave * 16 + 8]);
      *reinterpret_cast<float4*>(&ra[12]) = *reinterpret_cast<const float4*>(&qT[d * 133 + wave * 16 + 12]);
      *reinterpret_cast<float4*>(&rb4[0]) = *reinterpret_cast<const float4*>(&kT[d * 261 + lane * 4]);
#pragma unroll
      for (int i = 0; i < 16; ++i)
#pragma unroll
        for (int j = 0; j < 4; ++j) acc[i][j] += ra[i] * rb4[j];
    }
    __syncthreads();   // all waves done reading before next-pass / phase-B writes
  }

  int kp = keepArr[b * ng + g];
  float beta = 0.f, wgt = 0.f;
  int lo = 0, hi = 0;
  if (lvl > 0) {
    beta = 1.f / (1.f + expf(-betaL[lvl]));
    float pos = ((float)g + 0.5f) * ((float)prev_ng / (float)ng) - 0.5f;
    float fl = floorf(pos);
    lo = (int)fl;
    if (lo < 0) lo = 0;
    if (lo > prev_ng - 1) lo = prev_ng - 1;
    hi = lo + 1; if (hi > prev_ng - 1) hi = prev_ng - 1;
    wgt = fminf(fmaxf(pos - fl, 0.f), 1.f);
  }
  u64 lmask = (1ull << lane) - 1ull;

  // ---- per-row: ballot top-k -> softmax -> prior mix; retain packed bf16 ---
  unsigned atp[16][2];
#pragma unroll
  for (int r = 0; r < 16; ++r) {
    int i = wave * 16 + r;
    float sv[4];
    unsigned um[4];
#pragma unroll
    for (int e = 0; e < 4; ++e) {
      sv[e] = acc[r][e] * 0.125f;
      unsigned u = __float_as_uint(sv[e]);
      um[e] = (u & 0x80000000u) ? ~u : (u | 0x80000000u);
    }
    unsigned T = 0u;
    for (int bit = 31; bit >= 0; --bit) {
      unsigned T2 = T | (1u << bit);
      int c = __popcll(__ballot(um[0] >= T2)) + __popcll(__ballot(um[1] >= T2))
            + __popcll(__ballot(um[2] >= T2)) + __popcll(__ballot(um[3] >= T2));
      if (c >= kp) T = T2;
    }
    int c_gt = __popcll(__ballot(um[0] > T)) + __popcll(__ballot(um[1] > T))
             + __popcll(__ballot(um[2] > T)) + __popcll(__ballot(um[3] > T));
    u64 beq[4];
#pragma unroll
    for (int e = 0; e < 4; ++e) beq[e] = __ballot(um[e] == T);
    int trbase = __popcll(beq[0] & lmask) + __popcll(beq[1] & lmask)
               + __popcll(beq[2] & lmask) + __popcll(beq[3] & lmask);
    int need = kp - c_gt;
    bool msk[4];
    int own = 0;
#pragma unroll
    for (int e = 0; e < 4; ++e) {
      bool eq = (um[e] == T);
      msk[e] = (um[e] > T) || (eq && (trbase + own) < need);
      own += eq ? 1 : 0;
    }
    float m = -3.0e38f;
#pragma unroll
    for (int e = 0; e < 4; ++e) if (msk[e]) m = fmaxf(m, sv[e]);
    m = wave_max64(m);
    float ez[4], zs = 0.f;
#pragma unroll
    for (int e = 0; e < 4; ++e) { ez[e] = msk[e] ? __expf(sv[e] - m) : 0.f; zs += ez[e]; }
    zs = wave_sum64(zs);
    float at[4];
#pragma unroll
    for (int e = 0; e < 4; ++e) at[e] = ez[e] / zs;
    if (lvl > 0) {
      size_t baseLo = ((((size_t)b * prev_ng + lo) * 8 + h) * GS + i) * WIN + lane * 4;
      size_t baseHi = ((((size_t)b * prev_ng + hi) * 8 + h) * GS + i) * WIN + lane * 4;
      uint2 rlo = *reinterpret_cast<const uint2*>(prevA + baseLo);
      uint2 rhi = *reinterpret_cast<const uint2*>(prevA + baseHi);
      float pl[4] = { b2f_lo(rlo.x), b2f_hi(rlo.x), b2f_lo(rlo.y), b2f_hi(rlo.y) };
      float ph[4] = { b2f_lo(rhi.x), b2f_hi(rhi.x), b2f_lo(rhi.y), b2f_hi(rhi.y) };
      float pr[4], ps = 0.f;
#pragma unroll
      for (int e = 0; e < 4; ++e) {
        pr[e] = fmaxf((1.f - wgt) * pl[e] + wgt * ph[e], 0.f);
        ps += pr[e];
      }
      ps = wave_sum64(ps) + 1e-9f;
#pragma unroll
      for (int e = 0; e < 4; ++e) at[e] = (1.f - beta) * at[e] + beta * (pr[e] / ps);
    }
    atp[r][0] = (unsigned)f2b(at[0]) | ((unsigned)f2b(at[1]) << 16);
    atp[r][1] = (unsigned)f2b(at[2]) | ((unsigned)f2b(at[3]) << 16);
    if (curA != nullptr) {
      uint2 o = { atp[r][0], atp[r][1] };
      *reinterpret_cast<uint2*>(curA + ((size_t)bid * GS + i) * WIN + lane * 4) = o;
    }
  }

  // ---- PV in two j-halves: out(128x64) += attn(128x128) @ V(128x64) ----
  const u16* vbase = vbf + (size_t)b * n_l * DIMC + h * DV;
  int txp = t & 15, typ = t >> 4;
  float o2[4][4] = {};
#pragma unroll
  for (int jp = 0; jp < 2; ++jp) {
    // stage vsh half: 128 j x 16 d-chunks
#pragma unroll
    for (int it = 0; it < 4; ++it) {
      int idx = it * 512 + t;
      int jj = idx >> 4, d4 = idx & 15;
      int p = g * GS + jp * 128 + jj;
      int src = (p < n_l) ? p : (2 * n_l - 1 - p);
      ushort4 vv = *reinterpret_cast<const ushort4*>(vbase + (size_t)src * DIMC + d4 * 4);
      *reinterpret_cast<ushort4*>(&vsh[jj * 72 + d4 * 4]) = vv;
    }
    // write aT half from retained regs: lanes owning cols in this half
    if ((lane >> 5) == jp) {
      int jl = (lane & 31) * 4;          // local col base within half
#pragma unroll
      for (int r = 0; r < 16; ++r) {
        int i = wave * 16 + r;
        aT[(jl + 0) * 129 + i] = (u16)(atp[r][0] & 0xffffu);
        aT[(jl + 1) * 129 + i] = (u16)(atp[r][0] >> 16);
        aT[(jl + 2) * 129 + i] = (u16)(atp[r][1] & 0xffffu);
        aT[(jl + 3) * 129 + i] = (u16)(atp[r][1] >> 16);
      }
    }
    __syncthreads();
#pragma unroll 4
    for (int j = 0; j < 128; ++j) {
      uint2 a2 = *reinterpret_cast<const uint2*>(&aT[j * 129 + typ * 4]);
      uint2 v2 = *reinterpret_cast<const uint2*>(&vsh[j * 72 + txp * 4]);
      float pa[4]  = { b2f_lo(a2.x), b2f_hi(a2.x), b2f_lo(a2.y), b2f_hi(a2.y) };
      float pv4[4] = { b2f_lo(v2.x), b2f_hi(v2.x), b2f_lo(v2.y), b2f_hi(v2.y) };
#pragma unroll
      for (int ii = 0; ii < 4; ++ii)
#pragma unroll
        for (int jj = 0; jj < 4; ++jj) o2[ii][jj] += pa[ii] * pv4[jj];
    }
    __syncthreads();
  }
  float* obase = outp + ((size_t)b * n_l + (size_t)g * GS) * DIMC + h * DV;
#pragma unroll
  for (int ii = 0; ii < 4; ++ii) {
    float4 o = { o2[ii][0], o2[ii][1], o2[ii][2], o2[ii][3] };
    *reinterpret_cast<float4*>(&obase[(size_t)(typ * 4 + ii) * DIMC + txp * 4]) = o;
  }
}

// ---------------------------------------------------------------------------
extern "C" void kernel_launch(void* const* d_in, const int* in_sizes, int n_in,
                              void* d_out, int out_size, void* d_ws, size_t ws_size,
                              hipStream_t stream) {
  (void)in_sizes; (void)n_in; (void)out_size; (void)ws_size;
  const float* x        = (const float*)d_in[0];
  const int*   labels   = (const int*)d_in[1];
  const float* scores   = (const float*)d_in[2];
  const int*   idx_last = (const int*)d_in[3];
  const float* Wq       = (const float*)d_in[4];
  const float* Wk       = (const float*)d_in[5];
  const float* Wv       = (const float*)d_in[6];
  const float* Wp       = (const float*)d_in[7];
  const float* betaL    = (const float*)d_in[8];
  float* out = (float*)d_out;

  char* w = (char*)d_ws;
  size_t off = 0;
  auto take = [&](size_t bytes) -> char* {
    char* p = w + off;
    off += (bytes + 255) & ~(size_t)255;
    return p;
  };
  float* qb    = (float*)take(33554432);   // q f32 (max 2*8192*512)
  float* kb    = (float*)take(33554432);   // k f32
  u16*   vbf   = (u16*)  take(16777216);   // v bf16
  float* xo    = (float*)take(33554432);   // xl (pooled x) / outp union
  u16*   attnA = (u16*)  take(16777216);   // lvl0 attn bf16
  u16*   attnB = (u16*)  take(33554432);   // lvl1 attn bf16
  u16*   wqhi  = (u16*)  take(524288);     // transposed+split weights
  u16*   wqlo  = (u16*)  take(524288);
  u16*   wkhi  = (u16*)  take(524288);
  u16*   wklo  = (u16*)  take(524288);
  u16*   wvhi  = (u16*)  take(524288);
  u16*   wphi  = (u16*)  take(524288);
  float* sl    = (float*)take(32768);
  int*   ll    = (int*)  take(32768);
  int*   keepb = (int*)  take(1024);

  const size_t wstride = (size_t)DIMC * DIMC;
  for (int lvl = 0; lvl < 3; ++lvl) {
    int scale = (lvl == 0) ? 4 : (lvl == 1) ? 2 : 1;
    int n_l = NTOK / scale;
    int ng  = n_l / GS;
    int M   = 2 * n_l;
    const float* xin; const int* lin; const float* sin_;
    if (scale > 1) {
      int tfeat = 2 * n_l * (DIMC / 4);
      pool_feat_kernel<<<(tfeat + 255) / 256, 256, 0, stream>>>(x, scores, xo, sl, NTOK, scale);
      pool_label_kernel<<<(2 * n_l + 255) / 256, 256, 0, stream>>>(labels, scores, ll, NTOK, scale);
      xin = xo; lin = ll; sin_ = sl;
    } else {
      xin = x; lin = labels; sin_ = scores;
    }
    keep_kernel<<<(2 * ng + 127) / 128, 128, 0, stream>>>(lin, sin_, keepb, 2 * ng);

    wsplitT_kernel<<<256, 256, 0, stream>>>(Wq + lvl * wstride, wqhi, wqlo);
    wsplitT_kernel<<<256, 256, 0, stream>>>(Wk + lvl * wstride, wkhi, wklo);
    wsplitT_kernel<<<256, 256, 0, stream>>>(Wv + lvl * wstride, wvhi, nullptr);
    wsplitT_kernel<<<256, 256, 0, stream>>>(Wp + lvl * wstride, wphi, nullptr);

    dim3 gg(4, M / 128);
    mgemm_kernel<1, 0><<<gg, 256, 0, stream>>>(xin, wqhi, wqlo, qb, nullptr, nullptr, M, 0, 0);
    mgemm_kernel<1, 0><<<gg, 256, 0, stream>>>(xin, wkhi, wklo, kb, nullptr, nullptr, M, 0, 0);
    mgemm_kernel<0, 1><<<gg, 256, 0, stream>>>(xin, wvhi, nullptr, nullptr, vbf, nullptr, M, 0, 0);

    const u16* prev = (lvl == 0) ? nullptr : ((lvl == 1) ? attnA : attnB);
    u16* cur = (lvl == 0) ? attnA : ((lvl == 1) ? attnB : nullptr);
    attn_fused_kernel<<<2 * ng * 8, 512, 0, stream>>>(qb, kb, vbf, keepb, prev, cur,
                                                      betaL, xo, lvl, n_l, ng, ng / 2);

    if (lvl == 0)
      mgemm_kernel<0, 2><<<gg, 256, 0, stream>>>(xo, wphi, nullptr, out, nullptr, idx_last, M, scale, n_l);
    else
      mgemm_kernel<0, 3><<<gg, 256, 0, stream>>>(xo, wphi, nullptr, out, nullptr, idx_last, M, scale, n_l);
  }
}

// Round 6
// 909.564 us; speedup vs baseline: 1.5100x; 1.5100x over previous
//
#include <hip/hip_runtime.h>
#include <math.h>

// ---------------------------------------------------------------------------
// LowToHighMultiLevelReconstruction — round 6.
// Change vs round 5: attention re-split to 2 blocks per (b,g,h) x 64 q-rows
// -> per-wave state acc[8][4]+atp[8][2] (~80 VGPR, NO launch-bounds cap, no
// spill), LDS 42KB -> 3 blocks/CU. Round-5 regression was acc spilled to
// scratch under the (512,4) 128-VGPR cap (VGPR_Count=60 < 64-reg acc).
// Strides: qT 68 / kT 260 (16B-aligned b128 reads) / aT 66 / vsh 72.
// GEMMs (bf16-split MFMA) unchanged.
// ---------------------------------------------------------------------------

#define GS   128
#define WIN  256        // 2*GS
#define DQK  64
#define DV   64
#define DIMC 512
#define NTOK 8192

typedef unsigned long long u64;
typedef unsigned short u16;
typedef __attribute__((ext_vector_type(8))) short bf16x8;
typedef __attribute__((ext_vector_type(4))) float f32x4;

__device__ __forceinline__ u16 f2b(float f) {     // f32 -> bf16 RNE
  unsigned u = __float_as_uint(f);
  u = (u + 0x7fffu + ((u >> 16) & 1u)) >> 16;
  return (u16)u;
}
__device__ __forceinline__ float b2f(u16 h) { return __uint_as_float(((unsigned)h) << 16); }
__device__ __forceinline__ float b2f_lo(unsigned u) { return __uint_as_float(u << 16); }
__device__ __forceinline__ float b2f_hi(unsigned u) { return __uint_as_float(u & 0xffff0000u); }

__device__ __forceinline__ float wave_max64(float v) {
#pragma unroll
  for (int m = 1; m < 64; m <<= 1) v = fmaxf(v, __shfl_xor(v, m, 64));
  return v;
}
__device__ __forceinline__ float wave_sum64(float v) {
#pragma unroll
  for (int m = 1; m < 64; m <<= 1) v += __shfl_xor(v, m, 64);
  return v;
}

// ---------------------------------------------------------------- pooling ---
__global__ void pool_feat_kernel(const float* __restrict__ x,
                                 const float* __restrict__ scores,
                                 float* __restrict__ xl, float* __restrict__ sl,
                                 int n, int scale) {
  int npool = n / scale;
  int total = 2 * npool * (DIMC / 4);
  int tid = blockIdx.x * blockDim.x + threadIdx.x;
  if (tid >= total) return;
  int c4 = tid & 127;
  int g  = (tid >> 7) % npool;
  int b  = (tid >> 7) / npool;
  const float* xp = x + ((size_t)b * n + (size_t)g * scale) * DIMC + c4 * 4;
  float ax = 0.f, ay = 0.f, az = 0.f, aw = 0.f, wsum = 0.f, ssum = 0.f;
  for (int s = 0; s < scale; ++s) {
    float sc = scores[(size_t)b * n + (size_t)g * scale + s];
    float w  = fmaxf(sc, 1e-6f);
    float4 xv = *reinterpret_cast<const float4*>(xp + (size_t)s * DIMC);
    ax += xv.x * w; ay += xv.y * w; az += xv.z * w; aw += xv.w * w;
    wsum += w; ssum += sc;
  }
  float4 o = { ax / wsum, ay / wsum, az / wsum, aw / wsum };
  *reinterpret_cast<float4*>(xl + ((size_t)b * npool + g) * DIMC + c4 * 4) = o;
  if (c4 == 0) sl[(size_t)b * npool + g] = ssum / (float)scale;
}

__global__ void pool_label_kernel(const int* __restrict__ labels,
                                  const float* __restrict__ scores,
                                  int* __restrict__ ll, int n, int scale) {
  int npool = n / scale;
  int tid = blockIdx.x * blockDim.x + threadIdx.x;
  if (tid >= 2 * npool) return;
  int b = tid / npool, g = tid % npool;
  float counts[4] = {0.f, 0.f, 0.f, 0.f};
  float ssum[4]   = {0.f, 0.f, 0.f, 0.f};
  int firstp[4];
  for (int c = 0; c < 4; ++c) firstp[c] = scale;
  for (int s = 0; s < scale; ++s) {
    int   L = labels[(size_t)b * n + (size_t)g * scale + s];
    float S = scores[(size_t)b * n + (size_t)g * scale + s];
    counts[L] += 1.0f;
    ssum[L]   += S;
    if (s < firstp[L]) firstp[L] = s;
  }
  float cmax = fmaxf(fmaxf(counts[0], counts[1]), fmaxf(counts[2], counts[3]));
  float s2[4];
  for (int c = 0; c < 4; ++c) s2[c] = (counts[c] == cmax) ? ssum[c] : -1e9f;
  float smax = fmaxf(fmaxf(s2[0], s2[1]), fmaxf(s2[2], s2[3]));
  int fp[4];
  for (int c = 0; c < 4; ++c) fp[c] = (s2[c] == smax) ? firstp[c] : scale;
  int best = 0, bv = fp[0];
  for (int c = 1; c < 4; ++c) if (fp[c] < bv) { bv = fp[c]; best = c; }
  ll[(size_t)b * npool + g] = best;
}

// ------------------------------------------------------------ keep (focus) --
__global__ void keep_kernel(const int* __restrict__ ll, const float* __restrict__ sl,
                            int* __restrict__ keep, int total) {
  int tid = blockIdx.x * blockDim.x + threadIdx.x;
  if (tid >= total) return;
  const int*   lp = ll + (size_t)tid * GS;
  const float* sp = sl + (size_t)tid * GS;
  float counts[4] = {0.f, 0.f, 0.f, 0.f};
  for (int i = 0; i < GS; ++i) counts[lp[i]] += 1.f;
  int mode = 0; float bv = counts[0];
  for (int c = 1; c < 4; ++c) if (counts[c] > bv) { bv = counts[c]; mode = c; }
  float pm = 0.f, mean = 0.f;
  for (int i = 0; i < GS; ++i) { pm += (lp[i] == mode) ? 1.f : 0.f; mean += sp[i]; }
  float purity = pm / (float)GS;
  mean /= (float)GS;
  float var = 0.f;
  for (int i = 0; i < GS; ++i) { float d = sp[i] - mean; var += d * d; }
  var /= (float)GS;
  float focus = 0.5f + 0.25f * purity - 0.25f * var;
  focus = fminf(fmaxf(focus, 0.25f), 0.75f);
  keep[tid] = (int)ceilf(focus * (float)WIN);
}

// ------------------------------------------- weight transpose + bf16 split --
__global__ __launch_bounds__(256) void wsplitT_kernel(const float* __restrict__ W,
                                                      u16* __restrict__ bthi,
                                                      u16* __restrict__ btlo) {
  __shared__ float tile[32][33];
  int bx = blockIdx.x & 15;        // n block
  int by = blockIdx.x >> 4;        // k block
  int tx = threadIdx.x & 31;
  int ty = threadIdx.x >> 5;       // 0..7
#pragma unroll
  for (int i = 0; i < 4; ++i) {
    int kk = ty + i * 8;
    tile[kk][tx] = W[(size_t)(by * 32 + kk) * 512 + bx * 32 + tx];
  }
  __syncthreads();
#pragma unroll
  for (int i = 0; i < 4; ++i) {
    int nn = ty + i * 8;
    float v = tile[tx][nn];        // = W[by*32+tx][bx*32+nn]
    u16 h = f2b(v);
    size_t o = (size_t)(bx * 32 + nn) * 512 + by * 32 + tx;
    bthi[o] = h;
    if (btlo) btlo[o] = f2b(v - b2f(h));
  }
}

// ------------------------------------------------------- MFMA split GEMM ----
// C(MxN=512) = A(Mx512 f32) @ W(512x512), K=N=512.
// SPLIT=1: 3-product split (q,k). SPLIT=0: hi-only (v, wp).
// EMODE 0: f32 store C. 1: bf16 store Cb. 2: scatter via idx. 3: scatter +=.
template<int SPLIT, int EMODE>
__global__ __launch_bounds__(256) void mgemm_kernel(
    const float* __restrict__ Af,
    const u16* __restrict__ Bthi, const u16* __restrict__ Btlo,
    float* __restrict__ C, u16* __restrict__ Cb, const int* __restrict__ idx,
    int M, int scale, int n_l) {
  __shared__ u16 smem[SPLIT ? 4 * 5120 : 2 * 5120];   // [128][40] tiles
  u16* sAhi = smem;
  u16* sBhi = smem + 5120;
  u16* sAlo = SPLIT ? smem + 2 * 5120 : smem;
  u16* sBlo = SPLIT ? smem + 3 * 5120 : smem;

  int t = threadIdx.x, lane = t & 63, wave = t >> 6;
  int wr = wave >> 1, wc = wave & 1;
  int row0 = blockIdx.y * 128, col0 = blockIdx.x * 128;

  const f32x4 zero = { 0.f, 0.f, 0.f, 0.f };
  f32x4 acc[4][4];
#pragma unroll
  for (int i = 0; i < 4; ++i)
#pragma unroll
    for (int j = 0; j < 4; ++j) acc[i][j] = zero;

  for (int k0 = 0; k0 < 512; k0 += 32) {
#pragma unroll
    for (int it = 0; it < 4; ++it) {
      int c = it * 256 + t;
      int r = c >> 3, s = c & 7;
      float4 v = *reinterpret_cast<const float4*>(Af + (size_t)(row0 + r) * 512 + k0 + s * 4);
      ushort4 h, l;
      h.x = f2b(v.x); h.y = f2b(v.y); h.z = f2b(v.z); h.w = f2b(v.w);
      *reinterpret_cast<ushort4*>(&sAhi[r * 40 + s * 4]) = h;
      if (SPLIT) {
        l.x = f2b(v.x - b2f(h.x)); l.y = f2b(v.y - b2f(h.y));
        l.z = f2b(v.z - b2f(h.z)); l.w = f2b(v.w - b2f(h.w));
        *reinterpret_cast<ushort4*>(&sAlo[r * 40 + s * 4]) = l;
      }
    }
#pragma unroll
    for (int it = 0; it < 2; ++it) {
      int c = it * 256 + t;
      int r = c >> 2, s = c & 3;
      uint4 vb = *reinterpret_cast<const uint4*>(Bthi + (size_t)(col0 + r) * 512 + k0 + s * 8);
      *reinterpret_cast<uint4*>(&sBhi[r * 40 + s * 8]) = vb;
      if (SPLIT) {
        uint4 vl = *reinterpret_cast<const uint4*>(Btlo + (size_t)(col0 + r) * 512 + k0 + s * 8);
        *reinterpret_cast<uint4*>(&sBlo[r * 40 + s * 8]) = vl;
      }
    }
    __syncthreads();

    int fr = lane & 15;
    int kf = (lane >> 4) * 8;
    bf16x8 ah[4], bh[4], al[4], bl[4];
#pragma unroll
    for (int i = 0; i < 4; ++i) {
      ah[i] = *reinterpret_cast<const bf16x8*>(&sAhi[(wr * 64 + i * 16 + fr) * 40 + kf]);
      bh[i] = *reinterpret_cast<const bf16x8*>(&sBhi[(wc * 64 + i * 16 + fr) * 40 + kf]);
      if (SPLIT) {
        al[i] = *reinterpret_cast<const bf16x8*>(&sAlo[(wr * 64 + i * 16 + fr) * 40 + kf]);
        bl[i] = *reinterpret_cast<const bf16x8*>(&sBlo[(wc * 64 + i * 16 + fr) * 40 + kf]);
      }
    }
#pragma unroll
    for (int i = 0; i < 4; ++i)
#pragma unroll
      for (int j = 0; j < 4; ++j) {
        acc[i][j] = __builtin_amdgcn_mfma_f32_16x16x32_bf16(ah[i], bh[j], acc[i][j], 0, 0, 0);
        if (SPLIT) {
          acc[i][j] = __builtin_amdgcn_mfma_f32_16x16x32_bf16(ah[i], bl[j], acc[i][j], 0, 0, 0);
          acc[i][j] = __builtin_amdgcn_mfma_f32_16x16x32_bf16(al[i], bh[j], acc[i][j], 0, 0, 0);
        }
      }
    __syncthreads();
  }

  int ccol = col0 + wc * 64 + (lane & 15);
  int crow = row0 + wr * 64 + (lane >> 4) * 4;
#pragma unroll
  for (int i = 0; i < 4; ++i) {
#pragma unroll
    for (int r = 0; r < 4; ++r) {
      int gr = crow + i * 16 + r;
      if (EMODE == 0) {
#pragma unroll
        for (int j = 0; j < 4; ++j)
          C[(size_t)gr * 512 + ccol + j * 16] = acc[i][j][r];
      } else if (EMODE == 1) {
#pragma unroll
        for (int j = 0; j < 4; ++j)
          Cb[(size_t)gr * 512 + ccol + j * 16] = f2b(acc[i][j][r]);
      } else {
        int bb = gr / n_l, rr = gr - bb * n_l;
        for (int s = 0; s < scale; ++s) {
          int dst = idx[(size_t)bb * NTOK + (size_t)rr * scale + s];
          float* p = C + ((size_t)bb * NTOK + dst) * 512 + ccol;
          if (EMODE == 3) {
#pragma unroll
            for (int j = 0; j < 4; ++j) p[j * 16] += acc[i][j][r];
          } else {
#pragma unroll
            for (int j = 0; j < 4; ++j) p[j * 16] = acc[i][j][r];
          }
        }
      }
    }
  }
}

// ----------------------------------------------- fused windowed attention ---
// TWO blocks (512 thr, 8 waves) per (b,g,h), each owns 64 q-rows (p=bid&1).
// Per wave: 8 rows -> acc[8][4] (32 regs) + atp[8][2] (16 regs), no cap.
// LDS 41984 B -> 3 blocks/CU. Phase A: sim in 2 d-halves (qT/kT f32).
// Ballot top-k -> softmax -> prior mix (bit-identical numerics).
// Phase B: PV in 2 j-halves (aT/vsh bf16), attn retained packed in regs.
__global__ __launch_bounds__(512) void attn_fused_kernel(
    const float* __restrict__ q, const float* __restrict__ k,
    const u16* __restrict__ vbf, const int* __restrict__ keepArr,
    const u16* __restrict__ prevA, u16* __restrict__ curA,
    const float* __restrict__ betaL, float* __restrict__ outp,
    int lvl, int n_l, int ng, int prev_ng) {
  __shared__ u64 smem8[5248];             // 41984 B
  float* qT  = (float*)smem8;             // [32][68]   (d, qi<64)
  float* kT  = qT + 32 * 68;              // [32][260]  (d, j<256)
  u16*   aT  = (u16*)smem8;               // [128][66]  (j-half col, i<64)
  u16*   vsh = aT + 128 * 66;             // [128][72]  (j-half col, d<64)

  int t = threadIdx.x;
  int lane = t & 63, wave = t >> 6;
  int bid = blockIdx.x;
  int p   = bid & 1;
  int h   = (bid >> 1) & 7;
  int gl  = bid >> 4;
  int g   = gl % ng;
  int b   = gl / ng;
  int bgh = bid >> 1;                     // (b,g,h) index for attn state

  const float* qbase = q + ((size_t)b * n_l + (size_t)g * GS + p * 64) * DIMC + h * DQK;
  const float* kbase = k + (size_t)b * n_l * DIMC + h * DQK;

  // ---- sim over two d-halves; acc identical to full-d accumulation ----
  float acc[8][4] = {};
#pragma unroll
  for (int dp = 0; dp < 2; ++dp) {
    int d0 = dp * 32;
    {  // qT: 64 qi x 8 d4 chunks = 512
      int qi = t >> 3, d4 = t & 7;
      float4 vv = *reinterpret_cast<const float4*>(qbase + (size_t)qi * DIMC + d0 + d4 * 4);
      qT[(d4 * 4 + 0) * 68 + qi] = vv.x;
      qT[(d4 * 4 + 1) * 68 + qi] = vv.y;
      qT[(d4 * 4 + 2) * 68 + qi] = vv.z;
      qT[(d4 * 4 + 3) * 68 + qi] = vv.w;
    }
#pragma unroll
    for (int it = 0; it < 4; ++it) {      // kT: 256 j x 8 d4 chunks
      int idx = it * 512 + t;
      int j = idx >> 3, d4 = idx & 7;
      int pp = g * GS + j;
      int src = (pp < n_l) ? pp : (2 * n_l - 1 - pp);
      float4 vv = *reinterpret_cast<const float4*>(kbase + (size_t)src * DIMC + d0 + d4 * 4);
      kT[(d4 * 4 + 0) * 260 + j] = vv.x;
      kT[(d4 * 4 + 1) * 260 + j] = vv.y;
      kT[(d4 * 4 + 2) * 260 + j] = vv.z;
      kT[(d4 * 4 + 3) * 260 + j] = vv.w;
    }
    __syncthreads();
#pragma unroll 2
    for (int d = 0; d < 32; ++d) {
      float ra[8], rb4[4];
      *reinterpret_cast<float4*>(&ra[0]) = *reinterpret_cast<const float4*>(&qT[d * 68 + wave * 8 + 0]);
      *reinterpret_cast<float4*>(&ra[4]) = *reinterpret_cast<const float4*>(&qT[d * 68 + wave * 8 + 4]);
      *reinterpret_cast<float4*>(&rb4[0]) = *reinterpret_cast<const float4*>(&kT[d * 260 + lane * 4]);
#pragma unroll
      for (int i = 0; i < 8; ++i)
#pragma unroll
        for (int j = 0; j < 4; ++j) acc[i][j] += ra[i] * rb4[j];
    }
    __syncthreads();
  }

  int kp = keepArr[b * ng + g];
  float beta = 0.f, wgt = 0.f;
  int lo = 0, hi = 0;
  if (lvl > 0) {
    beta = 1.f / (1.f + expf(-betaL[lvl]));
    float pos = ((float)g + 0.5f) * ((float)prev_ng / (float)ng) - 0.5f;
    float fl = floorf(pos);
    lo = (int)fl;
    if (lo < 0) lo = 0;
    if (lo > prev_ng - 1) lo = prev_ng - 1;
    hi = lo + 1; if (hi > prev_ng - 1) hi = prev_ng - 1;
    wgt = fminf(fmaxf(pos - fl, 0.f), 1.f);
  }
  u64 lmask = (1ull << lane) - 1ull;

  // ---- per-row: ballot top-k -> softmax -> prior mix; retain packed bf16 ---
  unsigned atp[8][2];
#pragma unroll
  for (int r = 0; r < 8; ++r) {
    int i = p * 64 + wave * 8 + r;        // row within the 128-row group
    float sv[4];
    unsigned um[4];
#pragma unroll
    for (int e = 0; e < 4; ++e) {
      sv[e] = acc[r][e] * 0.125f;
      unsigned u = __float_as_uint(sv[e]);
      um[e] = (u & 0x80000000u) ? ~u : (u | 0x80000000u);
    }
    unsigned T = 0u;
    for (int bit = 31; bit >= 0; --bit) {
      unsigned T2 = T | (1u << bit);
      int c = __popcll(__ballot(um[0] >= T2)) + __popcll(__ballot(um[1] >= T2))
            + __popcll(__ballot(um[2] >= T2)) + __popcll(__ballot(um[3] >= T2));
      if (c >= kp) T = T2;
    }
    int c_gt = __popcll(__ballot(um[0] > T)) + __popcll(__ballot(um[1] > T))
             + __popcll(__ballot(um[2] > T)) + __popcll(__ballot(um[3] > T));
    u64 beq[4];
#pragma unroll
    for (int e = 0; e < 4; ++e) beq[e] = __ballot(um[e] == T);
    int trbase = __popcll(beq[0] & lmask) + __popcll(beq[1] & lmask)
               + __popcll(beq[2] & lmask) + __popcll(beq[3] & lmask);
    int need = kp - c_gt;
    bool msk[4];
    int own = 0;
#pragma unroll
    for (int e = 0; e < 4; ++e) {
      bool eq = (um[e] == T);
      msk[e] = (um[e] > T) || (eq && (trbase + own) < need);
      own += eq ? 1 : 0;
    }
    float m = -3.0e38f;
#pragma unroll
    for (int e = 0; e < 4; ++e) if (msk[e]) m = fmaxf(m, sv[e]);
    m = wave_max64(m);
    float ez[4], zs = 0.f;
#pragma unroll
    for (int e = 0; e < 4; ++e) { ez[e] = msk[e] ? __expf(sv[e] - m) : 0.f; zs += ez[e]; }
    zs = wave_sum64(zs);
    float at[4];
#pragma unroll
    for (int e = 0; e < 4; ++e) at[e] = ez[e] / zs;
    if (lvl > 0) {
      size_t baseLo = ((((size_t)b * prev_ng + lo) * 8 + h) * GS + i) * WIN + lane * 4;
      size_t baseHi = ((((size_t)b * prev_ng + hi) * 8 + h) * GS + i) * WIN + lane * 4;
      uint2 rlo = *reinterpret_cast<const uint2*>(prevA + baseLo);
      uint2 rhi = *reinterpret_cast<const uint2*>(prevA + baseHi);
      float pl[4] = { b2f_lo(rlo.x), b2f_hi(rlo.x), b2f_lo(rlo.y), b2f_hi(rlo.y) };
      float ph[4] = { b2f_lo(rhi.x), b2f_hi(rhi.x), b2f_lo(rhi.y), b2f_hi(rhi.y) };
      float pr[4], ps = 0.f;
#pragma unroll
      for (int e = 0; e < 4; ++e) {
        pr[e] = fmaxf((1.f - wgt) * pl[e] + wgt * ph[e], 0.f);
        ps += pr[e];
      }
      ps = wave_sum64(ps) + 1e-9f;
#pragma unroll
      for (int e = 0; e < 4; ++e) at[e] = (1.f - beta) * at[e] + beta * (pr[e] / ps);
    }
    atp[r][0] = (unsigned)f2b(at[0]) | ((unsigned)f2b(at[1]) << 16);
    atp[r][1] = (unsigned)f2b(at[2]) | ((unsigned)f2b(at[3]) << 16);
    if (curA != nullptr) {
      uint2 o = { atp[r][0], atp[r][1] };
      *reinterpret_cast<uint2*>(curA + ((size_t)bgh * GS + i) * WIN + lane * 4) = o;
    }
  }

  // ---- PV in two j-halves: out(64x64) += attn(64x128) @ V(128x64) ----
  const u16* vbase = vbf + (size_t)b * n_l * DIMC + h * DV;
  int txp = t & 15, typ = t >> 4;        // typ 0..31: rows typ*2, typ*2+1
  float o2[2][4] = {};
#pragma unroll
  for (int jp = 0; jp < 2; ++jp) {
    // stage vsh half: 128 j x 16 d-chunks
#pragma unroll
    for (int it = 0; it < 4; ++it) {
      int idx = it * 512 + t;
      int jj = idx >> 4, d4 = idx & 15;
      int pp = g * GS + jp * 128 + jj;
      int src = (pp < n_l) ? pp : (2 * n_l - 1 - pp);
      ushort4 vv = *reinterpret_cast<const ushort4*>(vbase + (size_t)src * DIMC + d4 * 4);
      *reinterpret_cast<ushort4*>(&vsh[jj * 72 + d4 * 4]) = vv;
    }
    // write aT half from retained regs: lanes owning cols in this half
    if ((lane >> 5) == jp) {
      int jl = (lane & 31) * 4;          // local col base within half
#pragma unroll
      for (int r = 0; r < 8; ++r) {
        int il = wave * 8 + r;           // local row 0..63
        aT[(jl + 0) * 66 + il] = (u16)(atp[r][0] & 0xffffu);
        aT[(jl + 1) * 66 + il] = (u16)(atp[r][0] >> 16);
        aT[(jl + 2) * 66 + il] = (u16)(atp[r][1] & 0xffffu);
        aT[(jl + 3) * 66 + il] = (u16)(atp[r][1] >> 16);
      }
    }
    __syncthreads();
#pragma unroll 4
    for (int j = 0; j < 128; ++j) {
      unsigned a2 = *reinterpret_cast<const unsigned*>(&aT[j * 66 + typ * 2]);
      uint2 v2 = *reinterpret_cast<const uint2*>(&vsh[j * 72 + txp * 4]);
      float pa0 = b2f_lo(a2), pa1 = b2f_hi(a2);
      float pv4[4] = { b2f_lo(v2.x), b2f_hi(v2.x), b2f_lo(v2.y), b2f_hi(v2.y) };
#pragma unroll
      for (int jj = 0; jj < 4; ++jj) {
        o2[0][jj] += pa0 * pv4[jj];
        o2[1][jj] += pa1 * pv4[jj];
      }
    }
    __syncthreads();
  }
  float* obase = outp + ((size_t)b * n_l + (size_t)g * GS + p * 64) * DIMC + h * DV;
#pragma unroll
  for (int ii = 0; ii < 2; ++ii) {
    float4 o = { o2[ii][0], o2[ii][1], o2[ii][2], o2[ii][3] };
    *reinterpret_cast<float4*>(&obase[(size_t)(typ * 2 + ii) * DIMC + txp * 4]) = o;
  }
}

// ---------------------------------------------------------------------------
extern "C" void kernel_launch(void* const* d_in, const int* in_sizes, int n_in,
                              void* d_out, int out_size, void* d_ws, size_t ws_size,
                              hipStream_t stream) {
  (void)in_sizes; (void)n_in; (void)out_size; (void)ws_size;
  const float* x        = (const float*)d_in[0];
  const int*   labels   = (const int*)d_in[1];
  const float* scores   = (const float*)d_in[2];
  const int*   idx_last = (const int*)d_in[3];
  const float* Wq       = (const float*)d_in[4];
  const float* Wk       = (const float*)d_in[5];
  const float* Wv       = (const float*)d_in[6];
  const float* Wp       = (const float*)d_in[7];
  const float* betaL    = (const float*)d_in[8];
  float* out = (float*)d_out;

  char* w = (char*)d_ws;
  size_t off = 0;
  auto take = [&](size_t bytes) -> char* {
    char* p = w + off;
    off += (bytes + 255) & ~(size_t)255;
    return p;
  };
  float* qb    = (float*)take(33554432);   // q f32 (max 2*8192*512)
  float* kb    = (float*)take(33554432);   // k f32
  u16*   vbf   = (u16*)  take(16777216);   // v bf16
  float* xo    = (float*)take(33554432);   // xl (pooled x) / outp union
  u16*   attnA = (u16*)  take(16777216);   // lvl0 attn bf16
  u16*   attnB = (u16*)  take(33554432);   // lvl1 attn bf16
  u16*   wqhi  = (u16*)  take(524288);     // transposed+split weights
  u16*   wqlo  = (u16*)  take(524288);
  u16*   wkhi  = (u16*)  take(524288);
  u16*   wklo  = (u16*)  take(524288);
  u16*   wvhi  = (u16*)  take(524288);
  u16*   wphi  = (u16*)  take(524288);
  float* sl    = (float*)take(32768);
  int*   ll    = (int*)  take(32768);
  int*   keepb = (int*)  take(1024);

  const size_t wstride = (size_t)DIMC * DIMC;
  for (int lvl = 0; lvl < 3; ++lvl) {
    int scale = (lvl == 0) ? 4 : (lvl == 1) ? 2 : 1;
    int n_l = NTOK / scale;
    int ng  = n_l / GS;
    int M   = 2 * n_l;
    const float* xin; const int* lin; const float* sin_;
    if (scale > 1) {
      int tfeat = 2 * n_l * (DIMC / 4);
      pool_feat_kernel<<<(tfeat + 255) / 256, 256, 0, stream>>>(x, scores, xo, sl, NTOK, scale);
      pool_label_kernel<<<(2 * n_l + 255) / 256, 256, 0, stream>>>(labels, scores, ll, NTOK, scale);
      xin = xo; lin = ll; sin_ = sl;
    } else {
      xin = x; lin = labels; sin_ = scores;
    }
    keep_kernel<<<(2 * ng + 127) / 128, 128, 0, stream>>>(lin, sin_, keepb, 2 * ng);

    wsplitT_kernel<<<256, 256, 0, stream>>>(Wq + lvl * wstride, wqhi, wqlo);
    wsplitT_kernel<<<256, 256, 0, stream>>>(Wk + lvl * wstride, wkhi, wklo);
    wsplitT_kernel<<<256, 256, 0, stream>>>(Wv + lvl * wstride, wvhi, nullptr);
    wsplitT_kernel<<<256, 256, 0, stream>>>(Wp + lvl * wstride, wphi, nullptr);

    dim3 gg(4, M / 128);
    mgemm_kernel<1, 0><<<gg, 256, 0, stream>>>(xin, wqhi, wqlo, qb, nullptr, nullptr, M, 0, 0);
    mgemm_kernel<1, 0><<<gg, 256, 0, stream>>>(xin, wkhi, wklo, kb, nullptr, nullptr, M, 0, 0);
    mgemm_kernel<0, 1><<<gg, 256, 0, stream>>>(xin, wvhi, nullptr, nullptr, vbf, nullptr, M, 0, 0);

    const u16* prev = (lvl == 0) ? nullptr : ((lvl == 1) ? attnA : attnB);
    u16* cur = (lvl == 0) ? attnA : ((lvl == 1) ? attnB : nullptr);
    attn_fused_kernel<<<2 * ng * 8 * 2, 512, 0, stream>>>(qb, kb, vbf, keepb, prev, cur,
                                                          betaL, xo, lvl, n_l, ng, ng / 2);

    if (lvl == 0)
      mgemm_kernel<0, 2><<<gg, 256, 0, stream>>>(xo, wphi, nullptr, out, nullptr, idx_last, M, scale, n_l);
    else
      mgemm_kernel<0, 3><<<gg, 256, 0, stream>>>(xo, wphi, nullptr, out, nullptr, idx_last, M, scale, n_l);
  }
}

// Round 7
// 763.295 us; speedup vs baseline: 1.7993x; 1.1916x over previous
//
#include <hip/hip_runtime.h>
#include <math.h>

// ---------------------------------------------------------------------------
// LowToHighMultiLevelReconstruction — round 7.
// Change vs round 6: attention PV moved to MFMA (16x16x32 bf16). P (post-
// softmax attn, bf16 in regs) -> P_lds[64][264]; V staged transposed
// Vt[64][136] per k-half; 2 C-frags/wave x 8 k-steps. Removes ~3600 VALU
// instr/thread (bf16 unpack + scalar FMA). sim/top-k/softmax/prior and all
// GEMMs unchanged. LDS 42 -> 51.2 KB (still 3 blocks/CU).
// ---------------------------------------------------------------------------

#define GS   128
#define WIN  256        // 2*GS
#define DQK  64
#define DV   64
#define DIMC 512
#define NTOK 8192

typedef unsigned long long u64;
typedef unsigned short u16;
typedef __attribute__((ext_vector_type(8))) short bf16x8;
typedef __attribute__((ext_vector_type(4))) float f32x4;

__device__ __forceinline__ u16 f2b(float f) {     // f32 -> bf16 RNE
  unsigned u = __float_as_uint(f);
  u = (u + 0x7fffu + ((u >> 16) & 1u)) >> 16;
  return (u16)u;
}
__device__ __forceinline__ float b2f(u16 h) { return __uint_as_float(((unsigned)h) << 16); }
__device__ __forceinline__ float b2f_lo(unsigned u) { return __uint_as_float(u << 16); }
__device__ __forceinline__ float b2f_hi(unsigned u) { return __uint_as_float(u & 0xffff0000u); }

__device__ __forceinline__ float wave_max64(float v) {
#pragma unroll
  for (int m = 1; m < 64; m <<= 1) v = fmaxf(v, __shfl_xor(v, m, 64));
  return v;
}
__device__ __forceinline__ float wave_sum64(float v) {
#pragma unroll
  for (int m = 1; m < 64; m <<= 1) v += __shfl_xor(v, m, 64);
  return v;
}

// ---------------------------------------------------------------- pooling ---
__global__ void pool_feat_kernel(const float* __restrict__ x,
                                 const float* __restrict__ scores,
                                 float* __restrict__ xl, float* __restrict__ sl,
                                 int n, int scale) {
  int npool = n / scale;
  int total = 2 * npool * (DIMC / 4);
  int tid = blockIdx.x * blockDim.x + threadIdx.x;
  if (tid >= total) return;
  int c4 = tid & 127;
  int g  = (tid >> 7) % npool;
  int b  = (tid >> 7) / npool;
  const float* xp = x + ((size_t)b * n + (size_t)g * scale) * DIMC + c4 * 4;
  float ax = 0.f, ay = 0.f, az = 0.f, aw = 0.f, wsum = 0.f, ssum = 0.f;
  for (int s = 0; s < scale; ++s) {
    float sc = scores[(size_t)b * n + (size_t)g * scale + s];
    float w  = fmaxf(sc, 1e-6f);
    float4 xv = *reinterpret_cast<const float4*>(xp + (size_t)s * DIMC);
    ax += xv.x * w; ay += xv.y * w; az += xv.z * w; aw += xv.w * w;
    wsum += w; ssum += sc;
  }
  float4 o = { ax / wsum, ay / wsum, az / wsum, aw / wsum };
  *reinterpret_cast<float4*>(xl + ((size_t)b * npool + g) * DIMC + c4 * 4) = o;
  if (c4 == 0) sl[(size_t)b * npool + g] = ssum / (float)scale;
}

__global__ void pool_label_kernel(const int* __restrict__ labels,
                                  const float* __restrict__ scores,
                                  int* __restrict__ ll, int n, int scale) {
  int npool = n / scale;
  int tid = blockIdx.x * blockDim.x + threadIdx.x;
  if (tid >= 2 * npool) return;
  int b = tid / npool, g = tid % npool;
  float counts[4] = {0.f, 0.f, 0.f, 0.f};
  float ssum[4]   = {0.f, 0.f, 0.f, 0.f};
  int firstp[4];
  for (int c = 0; c < 4; ++c) firstp[c] = scale;
  for (int s = 0; s < scale; ++s) {
    int   L = labels[(size_t)b * n + (size_t)g * scale + s];
    float S = scores[(size_t)b * n + (size_t)g * scale + s];
    counts[L] += 1.0f;
    ssum[L]   += S;
    if (s < firstp[L]) firstp[L] = s;
  }
  float cmax = fmaxf(fmaxf(counts[0], counts[1]), fmaxf(counts[2], counts[3]));
  float s2[4];
  for (int c = 0; c < 4; ++c) s2[c] = (counts[c] == cmax) ? ssum[c] : -1e9f;
  float smax = fmaxf(fmaxf(s2[0], s2[1]), fmaxf(s2[2], s2[3]));
  int fp[4];
  for (int c = 0; c < 4; ++c) fp[c] = (s2[c] == smax) ? firstp[c] : scale;
  int best = 0, bv = fp[0];
  for (int c = 1; c < 4; ++c) if (fp[c] < bv) { bv = fp[c]; best = c; }
  ll[(size_t)b * npool + g] = best;
}

// ------------------------------------------------------------ keep (focus) --
__global__ void keep_kernel(const int* __restrict__ ll, const float* __restrict__ sl,
                            int* __restrict__ keep, int total) {
  int tid = blockIdx.x * blockDim.x + threadIdx.x;
  if (tid >= total) return;
  const int*   lp = ll + (size_t)tid * GS;
  const float* sp = sl + (size_t)tid * GS;
  float counts[4] = {0.f, 0.f, 0.f, 0.f};
  for (int i = 0; i < GS; ++i) counts[lp[i]] += 1.f;
  int mode = 0; float bv = counts[0];
  for (int c = 1; c < 4; ++c) if (counts[c] > bv) { bv = counts[c]; mode = c; }
  float pm = 0.f, mean = 0.f;
  for (int i = 0; i < GS; ++i) { pm += (lp[i] == mode) ? 1.f : 0.f; mean += sp[i]; }
  float purity = pm / (float)GS;
  mean /= (float)GS;
  float var = 0.f;
  for (int i = 0; i < GS; ++i) { float d = sp[i] - mean; var += d * d; }
  var /= (float)GS;
  float focus = 0.5f + 0.25f * purity - 0.25f * var;
  focus = fminf(fmaxf(focus, 0.25f), 0.75f);
  keep[tid] = (int)ceilf(focus * (float)WIN);
}

// ------------------------------------------- weight transpose + bf16 split --
__global__ __launch_bounds__(256) void wsplitT_kernel(const float* __restrict__ W,
                                                      u16* __restrict__ bthi,
                                                      u16* __restrict__ btlo) {
  __shared__ float tile[32][33];
  int bx = blockIdx.x & 15;        // n block
  int by = blockIdx.x >> 4;        // k block
  int tx = threadIdx.x & 31;
  int ty = threadIdx.x >> 5;       // 0..7
#pragma unroll
  for (int i = 0; i < 4; ++i) {
    int kk = ty + i * 8;
    tile[kk][tx] = W[(size_t)(by * 32 + kk) * 512 + bx * 32 + tx];
  }
  __syncthreads();
#pragma unroll
  for (int i = 0; i < 4; ++i) {
    int nn = ty + i * 8;
    float v = tile[tx][nn];        // = W[by*32+tx][bx*32+nn]
    u16 h = f2b(v);
    size_t o = (size_t)(bx * 32 + nn) * 512 + by * 32 + tx;
    bthi[o] = h;
    if (btlo) btlo[o] = f2b(v - b2f(h));
  }
}

// ------------------------------------------------------- MFMA split GEMM ----
// C(MxN=512) = A(Mx512 f32) @ W(512x512), K=N=512.
// SPLIT=1: 3-product split (q,k). SPLIT=0: hi-only (v, wp).
// EMODE 0: f32 store C. 1: bf16 store Cb. 2: scatter via idx. 3: scatter +=.
template<int SPLIT, int EMODE>
__global__ __launch_bounds__(256) void mgemm_kernel(
    const float* __restrict__ Af,
    const u16* __restrict__ Bthi, const u16* __restrict__ Btlo,
    float* __restrict__ C, u16* __restrict__ Cb, const int* __restrict__ idx,
    int M, int scale, int n_l) {
  __shared__ u16 smem[SPLIT ? 4 * 5120 : 2 * 5120];   // [128][40] tiles
  u16* sAhi = smem;
  u16* sBhi = smem + 5120;
  u16* sAlo = SPLIT ? smem + 2 * 5120 : smem;
  u16* sBlo = SPLIT ? smem + 3 * 5120 : smem;

  int t = threadIdx.x, lane = t & 63, wave = t >> 6;
  int wr = wave >> 1, wc = wave & 1;
  int row0 = blockIdx.y * 128, col0 = blockIdx.x * 128;

  const f32x4 zero = { 0.f, 0.f, 0.f, 0.f };
  f32x4 acc[4][4];
#pragma unroll
  for (int i = 0; i < 4; ++i)
#pragma unroll
    for (int j = 0; j < 4; ++j) acc[i][j] = zero;

  for (int k0 = 0; k0 < 512; k0 += 32) {
#pragma unroll
    for (int it = 0; it < 4; ++it) {
      int c = it * 256 + t;
      int r = c >> 3, s = c & 7;
      float4 v = *reinterpret_cast<const float4*>(Af + (size_t)(row0 + r) * 512 + k0 + s * 4);
      ushort4 h, l;
      h.x = f2b(v.x); h.y = f2b(v.y); h.z = f2b(v.z); h.w = f2b(v.w);
      *reinterpret_cast<ushort4*>(&sAhi[r * 40 + s * 4]) = h;
      if (SPLIT) {
        l.x = f2b(v.x - b2f(h.x)); l.y = f2b(v.y - b2f(h.y));
        l.z = f2b(v.z - b2f(h.z)); l.w = f2b(v.w - b2f(h.w));
        *reinterpret_cast<ushort4*>(&sAlo[r * 40 + s * 4]) = l;
      }
    }
#pragma unroll
    for (int it = 0; it < 2; ++it) {
      int c = it * 256 + t;
      int r = c >> 2, s = c & 3;
      uint4 vb = *reinterpret_cast<const uint4*>(Bthi + (size_t)(col0 + r) * 512 + k0 + s * 8);
      *reinterpret_cast<uint4*>(&sBhi[r * 40 + s * 8]) = vb;
      if (SPLIT) {
        uint4 vl = *reinterpret_cast<const uint4*>(Btlo + (size_t)(col0 + r) * 512 + k0 + s * 8);
        *reinterpret_cast<uint4*>(&sBlo[r * 40 + s * 8]) = vl;
      }
    }
    __syncthreads();

    int fr = lane & 15;
    int kf = (lane >> 4) * 8;
    bf16x8 ah[4], bh[4], al[4], bl[4];
#pragma unroll
    for (int i = 0; i < 4; ++i) {
      ah[i] = *reinterpret_cast<const bf16x8*>(&sAhi[(wr * 64 + i * 16 + fr) * 40 + kf]);
      bh[i] = *reinterpret_cast<const bf16x8*>(&sBhi[(wc * 64 + i * 16 + fr) * 40 + kf]);
      if (SPLIT) {
        al[i] = *reinterpret_cast<const bf16x8*>(&sAlo[(wr * 64 + i * 16 + fr) * 40 + kf]);
        bl[i] = *reinterpret_cast<const bf16x8*>(&sBlo[(wc * 64 + i * 16 + fr) * 40 + kf]);
      }
    }
#pragma unroll
    for (int i = 0; i < 4; ++i)
#pragma unroll
      for (int j = 0; j < 4; ++j) {
        acc[i][j] = __builtin_amdgcn_mfma_f32_16x16x32_bf16(ah[i], bh[j], acc[i][j], 0, 0, 0);
        if (SPLIT) {
          acc[i][j] = __builtin_amdgcn_mfma_f32_16x16x32_bf16(ah[i], bl[j], acc[i][j], 0, 0, 0);
          acc[i][j] = __builtin_amdgcn_mfma_f32_16x16x32_bf16(al[i], bh[j], acc[i][j], 0, 0, 0);
        }
      }
    __syncthreads();
  }

  int ccol = col0 + wc * 64 + (lane & 15);
  int crow = row0 + wr * 64 + (lane >> 4) * 4;
#pragma unroll
  for (int i = 0; i < 4; ++i) {
#pragma unroll
    for (int r = 0; r < 4; ++r) {
      int gr = crow + i * 16 + r;
      if (EMODE == 0) {
#pragma unroll
        for (int j = 0; j < 4; ++j)
          C[(size_t)gr * 512 + ccol + j * 16] = acc[i][j][r];
      } else if (EMODE == 1) {
#pragma unroll
        for (int j = 0; j < 4; ++j)
          Cb[(size_t)gr * 512 + ccol + j * 16] = f2b(acc[i][j][r]);
      } else {
        int bb = gr / n_l, rr = gr - bb * n_l;
        for (int s = 0; s < scale; ++s) {
          int dst = idx[(size_t)bb * NTOK + (size_t)rr * scale + s];
          float* p = C + ((size_t)bb * NTOK + dst) * 512 + ccol;
          if (EMODE == 3) {
#pragma unroll
            for (int j = 0; j < 4; ++j) p[j * 16] += acc[i][j][r];
          } else {
#pragma unroll
            for (int j = 0; j < 4; ++j) p[j * 16] = acc[i][j][r];
          }
        }
      }
    }
  }
}

// ----------------------------------------------- fused windowed attention ---
// TWO blocks (512 thr, 8 waves) per (b,g,h), each owns 64 q-rows (p=bid&1).
// Phase A: sim in 2 d-halves (qT/kT f32, VALU — bit-identical ranking).
// Ballot top-k -> softmax -> prior mix; P kept packed bf16 in regs (atp).
// Phase B: PV via MFMA: P_lds[64][264] bf16 + Vt[64][136] bf16 per k-half;
// 2 C-frags/wave x 8 k-steps of mfma_f32_16x16x32_bf16.
// LDS 51200 B -> 3 blocks/CU.
__global__ __launch_bounds__(512) void attn_fused_kernel(
    const float* __restrict__ q, const float* __restrict__ k,
    const u16* __restrict__ vbf, const int* __restrict__ keepArr,
    const u16* __restrict__ prevA, u16* __restrict__ curA,
    const float* __restrict__ betaL, float* __restrict__ outp,
    int lvl, int n_l, int ng, int prev_ng) {
  __shared__ u64 smem8[6400];             // 51200 B
  float* qT    = (float*)smem8;           // [32][68]   (d, qi<64)     phase A
  float* kT    = qT + 32 * 68;            // [32][260]  (d, j<256)     phase A
  u16*   P_lds = (u16*)smem8;             // [64][264]  (q row, key)   phase B
  u16*   Vt    = (u16*)smem8 + 16896;     // [64][136]  (dv, k-half)   phase B

  int t = threadIdx.x;
  int lane = t & 63, wave = t >> 6;
  int bid = blockIdx.x;
  int p   = bid & 1;
  int h   = (bid >> 1) & 7;
  int gl  = bid >> 4;
  int g   = gl % ng;
  int b   = gl / ng;
  int bgh = bid >> 1;                     // (b,g,h) index for attn state

  const float* qbase = q + ((size_t)b * n_l + (size_t)g * GS + p * 64) * DIMC + h * DQK;
  const float* kbase = k + (size_t)b * n_l * DIMC + h * DQK;

  // ---- sim over two d-halves; acc identical to full-d accumulation ----
  float acc[8][4] = {};
#pragma unroll
  for (int dp = 0; dp < 2; ++dp) {
    int d0 = dp * 32;
    {  // qT: 64 qi x 8 d4 chunks = 512
      int qi = t >> 3, d4 = t & 7;
      float4 vv = *reinterpret_cast<const float4*>(qbase + (size_t)qi * DIMC + d0 + d4 * 4);
      qT[(d4 * 4 + 0) * 68 + qi] = vv.x;
      qT[(d4 * 4 + 1) * 68 + qi] = vv.y;
      qT[(d4 * 4 + 2) * 68 + qi] = vv.z;
      qT[(d4 * 4 + 3) * 68 + qi] = vv.w;
    }
#pragma unroll
    for (int it = 0; it < 4; ++it) {      // kT: 256 j x 8 d4 chunks
      int idx = it * 512 + t;
      int j = idx >> 3, d4 = idx & 7;
      int pp = g * GS + j;
      int src = (pp < n_l) ? pp : (2 * n_l - 1 - pp);
      float4 vv = *reinterpret_cast<const float4*>(kbase + (size_t)src * DIMC + d0 + d4 * 4);
      kT[(d4 * 4 + 0) * 260 + j] = vv.x;
      kT[(d4 * 4 + 1) * 260 + j] = vv.y;
      kT[(d4 * 4 + 2) * 260 + j] = vv.z;
      kT[(d4 * 4 + 3) * 260 + j] = vv.w;
    }
    __syncthreads();
#pragma unroll 2
    for (int d = 0; d < 32; ++d) {
      float ra[8], rb4[4];
      *reinterpret_cast<float4*>(&ra[0]) = *reinterpret_cast<const float4*>(&qT[d * 68 + wave * 8 + 0]);
      *reinterpret_cast<float4*>(&ra[4]) = *reinterpret_cast<const float4*>(&qT[d * 68 + wave * 8 + 4]);
      *reinterpret_cast<float4*>(&rb4[0]) = *reinterpret_cast<const float4*>(&kT[d * 260 + lane * 4]);
#pragma unroll
      for (int i = 0; i < 8; ++i)
#pragma unroll
        for (int j = 0; j < 4; ++j) acc[i][j] += ra[i] * rb4[j];
    }
    __syncthreads();
  }

  int kp = keepArr[b * ng + g];
  float beta = 0.f, wgt = 0.f;
  int lo = 0, hi = 0;
  if (lvl > 0) {
    beta = 1.f / (1.f + expf(-betaL[lvl]));
    float pos = ((float)g + 0.5f) * ((float)prev_ng / (float)ng) - 0.5f;
    float fl = floorf(pos);
    lo = (int)fl;
    if (lo < 0) lo = 0;
    if (lo > prev_ng - 1) lo = prev_ng - 1;
    hi = lo + 1; if (hi > prev_ng - 1) hi = prev_ng - 1;
    wgt = fminf(fmaxf(pos - fl, 0.f), 1.f);
  }
  u64 lmask = (1ull << lane) - 1ull;

  // ---- per-row: ballot top-k -> softmax -> prior mix; retain packed bf16 ---
  unsigned atp[8][2];
#pragma unroll
  for (int r = 0; r < 8; ++r) {
    int i = p * 64 + wave * 8 + r;        // row within the 128-row group
    float sv[4];
    unsigned um[4];
#pragma unroll
    for (int e = 0; e < 4; ++e) {
      sv[e] = acc[r][e] * 0.125f;
      unsigned u = __float_as_uint(sv[e]);
      um[e] = (u & 0x80000000u) ? ~u : (u | 0x80000000u);
    }
    unsigned T = 0u;
    for (int bit = 31; bit >= 0; --bit) {
      unsigned T2 = T | (1u << bit);
      int c = __popcll(__ballot(um[0] >= T2)) + __popcll(__ballot(um[1] >= T2))
            + __popcll(__ballot(um[2] >= T2)) + __popcll(__ballot(um[3] >= T2));
      if (c >= kp) T = T2;
    }
    int c_gt = __popcll(__ballot(um[0] > T)) + __popcll(__ballot(um[1] > T))
             + __popcll(__ballot(um[2] > T)) + __popcll(__ballot(um[3] > T));
    u64 beq[4];
#pragma unroll
    for (int e = 0; e < 4; ++e) beq[e] = __ballot(um[e] == T);
    int trbase = __popcll(beq[0] & lmask) + __popcll(beq[1] & lmask)
               + __popcll(beq[2] & lmask) + __popcll(beq[3] & lmask);
    int need = kp - c_gt;
    bool msk[4];
    int own = 0;
#pragma unroll
    for (int e = 0; e < 4; ++e) {
      bool eq = (um[e] == T);
      msk[e] = (um[e] > T) || (eq && (trbase + own) < need);
      own += eq ? 1 : 0;
    }
    float m = -3.0e38f;
#pragma unroll
    for (int e = 0; e < 4; ++e) if (msk[e]) m = fmaxf(m, sv[e]);
    m = wave_max64(m);
    float ez[4], zs = 0.f;
#pragma unroll
    for (int e = 0; e < 4; ++e) { ez[e] = msk[e] ? __expf(sv[e] - m) : 0.f; zs += ez[e]; }
    zs = wave_sum64(zs);
    float at[4];
#pragma unroll
    for (int e = 0; e < 4; ++e) at[e] = ez[e] / zs;
    if (lvl > 0) {
      size_t baseLo = ((((size_t)b * prev_ng + lo) * 8 + h) * GS + i) * WIN + lane * 4;
      size_t baseHi = ((((size_t)b * prev_ng + hi) * 8 + h) * GS + i) * WIN + lane * 4;
      uint2 rlo = *reinterpret_cast<const uint2*>(prevA + baseLo);
      uint2 rhi = *reinterpret_cast<const uint2*>(prevA + baseHi);
      float pl[4] = { b2f_lo(rlo.x), b2f_hi(rlo.x), b2f_lo(rlo.y), b2f_hi(rlo.y) };
      float ph[4] = { b2f_lo(rhi.x), b2f_hi(rhi.x), b2f_lo(rhi.y), b2f_hi(rhi.y) };
      float pr[4], ps = 0.f;
#pragma unroll
      for (int e = 0; e < 4; ++e) {
        pr[e] = fmaxf((1.f - wgt) * pl[e] + wgt * ph[e], 0.f);
        ps += pr[e];
      }
      ps = wave_sum64(ps) + 1e-9f;
#pragma unroll
      for (int e = 0; e < 4; ++e) at[e] = (1.f - beta) * at[e] + beta * (pr[e] / ps);
    }
    atp[r][0] = (unsigned)f2b(at[0]) | ((unsigned)f2b(at[1]) << 16);
    atp[r][1] = (unsigned)f2b(at[2]) | ((unsigned)f2b(at[3]) << 16);
    if (curA != nullptr) {
      uint2 o = { atp[r][0], atp[r][1] };
      *reinterpret_cast<uint2*>(curA + ((size_t)bgh * GS + i) * WIN + lane * 4) = o;
    }
  }

  // ---- PV via MFMA: O(64x64) = P(64x256) @ V(256x64) ----
  // write P rows (wave*8+r), keys 4*lane..4*lane+3 as one b64 store
#pragma unroll
  for (int r = 0; r < 8; ++r) {
    uint2 o = { atp[r][0], atp[r][1] };
    *reinterpret_cast<uint2*>(&P_lds[(wave * 8 + r) * 264 + lane * 4]) = o;
  }

  const u16* vbase = vbf + (size_t)b * n_l * DIMC + h * DV;
  int rf   = wave >> 1;                  // q-row frag 0..3
  int cf0  = (wave & 1) * 2;             // dv col frag base {0,2}
  int frow = lane & 15;
  int fk   = (lane >> 4) * 8;
  f32x4 oacc0 = { 0.f, 0.f, 0.f, 0.f };
  f32x4 oacc1 = { 0.f, 0.f, 0.f, 0.f };
  int jlo = t & 15, vd4 = (t >> 4) & 15, jh2 = t >> 8;

#pragma unroll
  for (int jp = 0; jp < 2; ++jp) {
    // stage Vt half: Vt[dv][j] = V[g*GS + jp*128 + j][h*64 + dv]
#pragma unroll
    for (int it = 0; it < 4; ++it) {
      int j = (jh2 * 4 + it) * 16 + jlo;           // 0..127
      int pp = g * GS + jp * 128 + j;
      int src = (pp < n_l) ? pp : (2 * n_l - 1 - pp);
      ushort4 vv = *reinterpret_cast<const ushort4*>(vbase + (size_t)src * DIMC + vd4 * 4);
      Vt[(vd4 * 4 + 0) * 136 + j] = vv.x;
      Vt[(vd4 * 4 + 1) * 136 + j] = vv.y;
      Vt[(vd4 * 4 + 2) * 136 + j] = vv.z;
      Vt[(vd4 * 4 + 3) * 136 + j] = vv.w;
    }
    __syncthreads();
    int kb2 = jp * 128;
#pragma unroll
    for (int ks = 0; ks < 4; ++ks) {
      bf16x8 a  = *reinterpret_cast<const bf16x8*>(&P_lds[(rf * 16 + frow) * 264 + kb2 + ks * 32 + fk]);
      bf16x8 b0 = *reinterpret_cast<const bf16x8*>(&Vt[(cf0 * 16 + frow) * 136 + ks * 32 + fk]);
      bf16x8 b1 = *reinterpret_cast<const bf16x8*>(&Vt[((cf0 + 1) * 16 + frow) * 136 + ks * 32 + fk]);
      oacc0 = __builtin_amdgcn_mfma_f32_16x16x32_bf16(a, b0, oacc0, 0, 0, 0);
      oacc1 = __builtin_amdgcn_mfma_f32_16x16x32_bf16(a, b1, oacc1, 0, 0, 0);
    }
    __syncthreads();
  }

  float* obase = outp + ((size_t)b * n_l + (size_t)g * GS + p * 64 + rf * 16) * DIMC + h * DV;
#pragma unroll
  for (int rr = 0; rr < 4; ++rr) {
    int qrow = (lane >> 4) * 4 + rr;
    obase[(size_t)qrow * DIMC + cf0 * 16 + frow]       = oacc0[rr];
    obase[(size_t)qrow * DIMC + (cf0 + 1) * 16 + frow] = oacc1[rr];
  }
}

// ---------------------------------------------------------------------------
extern "C" void kernel_launch(void* const* d_in, const int* in_sizes, int n_in,
                              void* d_out, int out_size, void* d_ws, size_t ws_size,
                              hipStream_t stream) {
  (void)in_sizes; (void)n_in; (void)out_size; (void)ws_size;
  const float* x        = (const float*)d_in[0];
  const int*   labels   = (const int*)d_in[1];
  const float* scores   = (const float*)d_in[2];
  const int*   idx_last = (const int*)d_in[3];
  const float* Wq       = (const float*)d_in[4];
  const float* Wk       = (const float*)d_in[5];
  const float* Wv       = (const float*)d_in[6];
  const float* Wp       = (const float*)d_in[7];
  const float* betaL    = (const float*)d_in[8];
  float* out = (float*)d_out;

  char* w = (char*)d_ws;
  size_t off = 0;
  auto take = [&](size_t bytes) -> char* {
    char* p = w + off;
    off += (bytes + 255) & ~(size_t)255;
    return p;
  };
  float* qb    = (float*)take(33554432);   // q f32 (max 2*8192*512)
  float* kb    = (float*)take(33554432);   // k f32
  u16*   vbf   = (u16*)  take(16777216);   // v bf16
  float* xo    = (float*)take(33554432);   // xl (pooled x) / outp union
  u16*   attnA = (u16*)  take(16777216);   // lvl0 attn bf16
  u16*   attnB = (u16*)  take(33554432);   // lvl1 attn bf16
  u16*   wqhi  = (u16*)  take(524288);     // transposed+split weights
  u16*   wqlo  = (u16*)  take(524288);
  u16*   wkhi  = (u16*)  take(524288);
  u16*   wklo  = (u16*)  take(524288);
  u16*   wvhi  = (u16*)  take(524288);
  u16*   wphi  = (u16*)  take(524288);
  float* sl    = (float*)take(32768);
  int*   ll    = (int*)  take(32768);
  int*   keepb = (int*)  take(1024);

  const size_t wstride = (size_t)DIMC * DIMC;
  for (int lvl = 0; lvl < 3; ++lvl) {
    int scale = (lvl == 0) ? 4 : (lvl == 1) ? 2 : 1;
    int n_l = NTOK / scale;
    int ng  = n_l / GS;
    int M   = 2 * n_l;
    const float* xin; const int* lin; const float* sin_;
    if (scale > 1) {
      int tfeat = 2 * n_l * (DIMC / 4);
      pool_feat_kernel<<<(tfeat + 255) / 256, 256, 0, stream>>>(x, scores, xo, sl, NTOK, scale);
      pool_label_kernel<<<(2 * n_l + 255) / 256, 256, 0, stream>>>(labels, scores, ll, NTOK, scale);
      xin = xo; lin = ll; sin_ = sl;
    } else {
      xin = x; lin = labels; sin_ = scores;
    }
    keep_kernel<<<(2 * ng + 127) / 128, 128, 0, stream>>>(lin, sin_, keepb, 2 * ng);

    wsplitT_kernel<<<256, 256, 0, stream>>>(Wq + lvl * wstride, wqhi, wqlo);
    wsplitT_kernel<<<256, 256, 0, stream>>>(Wk + lvl * wstride, wkhi, wklo);
    wsplitT_kernel<<<256, 256, 0, stream>>>(Wv + lvl * wstride, wvhi, nullptr);
    wsplitT_kernel<<<256, 256, 0, stream>>>(Wp + lvl * wstride, wphi, nullptr);

    dim3 gg(4, M / 128);
    mgemm_kernel<1, 0><<<gg, 256, 0, stream>>>(xin, wqhi, wqlo, qb, nullptr, nullptr, M, 0, 0);
    mgemm_kernel<1, 0><<<gg, 256, 0, stream>>>(xin, wkhi, wklo, kb, nullptr, nullptr, M, 0, 0);
    mgemm_kernel<0, 1><<<gg, 256, 0, stream>>>(xin, wvhi, nullptr, nullptr, vbf, nullptr, M, 0, 0);

    const u16* prev = (lvl == 0) ? nullptr : ((lvl == 1) ? attnA : attnB);
    u16* cur = (lvl == 0) ? attnA : ((lvl == 1) ? attnB : nullptr);
    attn_fused_kernel<<<2 * ng * 8 * 2, 512, 0, stream>>>(qb, kb, vbf, keepb, prev, cur,
                                                          betaL, xo, lvl, n_l, ng, ng / 2);

    if (lvl == 0)
      mgemm_kernel<0, 2><<<gg, 256, 0, stream>>>(xo, wphi, nullptr, out, nullptr, idx_last, M, scale, n_l);
    else
      mgemm_kernel<0, 3><<<gg, 256, 0, stream>>>(xo, wphi, nullptr, out, nullptr, idx_last, M, scale, n_l);
  }
}

// Round 8
// 741.291 us; speedup vs baseline: 1.8528x; 1.0297x over previous
//
#include <hip/hip_runtime.h>
#include <math.h>

// ---------------------------------------------------------------------------
// LowToHighMultiLevelReconstruction — round 8.
// Change vs round 7: A-side bf16 hi/lo split PRECOMPUTED once per level
// (pool_feat writes split directly; asplit kernel for lvl2 raw x). mgemm
// stages A with plain uint4 copies (no VALU conversion, half the A bytes).
// Attention writes its output as bf16-hi directly (Wp GEMM was hi-only),
// saving a 16MB roundtrip; outp aliases xhi. All MFMA operand values are
// bit-identical to round 7 -> absmax unchanged.
// ---------------------------------------------------------------------------

#define GS   128
#define WIN  256        // 2*GS
#define DQK  64
#define DV   64
#define DIMC 512
#define NTOK 8192

typedef unsigned long long u64;
typedef unsigned short u16;
typedef __attribute__((ext_vector_type(8))) short bf16x8;
typedef __attribute__((ext_vector_type(4))) float f32x4;

__device__ __forceinline__ u16 f2b(float f) {     // f32 -> bf16 RNE
  unsigned u = __float_as_uint(f);
  u = (u + 0x7fffu + ((u >> 16) & 1u)) >> 16;
  return (u16)u;
}
__device__ __forceinline__ float b2f(u16 h) { return __uint_as_float(((unsigned)h) << 16); }
__device__ __forceinline__ float b2f_lo(unsigned u) { return __uint_as_float(u << 16); }
__device__ __forceinline__ float b2f_hi(unsigned u) { return __uint_as_float(u & 0xffff0000u); }

__device__ __forceinline__ float wave_max64(float v) {
#pragma unroll
  for (int m = 1; m < 64; m <<= 1) v = fmaxf(v, __shfl_xor(v, m, 64));
  return v;
}
__device__ __forceinline__ float wave_sum64(float v) {
#pragma unroll
  for (int m = 1; m < 64; m <<= 1) v += __shfl_xor(v, m, 64);
  return v;
}

// --------------------------------------------- pooling (writes split bf16) --
__global__ void pool_split_kernel(const float* __restrict__ x,
                                  const float* __restrict__ scores,
                                  u16* __restrict__ xhi, u16* __restrict__ xlo,
                                  float* __restrict__ sl, int n, int scale) {
  int npool = n / scale;
  int total = 2 * npool * (DIMC / 4);
  int tid = blockIdx.x * blockDim.x + threadIdx.x;
  if (tid >= total) return;
  int c4 = tid & 127;
  int g  = (tid >> 7) % npool;
  int b  = (tid >> 7) / npool;
  const float* xp = x + ((size_t)b * n + (size_t)g * scale) * DIMC + c4 * 4;
  float ax = 0.f, ay = 0.f, az = 0.f, aw = 0.f, wsum = 0.f, ssum = 0.f;
  for (int s = 0; s < scale; ++s) {
    float sc = scores[(size_t)b * n + (size_t)g * scale + s];
    float w  = fmaxf(sc, 1e-6f);
    float4 xv = *reinterpret_cast<const float4*>(xp + (size_t)s * DIMC);
    ax += xv.x * w; ay += xv.y * w; az += xv.z * w; aw += xv.w * w;
    wsum += w; ssum += sc;
  }
  float o[4] = { ax / wsum, ay / wsum, az / wsum, aw / wsum };
  ushort4 h, l;
  h.x = f2b(o[0]); h.y = f2b(o[1]); h.z = f2b(o[2]); h.w = f2b(o[3]);
  l.x = f2b(o[0] - b2f(h.x)); l.y = f2b(o[1] - b2f(h.y));
  l.z = f2b(o[2] - b2f(h.z)); l.w = f2b(o[3] - b2f(h.w));
  size_t off = ((size_t)b * npool + g) * DIMC + c4 * 4;
  *reinterpret_cast<ushort4*>(xhi + off) = h;
  *reinterpret_cast<ushort4*>(xlo + off) = l;
  if (c4 == 0) sl[(size_t)b * npool + g] = ssum / (float)scale;
}

// --------------------------------------------------- raw x split (lvl 2) ----
__global__ void asplit_kernel(const float* __restrict__ x,
                              u16* __restrict__ xhi, u16* __restrict__ xlo) {
  int tid = blockIdx.x * 256 + threadIdx.x;     // over 2*NTOK*128 float4s
  float4 v = *reinterpret_cast<const float4*>(x + (size_t)tid * 4);
  ushort4 h, l;
  h.x = f2b(v.x); h.y = f2b(v.y); h.z = f2b(v.z); h.w = f2b(v.w);
  l.x = f2b(v.x - b2f(h.x)); l.y = f2b(v.y - b2f(h.y));
  l.z = f2b(v.z - b2f(h.z)); l.w = f2b(v.w - b2f(h.w));
  *reinterpret_cast<ushort4*>(xhi + (size_t)tid * 4) = h;
  *reinterpret_cast<ushort4*>(xlo + (size_t)tid * 4) = l;
}

__global__ void pool_label_kernel(const int* __restrict__ labels,
                                  const float* __restrict__ scores,
                                  int* __restrict__ ll, int n, int scale) {
  int npool = n / scale;
  int tid = blockIdx.x * blockDim.x + threadIdx.x;
  if (tid >= 2 * npool) return;
  int b = tid / npool, g = tid % npool;
  float counts[4] = {0.f, 0.f, 0.f, 0.f};
  float ssum[4]   = {0.f, 0.f, 0.f, 0.f};
  int firstp[4];
  for (int c = 0; c < 4; ++c) firstp[c] = scale;
  for (int s = 0; s < scale; ++s) {
    int   L = labels[(size_t)b * n + (size_t)g * scale + s];
    float S = scores[(size_t)b * n + (size_t)g * scale + s];
    counts[L] += 1.0f;
    ssum[L]   += S;
    if (s < firstp[L]) firstp[L] = s;
  }
  float cmax = fmaxf(fmaxf(counts[0], counts[1]), fmaxf(counts[2], counts[3]));
  float s2[4];
  for (int c = 0; c < 4; ++c) s2[c] = (counts[c] == cmax) ? ssum[c] : -1e9f;
  float smax = fmaxf(fmaxf(s2[0], s2[1]), fmaxf(s2[2], s2[3]));
  int fp[4];
  for (int c = 0; c < 4; ++c) fp[c] = (s2[c] == smax) ? firstp[c] : scale;
  int best = 0, bv = fp[0];
  for (int c = 1; c < 4; ++c) if (fp[c] < bv) { bv = fp[c]; best = c; }
  ll[(size_t)b * npool + g] = best;
}

// ------------------------------------------------------------ keep (focus) --
__global__ void keep_kernel(const int* __restrict__ ll, const float* __restrict__ sl,
                            int* __restrict__ keep, int total) {
  int tid = blockIdx.x * blockDim.x + threadIdx.x;
  if (tid >= total) return;
  const int*   lp = ll + (size_t)tid * GS;
  const float* sp = sl + (size_t)tid * GS;
  float counts[4] = {0.f, 0.f, 0.f, 0.f};
  for (int i = 0; i < GS; ++i) counts[lp[i]] += 1.f;
  int mode = 0; float bv = counts[0];
  for (int c = 1; c < 4; ++c) if (counts[c] > bv) { bv = counts[c]; mode = c; }
  float pm = 0.f, mean = 0.f;
  for (int i = 0; i < GS; ++i) { pm += (lp[i] == mode) ? 1.f : 0.f; mean += sp[i]; }
  float purity = pm / (float)GS;
  mean /= (float)GS;
  float var = 0.f;
  for (int i = 0; i < GS; ++i) { float d = sp[i] - mean; var += d * d; }
  var /= (float)GS;
  float focus = 0.5f + 0.25f * purity - 0.25f * var;
  focus = fminf(fmaxf(focus, 0.25f), 0.75f);
  keep[tid] = (int)ceilf(focus * (float)WIN);
}

// ------------------------------------------- weight transpose + bf16 split --
__global__ __launch_bounds__(256) void wsplitT_kernel(const float* __restrict__ W,
                                                      u16* __restrict__ bthi,
                                                      u16* __restrict__ btlo) {
  __shared__ float tile[32][33];
  int bx = blockIdx.x & 15;        // n block
  int by = blockIdx.x >> 4;        // k block
  int tx = threadIdx.x & 31;
  int ty = threadIdx.x >> 5;       // 0..7
#pragma unroll
  for (int i = 0; i < 4; ++i) {
    int kk = ty + i * 8;
    tile[kk][tx] = W[(size_t)(by * 32 + kk) * 512 + bx * 32 + tx];
  }
  __syncthreads();
#pragma unroll
  for (int i = 0; i < 4; ++i) {
    int nn = ty + i * 8;
    float v = tile[tx][nn];        // = W[by*32+tx][bx*32+nn]
    u16 h = f2b(v);
    size_t o = (size_t)(bx * 32 + nn) * 512 + by * 32 + tx;
    bthi[o] = h;
    if (btlo) btlo[o] = f2b(v - b2f(h));
  }
}

// ------------------------------------------------------- MFMA split GEMM ----
// C(MxN=512) = A(Mx512, pre-split bf16 hi/lo) @ W(512x512).
// SPLIT=1: 3-product split (q,k). SPLIT=0: hi-only (v, wp).
// EMODE 0: f32 store C. 1: bf16 store Cb. 2: scatter via idx. 3: scatter +=.
template<int SPLIT, int EMODE>
__global__ __launch_bounds__(256) void mgemm_kernel(
    const u16* __restrict__ Ahi, const u16* __restrict__ Alo,
    const u16* __restrict__ Bthi, const u16* __restrict__ Btlo,
    float* __restrict__ C, u16* __restrict__ Cb, const int* __restrict__ idx,
    int M, int scale, int n_l) {
  __shared__ u16 smem[SPLIT ? 4 * 5120 : 2 * 5120];   // [128][40] tiles
  u16* sAhi = smem;
  u16* sBhi = smem + 5120;
  u16* sAlo = SPLIT ? smem + 2 * 5120 : smem;
  u16* sBlo = SPLIT ? smem + 3 * 5120 : smem;

  int t = threadIdx.x, lane = t & 63, wave = t >> 6;
  int wr = wave >> 1, wc = wave & 1;
  int row0 = blockIdx.y * 128, col0 = blockIdx.x * 128;

  const f32x4 zero = { 0.f, 0.f, 0.f, 0.f };
  f32x4 acc[4][4];
#pragma unroll
  for (int i = 0; i < 4; ++i)
#pragma unroll
    for (int j = 0; j < 4; ++j) acc[i][j] = zero;

  for (int k0 = 0; k0 < 512; k0 += 32) {
    // ---- stage A (pre-split bf16): 128x32 tile, 512 uint4 chunks ----
#pragma unroll
    for (int it = 0; it < 2; ++it) {
      int c = it * 256 + t;
      int r = c >> 2, s = c & 3;
      uint4 va = *reinterpret_cast<const uint4*>(Ahi + (size_t)(row0 + r) * 512 + k0 + s * 8);
      *reinterpret_cast<uint4*>(&sAhi[r * 40 + s * 8]) = va;
      if (SPLIT) {
        uint4 vl = *reinterpret_cast<const uint4*>(Alo + (size_t)(row0 + r) * 512 + k0 + s * 8);
        *reinterpret_cast<uint4*>(&sAlo[r * 40 + s * 8]) = vl;
      }
    }
    // ---- stage B (bf16, pre-transposed): 128x32 tile, 512 uint4 chunks ----
#pragma unroll
    for (int it = 0; it < 2; ++it) {
      int c = it * 256 + t;
      int r = c >> 2, s = c & 3;
      uint4 vb = *reinterpret_cast<const uint4*>(Bthi + (size_t)(col0 + r) * 512 + k0 + s * 8);
      *reinterpret_cast<uint4*>(&sBhi[r * 40 + s * 8]) = vb;
      if (SPLIT) {
        uint4 vl = *reinterpret_cast<const uint4*>(Btlo + (size_t)(col0 + r) * 512 + k0 + s * 8);
        *reinterpret_cast<uint4*>(&sBlo[r * 40 + s * 8]) = vl;
      }
    }
    __syncthreads();

    int fr = lane & 15;
    int kf = (lane >> 4) * 8;
    bf16x8 ah[4], bh[4], al[4], bl[4];
#pragma unroll
    for (int i = 0; i < 4; ++i) {
      ah[i] = *reinterpret_cast<const bf16x8*>(&sAhi[(wr * 64 + i * 16 + fr) * 40 + kf]);
      bh[i] = *reinterpret_cast<const bf16x8*>(&sBhi[(wc * 64 + i * 16 + fr) * 40 + kf]);
      if (SPLIT) {
        al[i] = *reinterpret_cast<const bf16x8*>(&sAlo[(wr * 64 + i * 16 + fr) * 40 + kf]);
        bl[i] = *reinterpret_cast<const bf16x8*>(&sBlo[(wc * 64 + i * 16 + fr) * 40 + kf]);
      }
    }
#pragma unroll
    for (int i = 0; i < 4; ++i)
#pragma unroll
      for (int j = 0; j < 4; ++j) {
        acc[i][j] = __builtin_amdgcn_mfma_f32_16x16x32_bf16(ah[i], bh[j], acc[i][j], 0, 0, 0);
        if (SPLIT) {
          acc[i][j] = __builtin_amdgcn_mfma_f32_16x16x32_bf16(ah[i], bl[j], acc[i][j], 0, 0, 0);
          acc[i][j] = __builtin_amdgcn_mfma_f32_16x16x32_bf16(al[i], bh[j], acc[i][j], 0, 0, 0);
        }
      }
    __syncthreads();
  }

  int ccol = col0 + wc * 64 + (lane & 15);
  int crow = row0 + wr * 64 + (lane >> 4) * 4;
#pragma unroll
  for (int i = 0; i < 4; ++i) {
#pragma unroll
    for (int r = 0; r < 4; ++r) {
      int gr = crow + i * 16 + r;
      if (EMODE == 0) {
#pragma unroll
        for (int j = 0; j < 4; ++j)
          C[(size_t)gr * 512 + ccol + j * 16] = acc[i][j][r];
      } else if (EMODE == 1) {
#pragma unroll
        for (int j = 0; j < 4; ++j)
          Cb[(size_t)gr * 512 + ccol + j * 16] = f2b(acc[i][j][r]);
      } else {
        int bb = gr / n_l, rr = gr - bb * n_l;
        for (int s = 0; s < scale; ++s) {
          int dst = idx[(size_t)bb * NTOK + (size_t)rr * scale + s];
          float* p = C + ((size_t)bb * NTOK + dst) * 512 + ccol;
          if (EMODE == 3) {
#pragma unroll
            for (int j = 0; j < 4; ++j) p[j * 16] += acc[i][j][r];
          } else {
#pragma unroll
            for (int j = 0; j < 4; ++j) p[j * 16] = acc[i][j][r];
          }
        }
      }
    }
  }
}

// ----------------------------------------------- fused windowed attention ---
// TWO blocks (512 thr, 8 waves) per (b,g,h), each owns 64 q-rows (p=bid&1).
// Phase A: sim in 2 d-halves (qT/kT f32, VALU — bit-identical ranking).
// Ballot top-k -> softmax -> prior mix; P kept packed bf16 in regs (atp).
// Phase B: PV via MFMA; output written as bf16-hi (Wp GEMM is hi-only).
__global__ __launch_bounds__(512) void attn_fused_kernel(
    const float* __restrict__ q, const float* __restrict__ k,
    const u16* __restrict__ vbf, const int* __restrict__ keepArr,
    const u16* __restrict__ prevA, u16* __restrict__ curA,
    const float* __restrict__ betaL, u16* __restrict__ outp,
    int lvl, int n_l, int ng, int prev_ng) {
  __shared__ u64 smem8[6400];             // 51200 B
  float* qT    = (float*)smem8;           // [32][68]   (d, qi<64)     phase A
  float* kT    = qT + 32 * 68;            // [32][260]  (d, j<256)     phase A
  u16*   P_lds = (u16*)smem8;             // [64][264]  (q row, key)   phase B
  u16*   Vt    = (u16*)smem8 + 16896;     // [64][136]  (dv, k-half)   phase B

  int t = threadIdx.x;
  int lane = t & 63, wave = t >> 6;
  int bid = blockIdx.x;
  int p   = bid & 1;
  int h   = (bid >> 1) & 7;
  int gl  = bid >> 4;
  int g   = gl % ng;
  int b   = gl / ng;
  int bgh = bid >> 1;                     // (b,g,h) index for attn state

  const float* qbase = q + ((size_t)b * n_l + (size_t)g * GS + p * 64) * DIMC + h * DQK;
  const float* kbase = k + (size_t)b * n_l * DIMC + h * DQK;

  // ---- sim over two d-halves; acc identical to full-d accumulation ----
  float acc[8][4] = {};
#pragma unroll
  for (int dp = 0; dp < 2; ++dp) {
    int d0 = dp * 32;
    {  // qT: 64 qi x 8 d4 chunks = 512
      int qi = t >> 3, d4 = t & 7;
      float4 vv = *reinterpret_cast<const float4*>(qbase + (size_t)qi * DIMC + d0 + d4 * 4);
      qT[(d4 * 4 + 0) * 68 + qi] = vv.x;
      qT[(d4 * 4 + 1) * 68 + qi] = vv.y;
      qT[(d4 * 4 + 2) * 68 + qi] = vv.z;
      qT[(d4 * 4 + 3) * 68 + qi] = vv.w;
    }
#pragma unroll
    for (int it = 0; it < 4; ++it) {      // kT: 256 j x 8 d4 chunks
      int idx = it * 512 + t;
      int j = idx >> 3, d4 = idx & 7;
      int pp = g * GS + j;
      int src = (pp < n_l) ? pp : (2 * n_l - 1 - pp);
      float4 vv = *reinterpret_cast<const float4*>(kbase + (size_t)src * DIMC + d0 + d4 * 4);
      kT[(d4 * 4 + 0) * 260 + j] = vv.x;
      kT[(d4 * 4 + 1) * 260 + j] = vv.y;
      kT[(d4 * 4 + 2) * 260 + j] = vv.z;
      kT[(d4 * 4 + 3) * 260 + j] = vv.w;
    }
    __syncthreads();
#pragma unroll 2
    for (int d = 0; d < 32; ++d) {
      float ra[8], rb4[4];
      *reinterpret_cast<float4*>(&ra[0]) = *reinterpret_cast<const float4*>(&qT[d * 68 + wave * 8 + 0]);
      *reinterpret_cast<float4*>(&ra[4]) = *reinterpret_cast<const float4*>(&qT[d * 68 + wave * 8 + 4]);
      *reinterpret_cast<float4*>(&rb4[0]) = *reinterpret_cast<const float4*>(&kT[d * 260 + lane * 4]);
#pragma unroll
      for (int i = 0; i < 8; ++i)
#pragma unroll
        for (int j = 0; j < 4; ++j) acc[i][j] += ra[i] * rb4[j];
    }
    __syncthreads();
  }

  int kp = keepArr[b * ng + g];
  float beta = 0.f, wgt = 0.f;
  int lo = 0, hi = 0;
  if (lvl > 0) {
    beta = 1.f / (1.f + expf(-betaL[lvl]));
    float pos = ((float)g + 0.5f) * ((float)prev_ng / (float)ng) - 0.5f;
    float fl = floorf(pos);
    lo = (int)fl;
    if (lo < 0) lo = 0;
    if (lo > prev_ng - 1) lo = prev_ng - 1;
    hi = lo + 1; if (hi > prev_ng - 1) hi = prev_ng - 1;
    wgt = fminf(fmaxf(pos - fl, 0.f), 1.f);
  }
  u64 lmask = (1ull << lane) - 1ull;

  // ---- per-row: ballot top-k -> softmax -> prior mix; retain packed bf16 ---
  unsigned atp[8][2];
#pragma unroll
  for (int r = 0; r < 8; ++r) {
    int i = p * 64 + wave * 8 + r;        // row within the 128-row group
    float sv[4];
    unsigned um[4];
#pragma unroll
    for (int e = 0; e < 4; ++e) {
      sv[e] = acc[r][e] * 0.125f;
      unsigned u = __float_as_uint(sv[e]);
      um[e] = (u & 0x80000000u) ? ~u : (u | 0x80000000u);
    }
    unsigned T = 0u;
    for (int bit = 31; bit >= 0; --bit) {
      unsigned T2 = T | (1u << bit);
      int c = __popcll(__ballot(um[0] >= T2)) + __popcll(__ballot(um[1] >= T2))
            + __popcll(__ballot(um[2] >= T2)) + __popcll(__ballot(um[3] >= T2));
      if (c >= kp) T = T2;
    }
    int c_gt = __popcll(__ballot(um[0] > T)) + __popcll(__ballot(um[1] > T))
             + __popcll(__ballot(um[2] > T)) + __popcll(__ballot(um[3] > T));
    u64 beq[4];
#pragma unroll
    for (int e = 0; e < 4; ++e) beq[e] = __ballot(um[e] == T);
    int trbase = __popcll(beq[0] & lmask) + __popcll(beq[1] & lmask)
               + __popcll(beq[2] & lmask) + __popcll(beq[3] & lmask);
    int need = kp - c_gt;
    bool msk[4];
    int own = 0;
#pragma unroll
    for (int e = 0; e < 4; ++e) {
      bool eq = (um[e] == T);
      msk[e] = (um[e] > T) || (eq && (trbase + own) < need);
      own += eq ? 1 : 0;
    }
    float m = -3.0e38f;
#pragma unroll
    for (int e = 0; e < 4; ++e) if (msk[e]) m = fmaxf(m, sv[e]);
    m = wave_max64(m);
    float ez[4], zs = 0.f;
#pragma unroll
    for (int e = 0; e < 4; ++e) { ez[e] = msk[e] ? __expf(sv[e] - m) : 0.f; zs += ez[e]; }
    zs = wave_sum64(zs);
    float at[4];
#pragma unroll
    for (int e = 0; e < 4; ++e) at[e] = ez[e] / zs;
    if (lvl > 0) {
      size_t baseLo = ((((size_t)b * prev_ng + lo) * 8 + h) * GS + i) * WIN + lane * 4;
      size_t baseHi = ((((size_t)b * prev_ng + hi) * 8 + h) * GS + i) * WIN + lane * 4;
      uint2 rlo = *reinterpret_cast<const uint2*>(prevA + baseLo);
      uint2 rhi = *reinterpret_cast<const uint2*>(prevA + baseHi);
      float pl[4] = { b2f_lo(rlo.x), b2f_hi(rlo.x), b2f_lo(rlo.y), b2f_hi(rlo.y) };
      float ph[4] = { b2f_lo(rhi.x), b2f_hi(rhi.x), b2f_lo(rhi.y), b2f_hi(rhi.y) };
      float pr[4], ps = 0.f;
#pragma unroll
      for (int e = 0; e < 4; ++e) {
        pr[e] = fmaxf((1.f - wgt) * pl[e] + wgt * ph[e], 0.f);
        ps += pr[e];
      }
      ps = wave_sum64(ps) + 1e-9f;
#pragma unroll
      for (int e = 0; e < 4; ++e) at[e] = (1.f - beta) * at[e] + beta * (pr[e] / ps);
    }
    atp[r][0] = (unsigned)f2b(at[0]) | ((unsigned)f2b(at[1]) << 16);
    atp[r][1] = (unsigned)f2b(at[2]) | ((unsigned)f2b(at[3]) << 16);
    if (curA != nullptr) {
      uint2 o = { atp[r][0], atp[r][1] };
      *reinterpret_cast<uint2*>(curA + ((size_t)bgh * GS + i) * WIN + lane * 4) = o;
    }
  }

  // ---- PV via MFMA: O(64x64) = P(64x256) @ V(256x64) ----
#pragma unroll
  for (int r = 0; r < 8; ++r) {
    uint2 o = { atp[r][0], atp[r][1] };
    *reinterpret_cast<uint2*>(&P_lds[(wave * 8 + r) * 264 + lane * 4]) = o;
  }

  const u16* vbase = vbf + (size_t)b * n_l * DIMC + h * DV;
  int rf   = wave >> 1;                  // q-row frag 0..3
  int cf0  = (wave & 1) * 2;             // dv col frag base {0,2}
  int frow = lane & 15;
  int fk   = (lane >> 4) * 8;
  f32x4 oacc0 = { 0.f, 0.f, 0.f, 0.f };
  f32x4 oacc1 = { 0.f, 0.f, 0.f, 0.f };
  int jlo = t & 15, vd4 = (t >> 4) & 15, jh2 = t >> 8;

#pragma unroll
  for (int jp = 0; jp < 2; ++jp) {
#pragma unroll
    for (int it = 0; it < 4; ++it) {
      int j = (jh2 * 4 + it) * 16 + jlo;           // 0..127
      int pp = g * GS + jp * 128 + j;
      int src = (pp < n_l) ? pp : (2 * n_l - 1 - pp);
      ushort4 vv = *reinterpret_cast<const ushort4*>(vbase + (size_t)src * DIMC + vd4 * 4);
      Vt[(vd4 * 4 + 0) * 136 + j] = vv.x;
      Vt[(vd4 * 4 + 1) * 136 + j] = vv.y;
      Vt[(vd4 * 4 + 2) * 136 + j] = vv.z;
      Vt[(vd4 * 4 + 3) * 136 + j] = vv.w;
    }
    __syncthreads();
    int kb2 = jp * 128;
#pragma unroll
    for (int ks = 0; ks < 4; ++ks) {
      bf16x8 a  = *reinterpret_cast<const bf16x8*>(&P_lds[(rf * 16 + frow) * 264 + kb2 + ks * 32 + fk]);
      bf16x8 b0 = *reinterpret_cast<const bf16x8*>(&Vt[(cf0 * 16 + frow) * 136 + ks * 32 + fk]);
      bf16x8 b1 = *reinterpret_cast<const bf16x8*>(&Vt[((cf0 + 1) * 16 + frow) * 136 + ks * 32 + fk]);
      oacc0 = __builtin_amdgcn_mfma_f32_16x16x32_bf16(a, b0, oacc0, 0, 0, 0);
      oacc1 = __builtin_amdgcn_mfma_f32_16x16x32_bf16(a, b1, oacc1, 0, 0, 0);
    }
    __syncthreads();
  }

  u16* obase = outp + ((size_t)b * n_l + (size_t)g * GS + p * 64 + rf * 16) * DIMC + h * DV;
#pragma unroll
  for (int rr = 0; rr < 4; ++rr) {
    int qrow = (lane >> 4) * 4 + rr;
    obase[(size_t)qrow * DIMC + cf0 * 16 + frow]       = f2b(oacc0[rr]);
    obase[(size_t)qrow * DIMC + (cf0 + 1) * 16 + frow] = f2b(oacc1[rr]);
  }
}

// ---------------------------------------------------------------------------
extern "C" void kernel_launch(void* const* d_in, const int* in_sizes, int n_in,
                              void* d_out, int out_size, void* d_ws, size_t ws_size,
                              hipStream_t stream) {
  (void)in_sizes; (void)n_in; (void)out_size; (void)ws_size;
  const float* x        = (const float*)d_in[0];
  const int*   labels   = (const int*)d_in[1];
  const float* scores   = (const float*)d_in[2];
  const int*   idx_last = (const int*)d_in[3];
  const float* Wq       = (const float*)d_in[4];
  const float* Wk       = (const float*)d_in[5];
  const float* Wv       = (const float*)d_in[6];
  const float* Wp       = (const float*)d_in[7];
  const float* betaL    = (const float*)d_in[8];
  float* out = (float*)d_out;

  char* w = (char*)d_ws;
  size_t off = 0;
  auto take = [&](size_t bytes) -> char* {
    char* p = w + off;
    off += (bytes + 255) & ~(size_t)255;
    return p;
  };
  float* qb    = (float*)take(33554432);   // q f32 (max 2*8192*512)
  float* kb    = (float*)take(33554432);   // k f32
  u16*   vbf   = (u16*)  take(16777216);   // v bf16
  u16*   xhi   = (u16*)  take(16777216);   // A hi / attn-out (disjoint lifetimes)
  u16*   xlo   = (u16*)  take(16777216);   // A lo
  u16*   attnA = (u16*)  take(16777216);   // lvl0 attn bf16
  u16*   attnB = (u16*)  take(33554432);   // lvl1 attn bf16
  u16*   wqhi  = (u16*)  take(524288);     // transposed+split weights
  u16*   wqlo  = (u16*)  take(524288);
  u16*   wkhi  = (u16*)  take(524288);
  u16*   wklo  = (u16*)  take(524288);
  u16*   wvhi  = (u16*)  take(524288);
  u16*   wphi  = (u16*)  take(524288);
  float* sl    = (float*)take(32768);
  int*   ll    = (int*)  take(32768);
  int*   keepb = (int*)  take(1024);
  // total ~163 MB

  const size_t wstride = (size_t)DIMC * DIMC;
  for (int lvl = 0; lvl < 3; ++lvl) {
    int scale = (lvl == 0) ? 4 : (lvl == 1) ? 2 : 1;
    int n_l = NTOK / scale;
    int ng  = n_l / GS;
    int M   = 2 * n_l;
    const int* lin; const float* sin_;
    if (scale > 1) {
      int tfeat = 2 * n_l * (DIMC / 4);
      pool_split_kernel<<<(tfeat + 255) / 256, 256, 0, stream>>>(x, scores, xhi, xlo, sl, NTOK, scale);
      pool_label_kernel<<<(2 * n_l + 255) / 256, 256, 0, stream>>>(labels, scores, ll, NTOK, scale);
      lin = ll; sin_ = sl;
    } else {
      asplit_kernel<<<(2 * NTOK * 128) / 256, 256, 0, stream>>>(x, xhi, xlo);
      lin = labels; sin_ = scores;
    }
    keep_kernel<<<(2 * ng + 127) / 128, 128, 0, stream>>>(lin, sin_, keepb, 2 * ng);

    wsplitT_kernel<<<256, 256, 0, stream>>>(Wq + lvl * wstride, wqhi, wqlo);
    wsplitT_kernel<<<256, 256, 0, stream>>>(Wk + lvl * wstride, wkhi, wklo);
    wsplitT_kernel<<<256, 256, 0, stream>>>(Wv + lvl * wstride, wvhi, nullptr);
    wsplitT_kernel<<<256, 256, 0, stream>>>(Wp + lvl * wstride, wphi, nullptr);

    dim3 gg(4, M / 128);
    mgemm_kernel<1, 0><<<gg, 256, 0, stream>>>(xhi, xlo, wqhi, wqlo, qb, nullptr, nullptr, M, 0, 0);
    mgemm_kernel<1, 0><<<gg, 256, 0, stream>>>(xhi, xlo, wkhi, wklo, kb, nullptr, nullptr, M, 0, 0);
    mgemm_kernel<0, 1><<<gg, 256, 0, stream>>>(xhi, nullptr, wvhi, nullptr, nullptr, vbf, nullptr, M, 0, 0);

    const u16* prev = (lvl == 0) ? nullptr : ((lvl == 1) ? attnA : attnB);
    u16* cur = (lvl == 0) ? attnA : ((lvl == 1) ? attnB : nullptr);
    // attn output reuses xhi (A-side dead after the three GEMMs above)
    attn_fused_kernel<<<2 * ng * 8 * 2, 512, 0, stream>>>(qb, kb, vbf, keepb, prev, cur,
                                                          betaL, xhi, lvl, n_l, ng, ng / 2);

    if (lvl == 0)
      mgemm_kernel<0, 2><<<gg, 256, 0, stream>>>(xhi, nullptr, wphi, nullptr, out, nullptr, idx_last, M, scale, n_l);
    else
      mgemm_kernel<0, 3><<<gg, 256, 0, stream>>>(xhi, nullptr, wphi, nullptr, out, nullptr, idx_last, M, scale, n_l);
  }
}

// Round 9
// 723.892 us; speedup vs baseline: 1.8973x; 1.0240x over previous
//
#include <hip/hip_runtime.h>
#include <math.h>

// ---------------------------------------------------------------------------
// LowToHighMultiLevelReconstruction — round 9.
// Change vs round 8: mgemm staging via __builtin_amdgcn_global_load_lds
// (width 16, async global->LDS, no VGPR roundtrip, no staging VALU).
// LDS tiles unpadded [128][32] u16 so the wave-linear LDS dest matches
// (wave base + lane*16). MFMA operand values bit-identical -> absmax
// unchanged. Attention kernel untouched.
// ---------------------------------------------------------------------------

#define GS   128
#define WIN  256        // 2*GS
#define DQK  64
#define DV   64
#define DIMC 512
#define NTOK 8192

typedef unsigned long long u64;
typedef unsigned short u16;
typedef __attribute__((ext_vector_type(8))) short bf16x8;
typedef __attribute__((ext_vector_type(4))) float f32x4;

__device__ __forceinline__ u16 f2b(float f) {     // f32 -> bf16 RNE
  unsigned u = __float_as_uint(f);
  u = (u + 0x7fffu + ((u >> 16) & 1u)) >> 16;
  return (u16)u;
}
__device__ __forceinline__ float b2f(u16 h) { return __uint_as_float(((unsigned)h) << 16); }
__device__ __forceinline__ float b2f_lo(unsigned u) { return __uint_as_float(u << 16); }
__device__ __forceinline__ float b2f_hi(unsigned u) { return __uint_as_float(u & 0xffff0000u); }

__device__ __forceinline__ float wave_max64(float v) {
#pragma unroll
  for (int m = 1; m < 64; m <<= 1) v = fmaxf(v, __shfl_xor(v, m, 64));
  return v;
}
__device__ __forceinline__ float wave_sum64(float v) {
#pragma unroll
  for (int m = 1; m < 64; m <<= 1) v += __shfl_xor(v, m, 64);
  return v;
}

// --------------------------------------------- pooling (writes split bf16) --
__global__ void pool_split_kernel(const float* __restrict__ x,
                                  const float* __restrict__ scores,
                                  u16* __restrict__ xhi, u16* __restrict__ xlo,
                                  float* __restrict__ sl, int n, int scale) {
  int npool = n / scale;
  int total = 2 * npool * (DIMC / 4);
  int tid = blockIdx.x * blockDim.x + threadIdx.x;
  if (tid >= total) return;
  int c4 = tid & 127;
  int g  = (tid >> 7) % npool;
  int b  = (tid >> 7) / npool;
  const float* xp = x + ((size_t)b * n + (size_t)g * scale) * DIMC + c4 * 4;
  float ax = 0.f, ay = 0.f, az = 0.f, aw = 0.f, wsum = 0.f, ssum = 0.f;
  for (int s = 0; s < scale; ++s) {
    float sc = scores[(size_t)b * n + (size_t)g * scale + s];
    float w  = fmaxf(sc, 1e-6f);
    float4 xv = *reinterpret_cast<const float4*>(xp + (size_t)s * DIMC);
    ax += xv.x * w; ay += xv.y * w; az += xv.z * w; aw += xv.w * w;
    wsum += w; ssum += sc;
  }
  float o[4] = { ax / wsum, ay / wsum, az / wsum, aw / wsum };
  ushort4 h, l;
  h.x = f2b(o[0]); h.y = f2b(o[1]); h.z = f2b(o[2]); h.w = f2b(o[3]);
  l.x = f2b(o[0] - b2f(h.x)); l.y = f2b(o[1] - b2f(h.y));
  l.z = f2b(o[2] - b2f(h.z)); l.w = f2b(o[3] - b2f(h.w));
  size_t off = ((size_t)b * npool + g) * DIMC + c4 * 4;
  *reinterpret_cast<ushort4*>(xhi + off) = h;
  *reinterpret_cast<ushort4*>(xlo + off) = l;
  if (c4 == 0) sl[(size_t)b * npool + g] = ssum / (float)scale;
}

// --------------------------------------------------- raw x split (lvl 2) ----
__global__ void asplit_kernel(const float* __restrict__ x,
                              u16* __restrict__ xhi, u16* __restrict__ xlo) {
  int tid = blockIdx.x * 256 + threadIdx.x;     // over 2*NTOK*128 float4s
  float4 v = *reinterpret_cast<const float4*>(x + (size_t)tid * 4);
  ushort4 h, l;
  h.x = f2b(v.x); h.y = f2b(v.y); h.z = f2b(v.z); h.w = f2b(v.w);
  l.x = f2b(v.x - b2f(h.x)); l.y = f2b(v.y - b2f(h.y));
  l.z = f2b(v.z - b2f(h.z)); l.w = f2b(v.w - b2f(h.w));
  *reinterpret_cast<ushort4*>(xhi + (size_t)tid * 4) = h;
  *reinterpret_cast<ushort4*>(xlo + (size_t)tid * 4) = l;
}

__global__ void pool_label_kernel(const int* __restrict__ labels,
                                  const float* __restrict__ scores,
                                  int* __restrict__ ll, int n, int scale) {
  int npool = n / scale;
  int tid = blockIdx.x * blockDim.x + threadIdx.x;
  if (tid >= 2 * npool) return;
  int b = tid / npool, g = tid % npool;
  float counts[4] = {0.f, 0.f, 0.f, 0.f};
  float ssum[4]   = {0.f, 0.f, 0.f, 0.f};
  int firstp[4];
  for (int c = 0; c < 4; ++c) firstp[c] = scale;
  for (int s = 0; s < scale; ++s) {
    int   L = labels[(size_t)b * n + (size_t)g * scale + s];
    float S = scores[(size_t)b * n + (size_t)g * scale + s];
    counts[L] += 1.0f;
    ssum[L]   += S;
    if (s < firstp[L]) firstp[L] = s;
  }
  float cmax = fmaxf(fmaxf(counts[0], counts[1]), fmaxf(counts[2], counts[3]));
  float s2[4];
  for (int c = 0; c < 4; ++c) s2[c] = (counts[c] == cmax) ? ssum[c] : -1e9f;
  float smax = fmaxf(fmaxf(s2[0], s2[1]), fmaxf(s2[2], s2[3]));
  int fp[4];
  for (int c = 0; c < 4; ++c) fp[c] = (s2[c] == smax) ? firstp[c] : scale;
  int best = 0, bv = fp[0];
  for (int c = 1; c < 4; ++c) if (fp[c] < bv) { bv = fp[c]; best = c; }
  ll[(size_t)b * npool + g] = best;
}

// ------------------------------------------------------------ keep (focus) --
__global__ void keep_kernel(const int* __restrict__ ll, const float* __restrict__ sl,
                            int* __restrict__ keep, int total) {
  int tid = blockIdx.x * blockDim.x + threadIdx.x;
  if (tid >= total) return;
  const int*   lp = ll + (size_t)tid * GS;
  const float* sp = sl + (size_t)tid * GS;
  float counts[4] = {0.f, 0.f, 0.f, 0.f};
  for (int i = 0; i < GS; ++i) counts[lp[i]] += 1.f;
  int mode = 0; float bv = counts[0];
  for (int c = 1; c < 4; ++c) if (counts[c] > bv) { bv = counts[c]; mode = c; }
  float pm = 0.f, mean = 0.f;
  for (int i = 0; i < GS; ++i) { pm += (lp[i] == mode) ? 1.f : 0.f; mean += sp[i]; }
  float purity = pm / (float)GS;
  mean /= (float)GS;
  float var = 0.f;
  for (int i = 0; i < GS; ++i) { float d = sp[i] - mean; var += d * d; }
  var /= (float)GS;
  float focus = 0.5f + 0.25f * purity - 0.25f * var;
  focus = fminf(fmaxf(focus, 0.25f), 0.75f);
  keep[tid] = (int)ceilf(focus * (float)WIN);
}

// ------------------------------------------- weight transpose + bf16 split --
__global__ __launch_bounds__(256) void wsplitT_kernel(const float* __restrict__ W,
                                                      u16* __restrict__ bthi,
                                                      u16* __restrict__ btlo) {
  __shared__ float tile[32][33];
  int bx = blockIdx.x & 15;        // n block
  int by = blockIdx.x >> 4;        // k block
  int tx = threadIdx.x & 31;
  int ty = threadIdx.x >> 5;       // 0..7
#pragma unroll
  for (int i = 0; i < 4; ++i) {
    int kk = ty + i * 8;
    tile[kk][tx] = W[(size_t)(by * 32 + kk) * 512 + bx * 32 + tx];
  }
  __syncthreads();
#pragma unroll
  for (int i = 0; i < 4; ++i) {
    int nn = ty + i * 8;
    float v = tile[tx][nn];        // = W[by*32+tx][bx*32+nn]
    u16 h = f2b(v);
    size_t o = (size_t)(bx * 32 + nn) * 512 + by * 32 + tx;
    bthi[o] = h;
    if (btlo) btlo[o] = f2b(v - b2f(h));
  }
}

// ------------------------------------------------------- MFMA split GEMM ----
// C(MxN=512) = A(Mx512, pre-split bf16 hi/lo) @ W(512x512).
// Staging via global_load_lds (async, wave-linear LDS dest, unpadded [128][32]).
// SPLIT=1: 3-product split (q,k). SPLIT=0: hi-only (v, wp).
// EMODE 0: f32 store C. 1: bf16 store Cb. 2: scatter via idx. 3: scatter +=.
template<int SPLIT, int EMODE>
__global__ __launch_bounds__(256) void mgemm_kernel(
    const u16* __restrict__ Ahi, const u16* __restrict__ Alo,
    const u16* __restrict__ Bthi, const u16* __restrict__ Btlo,
    float* __restrict__ C, u16* __restrict__ Cb, const int* __restrict__ idx,
    int M, int scale, int n_l) {
  __shared__ u16 smem[SPLIT ? 4 * 4096 : 2 * 4096];   // [128][32] tiles
  u16* sAhi = smem;
  u16* sBhi = smem + 4096;
  u16* sAlo = SPLIT ? smem + 2 * 4096 : smem;
  u16* sBlo = SPLIT ? smem + 3 * 4096 : smem;

  int t = threadIdx.x, lane = t & 63, wave = t >> 6;
  int wr = wave >> 1, wc = wave & 1;
  int row0 = blockIdx.y * 128, col0 = blockIdx.x * 128;

  // per-lane staging geometry: wave w covers rows w*32 + j*16 + (lane>>2),
  // chunk (lane&3)*8 u16 (16B). LDS dest is wave-uniform base + lane*16.
  int srow = (lane >> 2);
  int schk = (lane & 3) * 8;

  const f32x4 zero = { 0.f, 0.f, 0.f, 0.f };
  f32x4 acc[4][4];
#pragma unroll
  for (int i = 0; i < 4; ++i)
#pragma unroll
    for (int j = 0; j < 4; ++j) acc[i][j] = zero;

  for (int k0 = 0; k0 < 512; k0 += 32) {
#pragma unroll
    for (int j = 0; j < 2; ++j) {
      int r = wave * 32 + j * 16 + srow;
      const u16* gA = Ahi + (size_t)(row0 + r) * 512 + k0 + schk;
      const u16* gB = Bthi + (size_t)(col0 + r) * 512 + k0 + schk;
      __builtin_amdgcn_global_load_lds(
          (const __attribute__((address_space(1))) void*)gA,
          (__attribute__((address_space(3))) void*)&sAhi[(wave * 32 + j * 16) * 32],
          16, 0, 0);
      __builtin_amdgcn_global_load_lds(
          (const __attribute__((address_space(1))) void*)gB,
          (__attribute__((address_space(3))) void*)&sBhi[(wave * 32 + j * 16) * 32],
          16, 0, 0);
      if (SPLIT) {
        const u16* gAl = Alo + (size_t)(row0 + r) * 512 + k0 + schk;
        const u16* gBl = Btlo + (size_t)(col0 + r) * 512 + k0 + schk;
        __builtin_amdgcn_global_load_lds(
            (const __attribute__((address_space(1))) void*)gAl,
            (__attribute__((address_space(3))) void*)&sAlo[(wave * 32 + j * 16) * 32],
            16, 0, 0);
        __builtin_amdgcn_global_load_lds(
            (const __attribute__((address_space(1))) void*)gBl,
            (__attribute__((address_space(3))) void*)&sBlo[(wave * 32 + j * 16) * 32],
            16, 0, 0);
      }
    }
    __syncthreads();   // drains vmcnt (global_load_lds) + barrier

    int fr = lane & 15;
    int kf = (lane >> 4) * 8;
    bf16x8 ah[4], bh[4], al[4], bl[4];
#pragma unroll
    for (int i = 0; i < 4; ++i) {
      ah[i] = *reinterpret_cast<const bf16x8*>(&sAhi[(wr * 64 + i * 16 + fr) * 32 + kf]);
      bh[i] = *reinterpret_cast<const bf16x8*>(&sBhi[(wc * 64 + i * 16 + fr) * 32 + kf]);
      if (SPLIT) {
        al[i] = *reinterpret_cast<const bf16x8*>(&sAlo[(wr * 64 + i * 16 + fr) * 32 + kf]);
        bl[i] = *reinterpret_cast<const bf16x8*>(&sBlo[(wc * 64 + i * 16 + fr) * 32 + kf]);
      }
    }
#pragma unroll
    for (int i = 0; i < 4; ++i)
#pragma unroll
      for (int j = 0; j < 4; ++j) {
        acc[i][j] = __builtin_amdgcn_mfma_f32_16x16x32_bf16(ah[i], bh[j], acc[i][j], 0, 0, 0);
        if (SPLIT) {
          acc[i][j] = __builtin_amdgcn_mfma_f32_16x16x32_bf16(ah[i], bl[j], acc[i][j], 0, 0, 0);
          acc[i][j] = __builtin_amdgcn_mfma_f32_16x16x32_bf16(al[i], bh[j], acc[i][j], 0, 0, 0);
        }
      }
    __syncthreads();   // all frag reads done before next stage overwrites
  }

  int ccol = col0 + wc * 64 + (lane & 15);
  int crow = row0 + wr * 64 + (lane >> 4) * 4;
#pragma unroll
  for (int i = 0; i < 4; ++i) {
#pragma unroll
    for (int r = 0; r < 4; ++r) {
      int gr = crow + i * 16 + r;
      if (EMODE == 0) {
#pragma unroll
        for (int j = 0; j < 4; ++j)
          C[(size_t)gr * 512 + ccol + j * 16] = acc[i][j][r];
      } else if (EMODE == 1) {
#pragma unroll
        for (int j = 0; j < 4; ++j)
          Cb[(size_t)gr * 512 + ccol + j * 16] = f2b(acc[i][j][r]);
      } else {
        int bb = gr / n_l, rr = gr - bb * n_l;
        for (int s = 0; s < scale; ++s) {
          int dst = idx[(size_t)bb * NTOK + (size_t)rr * scale + s];
          float* p = C + ((size_t)bb * NTOK + dst) * 512 + ccol;
          if (EMODE == 3) {
#pragma unroll
            for (int j = 0; j < 4; ++j) p[j * 16] += acc[i][j][r];
          } else {
#pragma unroll
            for (int j = 0; j < 4; ++j) p[j * 16] = acc[i][j][r];
          }
        }
      }
    }
  }
}

// ----------------------------------------------- fused windowed attention ---
// TWO blocks (512 thr, 8 waves) per (b,g,h), each owns 64 q-rows (p=bid&1).
// Phase A: sim in 2 d-halves (qT/kT f32, VALU — bit-identical ranking).
// Ballot top-k -> softmax -> prior mix; P kept packed bf16 in regs (atp).
// Phase B: PV via MFMA; output written as bf16-hi (Wp GEMM is hi-only).
__global__ __launch_bounds__(512) void attn_fused_kernel(
    const float* __restrict__ q, const float* __restrict__ k,
    const u16* __restrict__ vbf, const int* __restrict__ keepArr,
    const u16* __restrict__ prevA, u16* __restrict__ curA,
    const float* __restrict__ betaL, u16* __restrict__ outp,
    int lvl, int n_l, int ng, int prev_ng) {
  __shared__ u64 smem8[6400];             // 51200 B
  float* qT    = (float*)smem8;           // [32][68]   (d, qi<64)     phase A
  float* kT    = qT + 32 * 68;            // [32][260]  (d, j<256)     phase A
  u16*   P_lds = (u16*)smem8;             // [64][264]  (q row, key)   phase B
  u16*   Vt    = (u16*)smem8 + 16896;     // [64][136]  (dv, k-half)   phase B

  int t = threadIdx.x;
  int lane = t & 63, wave = t >> 6;
  int bid = blockIdx.x;
  int p   = bid & 1;
  int h   = (bid >> 1) & 7;
  int gl  = bid >> 4;
  int g   = gl % ng;
  int b   = gl / ng;
  int bgh = bid >> 1;                     // (b,g,h) index for attn state

  const float* qbase = q + ((size_t)b * n_l + (size_t)g * GS + p * 64) * DIMC + h * DQK;
  const float* kbase = k + (size_t)b * n_l * DIMC + h * DQK;

  // ---- sim over two d-halves; acc identical to full-d accumulation ----
  float acc[8][4] = {};
#pragma unroll
  for (int dp = 0; dp < 2; ++dp) {
    int d0 = dp * 32;
    {  // qT: 64 qi x 8 d4 chunks = 512
      int qi = t >> 3, d4 = t & 7;
      float4 vv = *reinterpret_cast<const float4*>(qbase + (size_t)qi * DIMC + d0 + d4 * 4);
      qT[(d4 * 4 + 0) * 68 + qi] = vv.x;
      qT[(d4 * 4 + 1) * 68 + qi] = vv.y;
      qT[(d4 * 4 + 2) * 68 + qi] = vv.z;
      qT[(d4 * 4 + 3) * 68 + qi] = vv.w;
    }
#pragma unroll
    for (int it = 0; it < 4; ++it) {      // kT: 256 j x 8 d4 chunks
      int idx = it * 512 + t;
      int j = idx >> 3, d4 = idx & 7;
      int pp = g * GS + j;
      int src = (pp < n_l) ? pp : (2 * n_l - 1 - pp);
      float4 vv = *reinterpret_cast<const float4*>(kbase + (size_t)src * DIMC + d0 + d4 * 4);
      kT[(d4 * 4 + 0) * 260 + j] = vv.x;
      kT[(d4 * 4 + 1) * 260 + j] = vv.y;
      kT[(d4 * 4 + 2) * 260 + j] = vv.z;
      kT[(d4 * 4 + 3) * 260 + j] = vv.w;
    }
    __syncthreads();
#pragma unroll 2
    for (int d = 0; d < 32; ++d) {
      float ra[8], rb4[4];
      *reinterpret_cast<float4*>(&ra[0]) = *reinterpret_cast<const float4*>(&qT[d * 68 + wave * 8 + 0]);
      *reinterpret_cast<float4*>(&ra[4]) = *reinterpret_cast<const float4*>(&qT[d * 68 + wave * 8 + 4]);
      *reinterpret_cast<float4*>(&rb4[0]) = *reinterpret_cast<const float4*>(&kT[d * 260 + lane * 4]);
#pragma unroll
      for (int i = 0; i < 8; ++i)
#pragma unroll
        for (int j = 0; j < 4; ++j) acc[i][j] += ra[i] * rb4[j];
    }
    __syncthreads();
  }

  int kp = keepArr[b * ng + g];
  float beta = 0.f, wgt = 0.f;
  int lo = 0, hi = 0;
  if (lvl > 0) {
    beta = 1.f / (1.f + expf(-betaL[lvl]));
    float pos = ((float)g + 0.5f) * ((float)prev_ng / (float)ng) - 0.5f;
    float fl = floorf(pos);
    lo = (int)fl;
    if (lo < 0) lo = 0;
    if (lo > prev_ng - 1) lo = prev_ng - 1;
    hi = lo + 1; if (hi > prev_ng - 1) hi = prev_ng - 1;
    wgt = fminf(fmaxf(pos - fl, 0.f), 1.f);
  }
  u64 lmask = (1ull << lane) - 1ull;

  // ---- per-row: ballot top-k -> softmax -> prior mix; retain packed bf16 ---
  unsigned atp[8][2];
#pragma unroll
  for (int r = 0; r < 8; ++r) {
    int i = p * 64 + wave * 8 + r;        // row within the 128-row group
    float sv[4];
    unsigned um[4];
#pragma unroll
    for (int e = 0; e < 4; ++e) {
      sv[e] = acc[r][e] * 0.125f;
      unsigned u = __float_as_uint(sv[e]);
      um[e] = (u & 0x80000000u) ? ~u : (u | 0x80000000u);
    }
    unsigned T = 0u;
    for (int bit = 31; bit >= 0; --bit) {
      unsigned T2 = T | (1u << bit);
      int c = __popcll(__ballot(um[0] >= T2)) + __popcll(__ballot(um[1] >= T2))
            + __popcll(__ballot(um[2] >= T2)) + __popcll(__ballot(um[3] >= T2));
      if (c >= kp) T = T2;
    }
    int c_gt = __popcll(__ballot(um[0] > T)) + __popcll(__ballot(um[1] > T))
             + __popcll(__ballot(um[2] > T)) + __popcll(__ballot(um[3] > T));
    u64 beq[4];
#pragma unroll
    for (int e = 0; e < 4; ++e) beq[e] = __ballot(um[e] == T);
    int trbase = __popcll(beq[0] & lmask) + __popcll(beq[1] & lmask)
               + __popcll(beq[2] & lmask) + __popcll(beq[3] & lmask);
    int need = kp - c_gt;
    bool msk[4];
    int own = 0;
#pragma unroll
    for (int e = 0; e < 4; ++e) {
      bool eq = (um[e] == T);
      msk[e] = (um[e] > T) || (eq && (trbase + own) < need);
      own += eq ? 1 : 0;
    }
    float m = -3.0e38f;
#pragma unroll
    for (int e = 0; e < 4; ++e) if (msk[e]) m = fmaxf(m, sv[e]);
    m = wave_max64(m);
    float ez[4], zs = 0.f;
#pragma unroll
    for (int e = 0; e < 4; ++e) { ez[e] = msk[e] ? __expf(sv[e] - m) : 0.f; zs += ez[e]; }
    zs = wave_sum64(zs);
    float at[4];
#pragma unroll
    for (int e = 0; e < 4; ++e) at[e] = ez[e] / zs;
    if (lvl > 0) {
      size_t baseLo = ((((size_t)b * prev_ng + lo) * 8 + h) * GS + i) * WIN + lane * 4;
      size_t baseHi = ((((size_t)b * prev_ng + hi) * 8 + h) * GS + i) * WIN + lane * 4;
      uint2 rlo = *reinterpret_cast<const uint2*>(prevA + baseLo);
      uint2 rhi = *reinterpret_cast<const uint2*>(prevA + baseHi);
      float pl[4] = { b2f_lo(rlo.x), b2f_hi(rlo.x), b2f_lo(rlo.y), b2f_hi(rlo.y) };
      float ph[4] = { b2f_lo(rhi.x), b2f_hi(rhi.x), b2f_lo(rhi.y), b2f_hi(rhi.y) };
      float pr[4], ps = 0.f;
#pragma unroll
      for (int e = 0; e < 4; ++e) {
        pr[e] = fmaxf((1.f - wgt) * pl[e] + wgt * ph[e], 0.f);
        ps += pr[e];
      }
      ps = wave_sum64(ps) + 1e-9f;
#pragma unroll
      for (int e = 0; e < 4; ++e) at[e] = (1.f - beta) * at[e] + beta * (pr[e] / ps);
    }
    atp[r][0] = (unsigned)f2b(at[0]) | ((unsigned)f2b(at[1]) << 16);
    atp[r][1] = (unsigned)f2b(at[2]) | ((unsigned)f2b(at[3]) << 16);
    if (curA != nullptr) {
      uint2 o = { atp[r][0], atp[r][1] };
      *reinterpret_cast<uint2*>(curA + ((size_t)bgh * GS + i) * WIN + lane * 4) = o;
    }
  }

  // ---- PV via MFMA: O(64x64) = P(64x256) @ V(256x64) ----
#pragma unroll
  for (int r = 0; r < 8; ++r) {
    uint2 o = { atp[r][0], atp[r][1] };
    *reinterpret_cast<uint2*>(&P_lds[(wave * 8 + r) * 264 + lane * 4]) = o;
  }

  const u16* vbase = vbf + (size_t)b * n_l * DIMC + h * DV;
  int rf   = wave >> 1;                  // q-row frag 0..3
  int cf0  = (wave & 1) * 2;             // dv col frag base {0,2}
  int frow = lane & 15;
  int fk   = (lane >> 4) * 8;
  f32x4 oacc0 = { 0.f, 0.f, 0.f, 0.f };
  f32x4 oacc1 = { 0.f, 0.f, 0.f, 0.f };
  int jlo = t & 15, vd4 = (t >> 4) & 15, jh2 = t >> 8;

#pragma unroll
  for (int jp = 0; jp < 2; ++jp) {
#pragma unroll
    for (int it = 0; it < 4; ++it) {
      int j = (jh2 * 4 + it) * 16 + jlo;           // 0..127
      int pp = g * GS + jp * 128 + j;
      int src = (pp < n_l) ? pp : (2 * n_l - 1 - pp);
      ushort4 vv = *reinterpret_cast<const ushort4*>(vbase + (size_t)src * DIMC + vd4 * 4);
      Vt[(vd4 * 4 + 0) * 136 + j] = vv.x;
      Vt[(vd4 * 4 + 1) * 136 + j] = vv.y;
      Vt[(vd4 * 4 + 2) * 136 + j] = vv.z;
      Vt[(vd4 * 4 + 3) * 136 + j] = vv.w;
    }
    __syncthreads();
    int kb2 = jp * 128;
#pragma unroll
    for (int ks = 0; ks < 4; ++ks) {
      bf16x8 a  = *reinterpret_cast<const bf16x8*>(&P_lds[(rf * 16 + frow) * 264 + kb2 + ks * 32 + fk]);
      bf16x8 b0 = *reinterpret_cast<const bf16x8*>(&Vt[(cf0 * 16 + frow) * 136 + ks * 32 + fk]);
      bf16x8 b1 = *reinterpret_cast<const bf16x8*>(&Vt[((cf0 + 1) * 16 + frow) * 136 + ks * 32 + fk]);
      oacc0 = __builtin_amdgcn_mfma_f32_16x16x32_bf16(a, b0, oacc0, 0, 0, 0);
      oacc1 = __builtin_amdgcn_mfma_f32_16x16x32_bf16(a, b1, oacc1, 0, 0, 0);
    }
    __syncthreads();
  }

  u16* obase = outp + ((size_t)b * n_l + (size_t)g * GS + p * 64 + rf * 16) * DIMC + h * DV;
#pragma unroll
  for (int rr = 0; rr < 4; ++rr) {
    int qrow = (lane >> 4) * 4 + rr;
    obase[(size_t)qrow * DIMC + cf0 * 16 + frow]       = f2b(oacc0[rr]);
    obase[(size_t)qrow * DIMC + (cf0 + 1) * 16 + frow] = f2b(oacc1[rr]);
  }
}

// ---------------------------------------------------------------------------
extern "C" void kernel_launch(void* const* d_in, const int* in_sizes, int n_in,
                              void* d_out, int out_size, void* d_ws, size_t ws_size,
                              hipStream_t stream) {
  (void)in_sizes; (void)n_in; (void)out_size; (void)ws_size;
  const float* x        = (const float*)d_in[0];
  const int*   labels   = (const int*)d_in[1];
  const float* scores   = (const float*)d_in[2];
  const int*   idx_last = (const int*)d_in[3];
  const float* Wq       = (const float*)d_in[4];
  const float* Wk       = (const float*)d_in[5];
  const float* Wv       = (const float*)d_in[6];
  const float* Wp       = (const float*)d_in[7];
  const float* betaL    = (const float*)d_in[8];
  float* out = (float*)d_out;

  char* w = (char*)d_ws;
  size_t off = 0;
  auto take = [&](size_t bytes) -> char* {
    char* p = w + off;
    off += (bytes + 255) & ~(size_t)255;
    return p;
  };
  float* qb    = (float*)take(33554432);   // q f32 (max 2*8192*512)
  float* kb    = (float*)take(33554432);   // k f32
  u16*   vbf   = (u16*)  take(16777216);   // v bf16
  u16*   xhi   = (u16*)  take(16777216);   // A hi / attn-out (disjoint lifetimes)
  u16*   xlo   = (u16*)  take(16777216);   // A lo
  u16*   attnA = (u16*)  take(16777216);   // lvl0 attn bf16
  u16*   attnB = (u16*)  take(33554432);   // lvl1 attn bf16
  u16*   wqhi  = (u16*)  take(524288);     // transposed+split weights
  u16*   wqlo  = (u16*)  take(524288);
  u16*   wkhi  = (u16*)  take(524288);
  u16*   wklo  = (u16*)  take(524288);
  u16*   wvhi  = (u16*)  take(524288);
  u16*   wphi  = (u16*)  take(524288);
  float* sl    = (float*)take(32768);
  int*   ll    = (int*)  take(32768);
  int*   keepb = (int*)  take(1024);
  // total ~163 MB

  const size_t wstride = (size_t)DIMC * DIMC;
  for (int lvl = 0; lvl < 3; ++lvl) {
    int scale = (lvl == 0) ? 4 : (lvl == 1) ? 2 : 1;
    int n_l = NTOK / scale;
    int ng  = n_l / GS;
    int M   = 2 * n_l;
    const int* lin; const float* sin_;
    if (scale > 1) {
      int tfeat = 2 * n_l * (DIMC / 4);
      pool_split_kernel<<<(tfeat + 255) / 256, 256, 0, stream>>>(x, scores, xhi, xlo, sl, NTOK, scale);
      pool_label_kernel<<<(2 * n_l + 255) / 256, 256, 0, stream>>>(labels, scores, ll, NTOK, scale);
      lin = ll; sin_ = sl;
    } else {
      asplit_kernel<<<(2 * NTOK * 128) / 256, 256, 0, stream>>>(x, xhi, xlo);
      lin = labels; sin_ = scores;
    }
    keep_kernel<<<(2 * ng + 127) / 128, 128, 0, stream>>>(lin, sin_, keepb, 2 * ng);

    wsplitT_kernel<<<256, 256, 0, stream>>>(Wq + lvl * wstride, wqhi, wqlo);
    wsplitT_kernel<<<256, 256, 0, stream>>>(Wk + lvl * wstride, wkhi, wklo);
    wsplitT_kernel<<<256, 256, 0, stream>>>(Wv + lvl * wstride, wvhi, nullptr);
    wsplitT_kernel<<<256, 256, 0, stream>>>(Wp + lvl * wstride, wphi, nullptr);

    dim3 gg(4, M / 128);
    mgemm_kernel<1, 0><<<gg, 256, 0, stream>>>(xhi, xlo, wqhi, wqlo, qb, nullptr, nullptr, M, 0, 0);
    mgemm_kernel<1, 0><<<gg, 256, 0, stream>>>(xhi, xlo, wkhi, wklo, kb, nullptr, nullptr, M, 0, 0);
    mgemm_kernel<0, 1><<<gg, 256, 0, stream>>>(xhi, nullptr, wvhi, nullptr, nullptr, vbf, nullptr, M, 0, 0);

    const u16* prev = (lvl == 0) ? nullptr : ((lvl == 1) ? attnA : attnB);
    u16* cur = (lvl == 0) ? attnA : ((lvl == 1) ? attnB : nullptr);
    // attn output reuses xhi (A-side dead after the three GEMMs above)
    attn_fused_kernel<<<2 * ng * 8 * 2, 512, 0, stream>>>(qb, kb, vbf, keepb, prev, cur,
                                                          betaL, xhi, lvl, n_l, ng, ng / 2);

    if (lvl == 0)
      mgemm_kernel<0, 2><<<gg, 256, 0, stream>>>(xhi, nullptr, wphi, nullptr, out, nullptr, idx_last, M, scale, n_l);
    else
      mgemm_kernel<0, 3><<<gg, 256, 0, stream>>>(xhi, nullptr, wphi, nullptr, out, nullptr, idx_last, M, scale, n_l);
  }
}

// Round 10
// 637.494 us; speedup vs baseline: 2.1544x; 1.1355x over previous
//
#include <hip/hip_runtime.h>
#include <math.h>

// ---------------------------------------------------------------------------
// LowToHighMultiLevelReconstruction — round 10.
// Change vs round 9 (no numeric changes; absmax must stay bit-identical):
//  1. q/k/v GEMMs fused into ONE qkv_gemm launch (grid (12, M/128)) —
//     3x resident blocks for the projection phase, 2 fewer launches/level.
//  2. All 12 weight transpose+split tiles hoisted into ONE wprep launch
//     before the level loop (weights are loop-invariant).
//  Launch count 36 -> 17.
// ---------------------------------------------------------------------------

#define GS   128
#define WIN  256        // 2*GS
#define DQK  64
#define DV   64
#define DIMC 512
#define NTOK 8192
#define WSZ  262144     // 512*512 elements per weight matrix

typedef unsigned long long u64;
typedef unsigned short u16;
typedef __attribute__((ext_vector_type(8))) short bf16x8;
typedef __attribute__((ext_vector_type(4))) float f32x4;

__device__ __forceinline__ u16 f2b(float f) {     // f32 -> bf16 RNE
  unsigned u = __float_as_uint(f);
  u = (u + 0x7fffu + ((u >> 16) & 1u)) >> 16;
  return (u16)u;
}
__device__ __forceinline__ float b2f(u16 h) { return __uint_as_float(((unsigned)h) << 16); }
__device__ __forceinline__ float b2f_lo(unsigned u) { return __uint_as_float(u << 16); }
__device__ __forceinline__ float b2f_hi(unsigned u) { return __uint_as_float(u & 0xffff0000u); }

__device__ __forceinline__ float wave_max64(float v) {
#pragma unroll
  for (int m = 1; m < 64; m <<= 1) v = fmaxf(v, __shfl_xor(v, m, 64));
  return v;
}
__device__ __forceinline__ float wave_sum64(float v) {
#pragma unroll
  for (int m = 1; m < 64; m <<= 1) v += __shfl_xor(v, m, 64);
  return v;
}

// --------------------------------------------- pooling (writes split bf16) --
__global__ void pool_split_kernel(const float* __restrict__ x,
                                  const float* __restrict__ scores,
                                  u16* __restrict__ xhi, u16* __restrict__ xlo,
                                  float* __restrict__ sl, int n, int scale) {
  int npool = n / scale;
  int total = 2 * npool * (DIMC / 4);
  int tid = blockIdx.x * blockDim.x + threadIdx.x;
  if (tid >= total) return;
  int c4 = tid & 127;
  int g  = (tid >> 7) % npool;
  int b  = (tid >> 7) / npool;
  const float* xp = x + ((size_t)b * n + (size_t)g * scale) * DIMC + c4 * 4;
  float ax = 0.f, ay = 0.f, az = 0.f, aw = 0.f, wsum = 0.f, ssum = 0.f;
  for (int s = 0; s < scale; ++s) {
    float sc = scores[(size_t)b * n + (size_t)g * scale + s];
    float w  = fmaxf(sc, 1e-6f);
    float4 xv = *reinterpret_cast<const float4*>(xp + (size_t)s * DIMC);
    ax += xv.x * w; ay += xv.y * w; az += xv.z * w; aw += xv.w * w;
    wsum += w; ssum += sc;
  }
  float o[4] = { ax / wsum, ay / wsum, az / wsum, aw / wsum };
  ushort4 h, l;
  h.x = f2b(o[0]); h.y = f2b(o[1]); h.z = f2b(o[2]); h.w = f2b(o[3]);
  l.x = f2b(o[0] - b2f(h.x)); l.y = f2b(o[1] - b2f(h.y));
  l.z = f2b(o[2] - b2f(h.z)); l.w = f2b(o[3] - b2f(h.w));
  size_t off = ((size_t)b * npool + g) * DIMC + c4 * 4;
  *reinterpret_cast<ushort4*>(xhi + off) = h;
  *reinterpret_cast<ushort4*>(xlo + off) = l;
  if (c4 == 0) sl[(size_t)b * npool + g] = ssum / (float)scale;
}

// --------------------------------------------------- raw x split (lvl 2) ----
__global__ void asplit_kernel(const float* __restrict__ x,
                              u16* __restrict__ xhi, u16* __restrict__ xlo) {
  int tid = blockIdx.x * 256 + threadIdx.x;     // over 2*NTOK*128 float4s
  float4 v = *reinterpret_cast<const float4*>(x + (size_t)tid * 4);
  ushort4 h, l;
  h.x = f2b(v.x); h.y = f2b(v.y); h.z = f2b(v.z); h.w = f2b(v.w);
  l.x = f2b(v.x - b2f(h.x)); l.y = f2b(v.y - b2f(h.y));
  l.z = f2b(v.z - b2f(h.z)); l.w = f2b(v.w - b2f(h.w));
  *reinterpret_cast<ushort4*>(xhi + (size_t)tid * 4) = h;
  *reinterpret_cast<ushort4*>(xlo + (size_t)tid * 4) = l;
}

__global__ void pool_label_kernel(const int* __restrict__ labels,
                                  const float* __restrict__ scores,
                                  int* __restrict__ ll, int n, int scale) {
  int npool = n / scale;
  int tid = blockIdx.x * blockDim.x + threadIdx.x;
  if (tid >= 2 * npool) return;
  int b = tid / npool, g = tid % npool;
  float counts[4] = {0.f, 0.f, 0.f, 0.f};
  float ssum[4]   = {0.f, 0.f, 0.f, 0.f};
  int firstp[4];
  for (int c = 0; c < 4; ++c) firstp[c] = scale;
  for (int s = 0; s < scale; ++s) {
    int   L = labels[(size_t)b * n + (size_t)g * scale + s];
    float S = scores[(size_t)b * n + (size_t)g * scale + s];
    counts[L] += 1.0f;
    ssum[L]   += S;
    if (s < firstp[L]) firstp[L] = s;
  }
  float cmax = fmaxf(fmaxf(counts[0], counts[1]), fmaxf(counts[2], counts[3]));
  float s2[4];
  for (int c = 0; c < 4; ++c) s2[c] = (counts[c] == cmax) ? ssum[c] : -1e9f;
  float smax = fmaxf(fmaxf(s2[0], s2[1]), fmaxf(s2[2], s2[3]));
  int fp[4];
  for (int c = 0; c < 4; ++c) fp[c] = (s2[c] == smax) ? firstp[c] : scale;
  int best = 0, bv = fp[0];
  for (int c = 1; c < 4; ++c) if (fp[c] < bv) { bv = fp[c]; best = c; }
  ll[(size_t)b * npool + g] = best;
}

// ------------------------------------------------------------ keep (focus) --
__global__ void keep_kernel(const int* __restrict__ ll, const float* __restrict__ sl,
                            int* __restrict__ keep, int total) {
  int tid = blockIdx.x * blockDim.x + threadIdx.x;
  if (tid >= total) return;
  const int*   lp = ll + (size_t)tid * GS;
  const float* sp = sl + (size_t)tid * GS;
  float counts[4] = {0.f, 0.f, 0.f, 0.f};
  for (int i = 0; i < GS; ++i) counts[lp[i]] += 1.f;
  int mode = 0; float bv = counts[0];
  for (int c = 1; c < 4; ++c) if (counts[c] > bv) { bv = counts[c]; mode = c; }
  float pm = 0.f, mean = 0.f;
  for (int i = 0; i < GS; ++i) { pm += (lp[i] == mode) ? 1.f : 0.f; mean += sp[i]; }
  float purity = pm / (float)GS;
  mean /= (float)GS;
  float var = 0.f;
  for (int i = 0; i < GS; ++i) { float d = sp[i] - mean; var += d * d; }
  var /= (float)GS;
  float focus = 0.5f + 0.25f * purity - 0.25f * var;
  focus = fminf(fmaxf(focus, 0.25f), 0.75f);
  keep[tid] = (int)ceilf(focus * (float)WIN);
}

// --------------------- ALL weight transpose+split in one launch (12 mats) ---
// mat = kind*3+lvl, kind: 0=q,1=k,2=v,3=p. hi for all; lo only for q,k.
__global__ __launch_bounds__(256) void wprep_kernel(
    const float* __restrict__ Wq, const float* __restrict__ Wk,
    const float* __restrict__ Wv, const float* __restrict__ Wp,
    u16* __restrict__ whiAll, u16* __restrict__ wloAll) {
  __shared__ float tile[32][33];
  int blk = blockIdx.x;            // 0..3071
  int mat = blk >> 8;              // 0..11
  int sub = blk & 255;
  int kind = mat / 3, lvl = mat % 3;
  const float* W = (kind == 0 ? Wq : kind == 1 ? Wk : kind == 2 ? Wv : Wp)
                   + (size_t)lvl * WSZ;
  u16* bthi = whiAll + (size_t)mat * WSZ;
  u16* btlo = (mat < 6) ? (wloAll + (size_t)mat * WSZ) : nullptr;

  int bx = sub & 15;               // n block
  int by = sub >> 4;               // k block
  int tx = threadIdx.x & 31;
  int ty = threadIdx.x >> 5;       // 0..7
#pragma unroll
  for (int i = 0; i < 4; ++i) {
    int kk = ty + i * 8;
    tile[kk][tx] = W[(size_t)(by * 32 + kk) * 512 + bx * 32 + tx];
  }
  __syncthreads();
#pragma unroll
  for (int i = 0; i < 4; ++i) {
    int nn = ty + i * 8;
    float v = tile[tx][nn];        // = W[by*32+tx][bx*32+nn]
    u16 h = f2b(v);
    size_t o = (size_t)(bx * 32 + nn) * 512 + by * 32 + tx;
    bthi[o] = h;
    if (btlo) btlo[o] = f2b(v - b2f(h));
  }
}

// ---------------------------------------------------- fused q/k/v GEMM ------
// grid (12, M/128): sel=blockIdx.x>>2 (0=q split, 1=k split, 2=v hi-only),
// cx=blockIdx.x&3 column block. Staging via global_load_lds, [128][32] tiles.
__global__ __launch_bounds__(256) void qkv_gemm_kernel(
    const u16* __restrict__ Ahi, const u16* __restrict__ Alo,
    const u16* __restrict__ whiAll, const u16* __restrict__ wloAll,
    float* __restrict__ qb, float* __restrict__ kb, u16* __restrict__ vbf,
    int M, int lvl) {
  __shared__ u16 smem[4 * 4096];
  u16* sAhi = smem;
  u16* sBhi = smem + 4096;
  u16* sAlo = smem + 2 * 4096;
  u16* sBlo = smem + 3 * 4096;

  int sel = blockIdx.x >> 2;       // 0=q, 1=k, 2=v
  int cx  = blockIdx.x & 3;
  bool split = (sel < 2);
  const u16* Bh = whiAll + (size_t)(sel * 3 + lvl) * WSZ;
  const u16* Bl = wloAll + (size_t)(sel * 3 + lvl) * WSZ;   // valid only sel<2

  int t = threadIdx.x, lane = t & 63, wave = t >> 6;
  int wr = wave >> 1, wc = wave & 1;
  int row0 = blockIdx.y * 128, col0 = cx * 128;

  int srow = (lane >> 2);
  int schk = (lane & 3) * 8;

  const f32x4 zero = { 0.f, 0.f, 0.f, 0.f };
  f32x4 acc[4][4];
#pragma unroll
  for (int i = 0; i < 4; ++i)
#pragma unroll
    for (int j = 0; j < 4; ++j) acc[i][j] = zero;

  for (int k0 = 0; k0 < 512; k0 += 32) {
#pragma unroll
    for (int j = 0; j < 2; ++j) {
      int r = wave * 32 + j * 16 + srow;
      const u16* gA = Ahi + (size_t)(row0 + r) * 512 + k0 + schk;
      const u16* gB = Bh + (size_t)(col0 + r) * 512 + k0 + schk;
      __builtin_amdgcn_global_load_lds(
          (const __attribute__((address_space(1))) void*)gA,
          (__attribute__((address_space(3))) void*)&sAhi[(wave * 32 + j * 16) * 32],
          16, 0, 0);
      __builtin_amdgcn_global_load_lds(
          (const __attribute__((address_space(1))) void*)gB,
          (__attribute__((address_space(3))) void*)&sBhi[(wave * 32 + j * 16) * 32],
          16, 0, 0);
      if (split) {
        const u16* gAl = Alo + (size_t)(row0 + r) * 512 + k0 + schk;
        const u16* gBl = Bl + (size_t)(col0 + r) * 512 + k0 + schk;
        __builtin_amdgcn_global_load_lds(
            (const __attribute__((address_space(1))) void*)gAl,
            (__attribute__((address_space(3))) void*)&sAlo[(wave * 32 + j * 16) * 32],
            16, 0, 0);
        __builtin_amdgcn_global_load_lds(
            (const __attribute__((address_space(1))) void*)gBl,
            (__attribute__((address_space(3))) void*)&sBlo[(wave * 32 + j * 16) * 32],
            16, 0, 0);
      }
    }
    __syncthreads();

    int fr = lane & 15;
    int kf = (lane >> 4) * 8;
    bf16x8 ah[4], bh[4], al[4], bl[4];
#pragma unroll
    for (int i = 0; i < 4; ++i) {
      ah[i] = *reinterpret_cast<const bf16x8*>(&sAhi[(wr * 64 + i * 16 + fr) * 32 + kf]);
      bh[i] = *reinterpret_cast<const bf16x8*>(&sBhi[(wc * 64 + i * 16 + fr) * 32 + kf]);
      if (split) {
        al[i] = *reinterpret_cast<const bf16x8*>(&sAlo[(wr * 64 + i * 16 + fr) * 32 + kf]);
        bl[i] = *reinterpret_cast<const bf16x8*>(&sBlo[(wc * 64 + i * 16 + fr) * 32 + kf]);
      }
    }
#pragma unroll
    for (int i = 0; i < 4; ++i)
#pragma unroll
      for (int j = 0; j < 4; ++j) {
        acc[i][j] = __builtin_amdgcn_mfma_f32_16x16x32_bf16(ah[i], bh[j], acc[i][j], 0, 0, 0);
        if (split) {
          acc[i][j] = __builtin_amdgcn_mfma_f32_16x16x32_bf16(ah[i], bl[j], acc[i][j], 0, 0, 0);
          acc[i][j] = __builtin_amdgcn_mfma_f32_16x16x32_bf16(al[i], bh[j], acc[i][j], 0, 0, 0);
        }
      }
    __syncthreads();
  }

  int ccol = col0 + wc * 64 + (lane & 15);
  int crow = row0 + wr * 64 + (lane >> 4) * 4;
  if (sel == 2) {
#pragma unroll
    for (int i = 0; i < 4; ++i)
#pragma unroll
      for (int r = 0; r < 4; ++r) {
        int gr = crow + i * 16 + r;
#pragma unroll
        for (int j = 0; j < 4; ++j)
          vbf[(size_t)gr * 512 + ccol + j * 16] = f2b(acc[i][j][r]);
      }
  } else {
    float* C = (sel == 0) ? qb : kb;
#pragma unroll
    for (int i = 0; i < 4; ++i)
#pragma unroll
      for (int r = 0; r < 4; ++r) {
        int gr = crow + i * 16 + r;
#pragma unroll
        for (int j = 0; j < 4; ++j)
          C[(size_t)gr * 512 + ccol + j * 16] = acc[i][j][r];
      }
  }
}

// --------------------------------------------------- Wp GEMM (scatter) ------
// EMODE 2: scatter-store via idx (rows expanded by scale). 3: scatter +=.
template<int EMODE>
__global__ __launch_bounds__(256) void wp_gemm_kernel(
    const u16* __restrict__ Ahi, const u16* __restrict__ Bthi,
    float* __restrict__ C, const int* __restrict__ idx,
    int M, int scale, int n_l) {
  __shared__ u16 smem[2 * 4096];
  u16* sAhi = smem;
  u16* sBhi = smem + 4096;

  int t = threadIdx.x, lane = t & 63, wave = t >> 6;
  int wr = wave >> 1, wc = wave & 1;
  int row0 = blockIdx.y * 128, col0 = blockIdx.x * 128;

  int srow = (lane >> 2);
  int schk = (lane & 3) * 8;

  const f32x4 zero = { 0.f, 0.f, 0.f, 0.f };
  f32x4 acc[4][4];
#pragma unroll
  for (int i = 0; i < 4; ++i)
#pragma unroll
    for (int j = 0; j < 4; ++j) acc[i][j] = zero;

  for (int k0 = 0; k0 < 512; k0 += 32) {
#pragma unroll
    for (int j = 0; j < 2; ++j) {
      int r = wave * 32 + j * 16 + srow;
      const u16* gA = Ahi + (size_t)(row0 + r) * 512 + k0 + schk;
      const u16* gB = Bthi + (size_t)(col0 + r) * 512 + k0 + schk;
      __builtin_amdgcn_global_load_lds(
          (const __attribute__((address_space(1))) void*)gA,
          (__attribute__((address_space(3))) void*)&sAhi[(wave * 32 + j * 16) * 32],
          16, 0, 0);
      __builtin_amdgcn_global_load_lds(
          (const __attribute__((address_space(1))) void*)gB,
          (__attribute__((address_space(3))) void*)&sBhi[(wave * 32 + j * 16) * 32],
          16, 0, 0);
    }
    __syncthreads();

    int fr = lane & 15;
    int kf = (lane >> 4) * 8;
    bf16x8 ah[4], bh[4];
#pragma unroll
    for (int i = 0; i < 4; ++i) {
      ah[i] = *reinterpret_cast<const bf16x8*>(&sAhi[(wr * 64 + i * 16 + fr) * 32 + kf]);
      bh[i] = *reinterpret_cast<const bf16x8*>(&sBhi[(wc * 64 + i * 16 + fr) * 32 + kf]);
    }
#pragma unroll
    for (int i = 0; i < 4; ++i)
#pragma unroll
      for (int j = 0; j < 4; ++j)
        acc[i][j] = __builtin_amdgcn_mfma_f32_16x16x32_bf16(ah[i], bh[j], acc[i][j], 0, 0, 0);
    __syncthreads();
  }

  int ccol = col0 + wc * 64 + (lane & 15);
  int crow = row0 + wr * 64 + (lane >> 4) * 4;
#pragma unroll
  for (int i = 0; i < 4; ++i) {
#pragma unroll
    for (int r = 0; r < 4; ++r) {
      int gr = crow + i * 16 + r;
      int bb = gr / n_l, rr = gr - bb * n_l;
      for (int s = 0; s < scale; ++s) {
        int dst = idx[(size_t)bb * NTOK + (size_t)rr * scale + s];
        float* p = C + ((size_t)bb * NTOK + dst) * 512 + ccol;
        if (EMODE == 3) {
#pragma unroll
          for (int j = 0; j < 4; ++j) p[j * 16] += acc[i][j][r];
        } else {
#pragma unroll
          for (int j = 0; j < 4; ++j) p[j * 16] = acc[i][j][r];
        }
      }
    }
  }
}

// ----------------------------------------------- fused windowed attention ---
// TWO blocks (512 thr, 8 waves) per (b,g,h), each owns 64 q-rows (p=bid&1).
// Phase A: sim in 2 d-halves (qT/kT f32, VALU — bit-identical ranking).
// Ballot top-k -> softmax -> prior mix; P kept packed bf16 in regs (atp).
// Phase B: PV via MFMA; output written as bf16-hi (Wp GEMM is hi-only).
__global__ __launch_bounds__(512) void attn_fused_kernel(
    const float* __restrict__ q, const float* __restrict__ k,
    const u16* __restrict__ vbf, const int* __restrict__ keepArr,
    const u16* __restrict__ prevA, u16* __restrict__ curA,
    const float* __restrict__ betaL, u16* __restrict__ outp,
    int lvl, int n_l, int ng, int prev_ng) {
  __shared__ u64 smem8[6400];             // 51200 B
  float* qT    = (float*)smem8;           // [32][68]   (d, qi<64)     phase A
  float* kT    = qT + 32 * 68;            // [32][260]  (d, j<256)     phase A
  u16*   P_lds = (u16*)smem8;             // [64][264]  (q row, key)   phase B
  u16*   Vt    = (u16*)smem8 + 16896;     // [64][136]  (dv, k-half)   phase B

  int t = threadIdx.x;
  int lane = t & 63, wave = t >> 6;
  int bid = blockIdx.x;
  int p   = bid & 1;
  int h   = (bid >> 1) & 7;
  int gl  = bid >> 4;
  int g   = gl % ng;
  int b   = gl / ng;
  int bgh = bid >> 1;                     // (b,g,h) index for attn state

  const float* qbase = q + ((size_t)b * n_l + (size_t)g * GS + p * 64) * DIMC + h * DQK;
  const float* kbase = k + (size_t)b * n_l * DIMC + h * DQK;

  // ---- sim over two d-halves; acc identical to full-d accumulation ----
  float acc[8][4] = {};
#pragma unroll
  for (int dp = 0; dp < 2; ++dp) {
    int d0 = dp * 32;
    {  // qT: 64 qi x 8 d4 chunks = 512
      int qi = t >> 3, d4 = t & 7;
      float4 vv = *reinterpret_cast<const float4*>(qbase + (size_t)qi * DIMC + d0 + d4 * 4);
      qT[(d4 * 4 + 0) * 68 + qi] = vv.x;
      qT[(d4 * 4 + 1) * 68 + qi] = vv.y;
      qT[(d4 * 4 + 2) * 68 + qi] = vv.z;
      qT[(d4 * 4 + 3) * 68 + qi] = vv.w;
    }
#pragma unroll
    for (int it = 0; it < 4; ++it) {      // kT: 256 j x 8 d4 chunks
      int idx = it * 512 + t;
      int j = idx >> 3, d4 = idx & 7;
      int pp = g * GS + j;
      int src = (pp < n_l) ? pp : (2 * n_l - 1 - pp);
      float4 vv = *reinterpret_cast<const float4*>(kbase + (size_t)src * DIMC + d0 + d4 * 4);
      kT[(d4 * 4 + 0) * 260 + j] = vv.x;
      kT[(d4 * 4 + 1) * 260 + j] = vv.y;
      kT[(d4 * 4 + 2) * 260 + j] = vv.z;
      kT[(d4 * 4 + 3) * 260 + j] = vv.w;
    }
    __syncthreads();
#pragma unroll 2
    for (int d = 0; d < 32; ++d) {
      float ra[8], rb4[4];
      *reinterpret_cast<float4*>(&ra[0]) = *reinterpret_cast<const float4*>(&qT[d * 68 + wave * 8 + 0]);
      *reinterpret_cast<float4*>(&ra[4]) = *reinterpret_cast<const float4*>(&qT[d * 68 + wave * 8 + 4]);
      *reinterpret_cast<float4*>(&rb4[0]) = *reinterpret_cast<const float4*>(&kT[d * 260 + lane * 4]);
#pragma unroll
      for (int i = 0; i < 8; ++i)
#pragma unroll
        for (int j = 0; j < 4; ++j) acc[i][j] += ra[i] * rb4[j];
    }
    __syncthreads();
  }

  int kp = keepArr[b * ng + g];
  float beta = 0.f, wgt = 0.f;
  int lo = 0, hi = 0;
  if (lvl > 0) {
    beta = 1.f / (1.f + expf(-betaL[lvl]));
    float pos = ((float)g + 0.5f) * ((float)prev_ng / (float)ng) - 0.5f;
    float fl = floorf(pos);
    lo = (int)fl;
    if (lo < 0) lo = 0;
    if (lo > prev_ng - 1) lo = prev_ng - 1;
    hi = lo + 1; if (hi > prev_ng - 1) hi = prev_ng - 1;
    wgt = fminf(fmaxf(pos - fl, 0.f), 1.f);
  }
  u64 lmask = (1ull << lane) - 1ull;

  // ---- per-row: ballot top-k -> softmax -> prior mix; retain packed bf16 ---
  unsigned atp[8][2];
#pragma unroll
  for (int r = 0; r < 8; ++r) {
    int i = p * 64 + wave * 8 + r;        // row within the 128-row group
    float sv[4];
    unsigned um[4];
#pragma unroll
    for (int e = 0; e < 4; ++e) {
      sv[e] = acc[r][e] * 0.125f;
      unsigned u = __float_as_uint(sv[e]);
      um[e] = (u & 0x80000000u) ? ~u : (u | 0x80000000u);
    }
    unsigned T = 0u;
    for (int bit = 31; bit >= 0; --bit) {
      unsigned T2 = T | (1u << bit);
      int c = __popcll(__ballot(um[0] >= T2)) + __popcll(__ballot(um[1] >= T2))
            + __popcll(__ballot(um[2] >= T2)) + __popcll(__ballot(um[3] >= T2));
      if (c >= kp) T = T2;
    }
    int c_gt = __popcll(__ballot(um[0] > T)) + __popcll(__ballot(um[1] > T))
             + __popcll(__ballot(um[2] > T)) + __popcll(__ballot(um[3] > T));
    u64 beq[4];
#pragma unroll
    for (int e = 0; e < 4; ++e) beq[e] = __ballot(um[e] == T);
    int trbase = __popcll(beq[0] & lmask) + __popcll(beq[1] & lmask)
               + __popcll(beq[2] & lmask) + __popcll(beq[3] & lmask);
    int need = kp - c_gt;
    bool msk[4];
    int own = 0;
#pragma unroll
    for (int e = 0; e < 4; ++e) {
      bool eq = (um[e] == T);
      msk[e] = (um[e] > T) || (eq && (trbase + own) < need);
      own += eq ? 1 : 0;
    }
    float m = -3.0e38f;
#pragma unroll
    for (int e = 0; e < 4; ++e) if (msk[e]) m = fmaxf(m, sv[e]);
    m = wave_max64(m);
    float ez[4], zs = 0.f;
#pragma unroll
    for (int e = 0; e < 4; ++e) { ez[e] = msk[e] ? __expf(sv[e] - m) : 0.f; zs += ez[e]; }
    zs = wave_sum64(zs);
    float at[4];
#pragma unroll
    for (int e = 0; e < 4; ++e) at[e] = ez[e] / zs;
    if (lvl > 0) {
      size_t baseLo = ((((size_t)b * prev_ng + lo) * 8 + h) * GS + i) * WIN + lane * 4;
      size_t baseHi = ((((size_t)b * prev_ng + hi) * 8 + h) * GS + i) * WIN + lane * 4;
      uint2 rlo = *reinterpret_cast<const uint2*>(prevA + baseLo);
      uint2 rhi = *reinterpret_cast<const uint2*>(prevA + baseHi);
      float pl[4] = { b2f_lo(rlo.x), b2f_hi(rlo.x), b2f_lo(rlo.y), b2f_hi(rlo.y) };
      float ph[4] = { b2f_lo(rhi.x), b2f_hi(rhi.x), b2f_lo(rhi.y), b2f_hi(rhi.y) };
      float pr[4], ps = 0.f;
#pragma unroll
      for (int e = 0; e < 4; ++e) {
        pr[e] = fmaxf((1.f - wgt) * pl[e] + wgt * ph[e], 0.f);
        ps += pr[e];
      }
      ps = wave_sum64(ps) + 1e-9f;
#pragma unroll
      for (int e = 0; e < 4; ++e) at[e] = (1.f - beta) * at[e] + beta * (pr[e] / ps);
    }
    atp[r][0] = (unsigned)f2b(at[0]) | ((unsigned)f2b(at[1]) << 16);
    atp[r][1] = (unsigned)f2b(at[2]) | ((unsigned)f2b(at[3]) << 16);
    if (curA != nullptr) {
      uint2 o = { atp[r][0], atp[r][1] };
      *reinterpret_cast<uint2*>(curA + ((size_t)bgh * GS + i) * WIN + lane * 4) = o;
    }
  }

  // ---- PV via MFMA: O(64x64) = P(64x256) @ V(256x64) ----
#pragma unroll
  for (int r = 0; r < 8; ++r) {
    uint2 o = { atp[r][0], atp[r][1] };
    *reinterpret_cast<uint2*>(&P_lds[(wave * 8 + r) * 264 + lane * 4]) = o;
  }

  const u16* vbase = vbf + (size_t)b * n_l * DIMC + h * DV;
  int rf   = wave >> 1;                  // q-row frag 0..3
  int cf0  = (wave & 1) * 2;             // dv col frag base {0,2}
  int frow = lane & 15;
  int fk   = (lane >> 4) * 8;
  f32x4 oacc0 = { 0.f, 0.f, 0.f, 0.f };
  f32x4 oacc1 = { 0.f, 0.f, 0.f, 0.f };
  int jlo = t & 15, vd4 = (t >> 4) & 15, jh2 = t >> 8;

#pragma unroll
  for (int jp = 0; jp < 2; ++jp) {
#pragma unroll
    for (int it = 0; it < 4; ++it) {
      int j = (jh2 * 4 + it) * 16 + jlo;           // 0..127
      int pp = g * GS + jp * 128 + j;
      int src = (pp < n_l) ? pp : (2 * n_l - 1 - pp);
      ushort4 vv = *reinterpret_cast<const ushort4*>(vbase + (size_t)src * DIMC + vd4 * 4);
      Vt[(vd4 * 4 + 0) * 136 + j] = vv.x;
      Vt[(vd4 * 4 + 1) * 136 + j] = vv.y;
      Vt[(vd4 * 4 + 2) * 136 + j] = vv.z;
      Vt[(vd4 * 4 + 3) * 136 + j] = vv.w;
    }
    __syncthreads();
    int kb2 = jp * 128;
#pragma unroll
    for (int ks = 0; ks < 4; ++ks) {
      bf16x8 a  = *reinterpret_cast<const bf16x8*>(&P_lds[(rf * 16 + frow) * 264 + kb2 + ks * 32 + fk]);
      bf16x8 b0 = *reinterpret_cast<const bf16x8*>(&Vt[(cf0 * 16 + frow) * 136 + ks * 32 + fk]);
      bf16x8 b1 = *reinterpret_cast<const bf16x8*>(&Vt[((cf0 + 1) * 16 + frow) * 136 + ks * 32 + fk]);
      oacc0 = __builtin_amdgcn_mfma_f32_16x16x32_bf16(a, b0, oacc0, 0, 0, 0);
      oacc1 = __builtin_amdgcn_mfma_f32_16x16x32_bf16(a, b1, oacc1, 0, 0, 0);
    }
    __syncthreads();
  }

  u16* obase = outp + ((size_t)b * n_l + (size_t)g * GS + p * 64 + rf * 16) * DIMC + h * DV;
#pragma unroll
  for (int rr = 0; rr < 4; ++rr) {
    int qrow = (lane >> 4) * 4 + rr;
    obase[(size_t)qrow * DIMC + cf0 * 16 + frow]       = f2b(oacc0[rr]);
    obase[(size_t)qrow * DIMC + (cf0 + 1) * 16 + frow] = f2b(oacc1[rr]);
  }
}

// ---------------------------------------------------------------------------
extern "C" void kernel_launch(void* const* d_in, const int* in_sizes, int n_in,
                              void* d_out, int out_size, void* d_ws, size_t ws_size,
                              hipStream_t stream) {
  (void)in_sizes; (void)n_in; (void)out_size; (void)ws_size;
  const float* x        = (const float*)d_in[0];
  const int*   labels   = (const int*)d_in[1];
  const float* scores   = (const float*)d_in[2];
  const int*   idx_last = (const int*)d_in[3];
  const float* Wq       = (const float*)d_in[4];
  const float* Wk       = (const float*)d_in[5];
  const float* Wv       = (const float*)d_in[6];
  const float* Wp       = (const float*)d_in[7];
  const float* betaL    = (const float*)d_in[8];
  float* out = (float*)d_out;

  char* w = (char*)d_ws;
  size_t off = 0;
  auto take = [&](size_t bytes) -> char* {
    char* p = w + off;
    off += (bytes + 255) & ~(size_t)255;
    return p;
  };
  float* qb     = (float*)take(33554432);   // q f32 (max 2*8192*512)
  float* kb     = (float*)take(33554432);   // k f32
  u16*   vbf    = (u16*)  take(16777216);   // v bf16
  u16*   xhi    = (u16*)  take(16777216);   // A hi / attn-out (disjoint lifetimes)
  u16*   xlo    = (u16*)  take(16777216);   // A lo
  u16*   attnA  = (u16*)  take(16777216);   // lvl0 attn bf16
  u16*   attnB  = (u16*)  take(33554432);   // lvl1 attn bf16
  u16*   whiAll = (u16*)  take(6291456);    // 12 x [512][512] bf16 hi (q,k,v,p x 3 lvls)
  u16*   wloAll = (u16*)  take(3145728);    // 6  x [512][512] bf16 lo (q,k x 3 lvls)
  float* sl     = (float*)take(32768);
  int*   ll     = (int*)  take(32768);
  int*   keepb  = (int*)  take(1024);
  // total ~169 MB

  // all 12 weight transposes+splits, once
  wprep_kernel<<<3072, 256, 0, stream>>>(Wq, Wk, Wv, Wp, whiAll, wloAll);

  for (int lvl = 0; lvl < 3; ++lvl) {
    int scale = (lvl == 0) ? 4 : (lvl == 1) ? 2 : 1;
    int n_l = NTOK / scale;
    int ng  = n_l / GS;
    int M   = 2 * n_l;
    const int* lin; const float* sin_;
    if (scale > 1) {
      int tfeat = 2 * n_l * (DIMC / 4);
      pool_split_kernel<<<(tfeat + 255) / 256, 256, 0, stream>>>(x, scores, xhi, xlo, sl, NTOK, scale);
      pool_label_kernel<<<(2 * n_l + 255) / 256, 256, 0, stream>>>(labels, scores, ll, NTOK, scale);
      lin = ll; sin_ = sl;
    } else {
      asplit_kernel<<<(2 * NTOK * 128) / 256, 256, 0, stream>>>(x, xhi, xlo);
      lin = labels; sin_ = scores;
    }
    keep_kernel<<<(2 * ng + 127) / 128, 128, 0, stream>>>(lin, sin_, keepb, 2 * ng);

    dim3 gq(12, M / 128);
    qkv_gemm_kernel<<<gq, 256, 0, stream>>>(xhi, xlo, whiAll, wloAll, qb, kb, vbf, M, lvl);

    const u16* prev = (lvl == 0) ? nullptr : ((lvl == 1) ? attnA : attnB);
    u16* cur = (lvl == 0) ? attnA : ((lvl == 1) ? attnB : nullptr);
    // attn output reuses xhi (A-side dead after qkv gemm)
    attn_fused_kernel<<<2 * ng * 8 * 2, 512, 0, stream>>>(qb, kb, vbf, keepb, prev, cur,
                                                          betaL, xhi, lvl, n_l, ng, ng / 2);

    dim3 gp(4, M / 128);
    const u16* wphi = whiAll + (size_t)(9 + lvl) * WSZ;
    if (lvl == 0)
      wp_gemm_kernel<2><<<gp, 256, 0, stream>>>(xhi, wphi, out, idx_last, M, scale, n_l);
    else
      wp_gemm_kernel<3><<<gp, 256, 0, stream>>>(xhi, wphi, out, idx_last, M, scale, n_l);
  }
}

// Round 11
// 579.385 us; speedup vs baseline: 2.3705x; 1.1003x over previous
//
#include <hip/hip_runtime.h>
#include <math.h>

// ---------------------------------------------------------------------------
// LowToHighMultiLevelReconstruction — round 11.
// Changes vs round 10:
//  1. Attention sim moved to split-bf16 MFMA (3-product: hi*hi+hi*lo+lo*hi).
//     q/k now produced as pre-split bf16 hi/lo by qkv_gemm. K/Q staged via
//     global_load_lds (per-lane reflected source). S round-trips LDS f32
//     [32][264] in two q-halves into the proven ballot layout.
//  2. Ballot top-k early-exit: break when count(>=T2)==kp (mask provably
//     identical — all ties admitted).
//  PV / softmax / prior / GEMM structure unchanged.
// ---------------------------------------------------------------------------

#define GS   128
#define WIN  256        // 2*GS
#define DQK  64
#define DV   64
#define DIMC 512
#define NTOK 8192
#define WSZ  262144     // 512*512 elements per weight matrix

typedef unsigned long long u64;
typedef unsigned short u16;
typedef __attribute__((ext_vector_type(8))) short bf16x8;
typedef __attribute__((ext_vector_type(4))) float f32x4;

__device__ __forceinline__ u16 f2b(float f) {     // f32 -> bf16 RNE
  unsigned u = __float_as_uint(f);
  u = (u + 0x7fffu + ((u >> 16) & 1u)) >> 16;
  return (u16)u;
}
__device__ __forceinline__ float b2f(u16 h) { return __uint_as_float(((unsigned)h) << 16); }
__device__ __forceinline__ float b2f_lo(unsigned u) { return __uint_as_float(u << 16); }
__device__ __forceinline__ float b2f_hi(unsigned u) { return __uint_as_float(u & 0xffff0000u); }

__device__ __forceinline__ float wave_max64(float v) {
#pragma unroll
  for (int m = 1; m < 64; m <<= 1) v = fmaxf(v, __shfl_xor(v, m, 64));
  return v;
}
__device__ __forceinline__ float wave_sum64(float v) {
#pragma unroll
  for (int m = 1; m < 64; m <<= 1) v += __shfl_xor(v, m, 64);
  return v;
}

// --------------------------------------------- pooling (writes split bf16) --
__global__ void pool_split_kernel(const float* __restrict__ x,
                                  const float* __restrict__ scores,
                                  u16* __restrict__ xhi, u16* __restrict__ xlo,
                                  float* __restrict__ sl, int n, int scale) {
  int npool = n / scale;
  int total = 2 * npool * (DIMC / 4);
  int tid = blockIdx.x * blockDim.x + threadIdx.x;
  if (tid >= total) return;
  int c4 = tid & 127;
  int g  = (tid >> 7) % npool;
  int b  = (tid >> 7) / npool;
  const float* xp = x + ((size_t)b * n + (size_t)g * scale) * DIMC + c4 * 4;
  float ax = 0.f, ay = 0.f, az = 0.f, aw = 0.f, wsum = 0.f, ssum = 0.f;
  for (int s = 0; s < scale; ++s) {
    float sc = scores[(size_t)b * n + (size_t)g * scale + s];
    float w  = fmaxf(sc, 1e-6f);
    float4 xv = *reinterpret_cast<const float4*>(xp + (size_t)s * DIMC);
    ax += xv.x * w; ay += xv.y * w; az += xv.z * w; aw += xv.w * w;
    wsum += w; ssum += sc;
  }
  float o[4] = { ax / wsum, ay / wsum, az / wsum, aw / wsum };
  ushort4 h, l;
  h.x = f2b(o[0]); h.y = f2b(o[1]); h.z = f2b(o[2]); h.w = f2b(o[3]);
  l.x = f2b(o[0] - b2f(h.x)); l.y = f2b(o[1] - b2f(h.y));
  l.z = f2b(o[2] - b2f(h.z)); l.w = f2b(o[3] - b2f(h.w));
  size_t off = ((size_t)b * npool + g) * DIMC + c4 * 4;
  *reinterpret_cast<ushort4*>(xhi + off) = h;
  *reinterpret_cast<ushort4*>(xlo + off) = l;
  if (c4 == 0) sl[(size_t)b * npool + g] = ssum / (float)scale;
}

// --------------------------------------------------- raw x split (lvl 2) ----
__global__ void asplit_kernel(const float* __restrict__ x,
                              u16* __restrict__ xhi, u16* __restrict__ xlo) {
  int tid = blockIdx.x * 256 + threadIdx.x;     // over 2*NTOK*128 float4s
  float4 v = *reinterpret_cast<const float4*>(x + (size_t)tid * 4);
  ushort4 h, l;
  h.x = f2b(v.x); h.y = f2b(v.y); h.z = f2b(v.z); h.w = f2b(v.w);
  l.x = f2b(v.x - b2f(h.x)); l.y = f2b(v.y - b2f(h.y));
  l.z = f2b(v.z - b2f(h.z)); l.w = f2b(v.w - b2f(h.w));
  *reinterpret_cast<ushort4*>(xhi + (size_t)tid * 4) = h;
  *reinterpret_cast<ushort4*>(xlo + (size_t)tid * 4) = l;
}

__global__ void pool_label_kernel(const int* __restrict__ labels,
                                  const float* __restrict__ scores,
                                  int* __restrict__ ll, int n, int scale) {
  int npool = n / scale;
  int tid = blockIdx.x * blockDim.x + threadIdx.x;
  if (tid >= 2 * npool) return;
  int b = tid / npool, g = tid % npool;
  float counts[4] = {0.f, 0.f, 0.f, 0.f};
  float ssum[4]   = {0.f, 0.f, 0.f, 0.f};
  int firstp[4];
  for (int c = 0; c < 4; ++c) firstp[c] = scale;
  for (int s = 0; s < scale; ++s) {
    int   L = labels[(size_t)b * n + (size_t)g * scale + s];
    float S = scores[(size_t)b * n + (size_t)g * scale + s];
    counts[L] += 1.0f;
    ssum[L]   += S;
    if (s < firstp[L]) firstp[L] = s;
  }
  float cmax = fmaxf(fmaxf(counts[0], counts[1]), fmaxf(counts[2], counts[3]));
  float s2[4];
  for (int c = 0; c < 4; ++c) s2[c] = (counts[c] == cmax) ? ssum[c] : -1e9f;
  float smax = fmaxf(fmaxf(s2[0], s2[1]), fmaxf(s2[2], s2[3]));
  int fp[4];
  for (int c = 0; c < 4; ++c) fp[c] = (s2[c] == smax) ? firstp[c] : scale;
  int best = 0, bv = fp[0];
  for (int c = 1; c < 4; ++c) if (fp[c] < bv) { bv = fp[c]; best = c; }
  ll[(size_t)b * npool + g] = best;
}

// ------------------------------------------------------------ keep (focus) --
__global__ void keep_kernel(const int* __restrict__ ll, const float* __restrict__ sl,
                            int* __restrict__ keep, int total) {
  int tid = blockIdx.x * blockDim.x + threadIdx.x;
  if (tid >= total) return;
  const int*   lp = ll + (size_t)tid * GS;
  const float* sp = sl + (size_t)tid * GS;
  float counts[4] = {0.f, 0.f, 0.f, 0.f};
  for (int i = 0; i < GS; ++i) counts[lp[i]] += 1.f;
  int mode = 0; float bv = counts[0];
  for (int c = 1; c < 4; ++c) if (counts[c] > bv) { bv = counts[c]; mode = c; }
  float pm = 0.f, mean = 0.f;
  for (int i = 0; i < GS; ++i) { pm += (lp[i] == mode) ? 1.f : 0.f; mean += sp[i]; }
  float purity = pm / (float)GS;
  mean /= (float)GS;
  float var = 0.f;
  for (int i = 0; i < GS; ++i) { float d = sp[i] - mean; var += d * d; }
  var /= (float)GS;
  float focus = 0.5f + 0.25f * purity - 0.25f * var;
  focus = fminf(fmaxf(focus, 0.25f), 0.75f);
  keep[tid] = (int)ceilf(focus * (float)WIN);
}

// --------------------- ALL weight transpose+split in one launch (12 mats) ---
__global__ __launch_bounds__(256) void wprep_kernel(
    const float* __restrict__ Wq, const float* __restrict__ Wk,
    const float* __restrict__ Wv, const float* __restrict__ Wp,
    u16* __restrict__ whiAll, u16* __restrict__ wloAll) {
  __shared__ float tile[32][33];
  int blk = blockIdx.x;            // 0..3071
  int mat = blk >> 8;              // 0..11
  int sub = blk & 255;
  int kind = mat / 3, lvl = mat % 3;
  const float* W = (kind == 0 ? Wq : kind == 1 ? Wk : kind == 2 ? Wv : Wp)
                   + (size_t)lvl * WSZ;
  u16* bthi = whiAll + (size_t)mat * WSZ;
  u16* btlo = (mat < 6) ? (wloAll + (size_t)mat * WSZ) : nullptr;

  int bx = sub & 15;               // n block
  int by = sub >> 4;               // k block
  int tx = threadIdx.x & 31;
  int ty = threadIdx.x >> 5;       // 0..7
#pragma unroll
  for (int i = 0; i < 4; ++i) {
    int kk = ty + i * 8;
    tile[kk][tx] = W[(size_t)(by * 32 + kk) * 512 + bx * 32 + tx];
  }
  __syncthreads();
#pragma unroll
  for (int i = 0; i < 4; ++i) {
    int nn = ty + i * 8;
    float v = tile[tx][nn];        // = W[by*32+tx][bx*32+nn]
    u16 h = f2b(v);
    size_t o = (size_t)(bx * 32 + nn) * 512 + by * 32 + tx;
    bthi[o] = h;
    if (btlo) btlo[o] = f2b(v - b2f(h));
  }
}

// ---------------------------------------------------- fused q/k/v GEMM ------
// grid (12, M/128): sel=blockIdx.x>>2 (0=q split, 1=k split, 2=v hi-only).
// q,k now emitted as pre-split bf16 hi/lo; v as bf16 hi.
__global__ __launch_bounds__(256) void qkv_gemm_kernel(
    const u16* __restrict__ Ahi, const u16* __restrict__ Alo,
    const u16* __restrict__ whiAll, const u16* __restrict__ wloAll,
    u16* __restrict__ qhi, u16* __restrict__ qlo,
    u16* __restrict__ khi, u16* __restrict__ klo, u16* __restrict__ vbf,
    int M, int lvl) {
  __shared__ u16 smem[4 * 4096];
  u16* sAhi = smem;
  u16* sBhi = smem + 4096;
  u16* sAlo = smem + 2 * 4096;
  u16* sBlo = smem + 3 * 4096;

  int sel = blockIdx.x >> 2;       // 0=q, 1=k, 2=v
  int cx  = blockIdx.x & 3;
  bool split = (sel < 2);
  const u16* Bh = whiAll + (size_t)(sel * 3 + lvl) * WSZ;
  const u16* Bl = wloAll + (size_t)(sel * 3 + lvl) * WSZ;   // valid only sel<2

  int t = threadIdx.x, lane = t & 63, wave = t >> 6;
  int wr = wave >> 1, wc = wave & 1;
  int row0 = blockIdx.y * 128, col0 = cx * 128;

  int srow = (lane >> 2);
  int schk = (lane & 3) * 8;

  const f32x4 zero = { 0.f, 0.f, 0.f, 0.f };
  f32x4 acc[4][4];
#pragma unroll
  for (int i = 0; i < 4; ++i)
#pragma unroll
    for (int j = 0; j < 4; ++j) acc[i][j] = zero;

  for (int k0 = 0; k0 < 512; k0 += 32) {
#pragma unroll
    for (int j = 0; j < 2; ++j) {
      int r = wave * 32 + j * 16 + srow;
      const u16* gA = Ahi + (size_t)(row0 + r) * 512 + k0 + schk;
      const u16* gB = Bh + (size_t)(col0 + r) * 512 + k0 + schk;
      __builtin_amdgcn_global_load_lds(
          (const __attribute__((address_space(1))) void*)gA,
          (__attribute__((address_space(3))) void*)&sAhi[(wave * 32 + j * 16) * 32],
          16, 0, 0);
      __builtin_amdgcn_global_load_lds(
          (const __attribute__((address_space(1))) void*)gB,
          (__attribute__((address_space(3))) void*)&sBhi[(wave * 32 + j * 16) * 32],
          16, 0, 0);
      if (split) {
        const u16* gAl = Alo + (size_t)(row0 + r) * 512 + k0 + schk;
        const u16* gBl = Bl + (size_t)(col0 + r) * 512 + k0 + schk;
        __builtin_amdgcn_global_load_lds(
            (const __attribute__((address_space(1))) void*)gAl,
            (__attribute__((address_space(3))) void*)&sAlo[(wave * 32 + j * 16) * 32],
            16, 0, 0);
        __builtin_amdgcn_global_load_lds(
            (const __attribute__((address_space(1))) void*)gBl,
            (__attribute__((address_space(3))) void*)&sBlo[(wave * 32 + j * 16) * 32],
            16, 0, 0);
      }
    }
    __syncthreads();

    int fr = lane & 15;
    int kf = (lane >> 4) * 8;
    bf16x8 ah[4], bh[4], al[4], bl[4];
#pragma unroll
    for (int i = 0; i < 4; ++i) {
      ah[i] = *reinterpret_cast<const bf16x8*>(&sAhi[(wr * 64 + i * 16 + fr) * 32 + kf]);
      bh[i] = *reinterpret_cast<const bf16x8*>(&sBhi[(wc * 64 + i * 16 + fr) * 32 + kf]);
      if (split) {
        al[i] = *reinterpret_cast<const bf16x8*>(&sAlo[(wr * 64 + i * 16 + fr) * 32 + kf]);
        bl[i] = *reinterpret_cast<const bf16x8*>(&sBlo[(wc * 64 + i * 16 + fr) * 32 + kf]);
      }
    }
#pragma unroll
    for (int i = 0; i < 4; ++i)
#pragma unroll
      for (int j = 0; j < 4; ++j) {
        acc[i][j] = __builtin_amdgcn_mfma_f32_16x16x32_bf16(ah[i], bh[j], acc[i][j], 0, 0, 0);
        if (split) {
          acc[i][j] = __builtin_amdgcn_mfma_f32_16x16x32_bf16(ah[i], bl[j], acc[i][j], 0, 0, 0);
          acc[i][j] = __builtin_amdgcn_mfma_f32_16x16x32_bf16(al[i], bh[j], acc[i][j], 0, 0, 0);
        }
      }
    __syncthreads();
  }

  int ccol = col0 + wc * 64 + (lane & 15);
  int crow = row0 + wr * 64 + (lane >> 4) * 4;
  if (sel == 2) {
#pragma unroll
    for (int i = 0; i < 4; ++i)
#pragma unroll
      for (int r = 0; r < 4; ++r) {
        int gr = crow + i * 16 + r;
#pragma unroll
        for (int j = 0; j < 4; ++j)
          vbf[(size_t)gr * 512 + ccol + j * 16] = f2b(acc[i][j][r]);
      }
  } else {
    u16* Ch = (sel == 0) ? qhi : khi;
    u16* Cl = (sel == 0) ? qlo : klo;
#pragma unroll
    for (int i = 0; i < 4; ++i)
#pragma unroll
      for (int r = 0; r < 4; ++r) {
        int gr = crow + i * 16 + r;
#pragma unroll
        for (int j = 0; j < 4; ++j) {
          float v = acc[i][j][r];
          u16 hh = f2b(v);
          Ch[(size_t)gr * 512 + ccol + j * 16] = hh;
          Cl[(size_t)gr * 512 + ccol + j * 16] = f2b(v - b2f(hh));
        }
      }
  }
}

// --------------------------------------------------- Wp GEMM (scatter) ------
template<int EMODE>
__global__ __launch_bounds__(256) void wp_gemm_kernel(
    const u16* __restrict__ Ahi, const u16* __restrict__ Bthi,
    float* __restrict__ C, const int* __restrict__ idx,
    int M, int scale, int n_l) {
  __shared__ u16 smem[2 * 4096];
  u16* sAhi = smem;
  u16* sBhi = smem + 4096;

  int t = threadIdx.x, lane = t & 63, wave = t >> 6;
  int wr = wave >> 1, wc = wave & 1;
  int row0 = blockIdx.y * 128, col0 = blockIdx.x * 128;

  int srow = (lane >> 2);
  int schk = (lane & 3) * 8;

  const f32x4 zero = { 0.f, 0.f, 0.f, 0.f };
  f32x4 acc[4][4];
#pragma unroll
  for (int i = 0; i < 4; ++i)
#pragma unroll
    for (int j = 0; j < 4; ++j) acc[i][j] = zero;

  for (int k0 = 0; k0 < 512; k0 += 32) {
#pragma unroll
    for (int j = 0; j < 2; ++j) {
      int r = wave * 32 + j * 16 + srow;
      const u16* gA = Ahi + (size_t)(row0 + r) * 512 + k0 + schk;
      const u16* gB = Bthi + (size_t)(col0 + r) * 512 + k0 + schk;
      __builtin_amdgcn_global_load_lds(
          (const __attribute__((address_space(1))) void*)gA,
          (__attribute__((address_space(3))) void*)&sAhi[(wave * 32 + j * 16) * 32],
          16, 0, 0);
      __builtin_amdgcn_global_load_lds(
          (const __attribute__((address_space(1))) void*)gB,
          (__attribute__((address_space(3))) void*)&sBhi[(wave * 32 + j * 16) * 32],
          16, 0, 0);
    }
    __syncthreads();

    int fr = lane & 15;
    int kf = (lane >> 4) * 8;
    bf16x8 ah[4], bh[4];
#pragma unroll
    for (int i = 0; i < 4; ++i) {
      ah[i] = *reinterpret_cast<const bf16x8*>(&sAhi[(wr * 64 + i * 16 + fr) * 32 + kf]);
      bh[i] = *reinterpret_cast<const bf16x8*>(&sBhi[(wc * 64 + i * 16 + fr) * 32 + kf]);
    }
#pragma unroll
    for (int i = 0; i < 4; ++i)
#pragma unroll
      for (int j = 0; j < 4; ++j)
        acc[i][j] = __builtin_amdgcn_mfma_f32_16x16x32_bf16(ah[i], bh[j], acc[i][j], 0, 0, 0);
    __syncthreads();
  }

  int ccol = col0 + wc * 64 + (lane & 15);
  int crow = row0 + wr * 64 + (lane >> 4) * 4;
#pragma unroll
  for (int i = 0; i < 4; ++i) {
#pragma unroll
    for (int r = 0; r < 4; ++r) {
      int gr = crow + i * 16 + r;
      int bb = gr / n_l, rr = gr - bb * n_l;
      for (int s = 0; s < scale; ++s) {
        int dst = idx[(size_t)bb * NTOK + (size_t)rr * scale + s];
        float* p = C + ((size_t)bb * NTOK + dst) * 512 + ccol;
        if (EMODE == 3) {
#pragma unroll
          for (int j = 0; j < 4; ++j) p[j * 16] += acc[i][j][r];
        } else {
#pragma unroll
          for (int j = 0; j < 4; ++j) p[j * 16] = acc[i][j][r];
        }
      }
    }
  }
}

// ----------------------------------------------- fused windowed attention ---
// TWO blocks (512 thr, 8 waves) per (b,g,h), each owns 64 q-rows (p=bid&1).
// Phase A: sim via split-bf16 MFMA. K hi/lo [256][32] + Q hi/lo [64][32]
//   staged per d-half via global_load_lds (per-lane reflected source).
//   Wave w: q-tile qt=w>>1, key-tiles (w&1)*8..+7; acc[8] f32x4.
// S written to LDS f32 [32][264] in two q-halves -> ballot layout.
// Ballot top-k (early exit at count==kp) -> softmax -> prior mix -> atp.
// Phase B: PV via MFMA (unchanged); output bf16-hi.
__global__ __launch_bounds__(512) void attn_fused_kernel(
    const u16* __restrict__ qhi, const u16* __restrict__ qlo,
    const u16* __restrict__ khi, const u16* __restrict__ klo,
    const u16* __restrict__ vbf, const int* __restrict__ keepArr,
    const u16* __restrict__ prevA, u16* __restrict__ curA,
    const float* __restrict__ betaL, u16* __restrict__ outp,
    int lvl, int n_l, int ng, int prev_ng) {
  __shared__ u64 smem8[6400];             // 51200 B
  u16*   Khi_s = (u16*)smem8;             // [256][32] @0     (phase A stage)
  u16*   Klo_s = Khi_s + 256 * 32;        // @16384
  u16*   Qhi_s = Klo_s + 256 * 32;        // [64][32] @32768
  u16*   Qlo_s = Qhi_s + 64 * 32;         // @36864 (..40960)
  float* S_lds = (float*)smem8;           // [32][264] f32 @0 (after stage dead)
  u16*   P_lds = (u16*)smem8;             // [64][264] @0     (phase B)
  u16*   Vt    = P_lds + 64 * 264;        // [64][136] @33792 (phase B)

  int t = threadIdx.x;
  int lane = t & 63, wave = t >> 6;
  int bid = blockIdx.x;
  int p   = bid & 1;
  int h   = (bid >> 1) & 7;
  int gl  = bid >> 4;
  int g   = gl % ng;
  int b   = gl / ng;
  int bgh = bid >> 1;                     // (b,g,h) index for attn state

  const u16* qhbase = qhi + ((size_t)b * n_l + (size_t)g * GS + p * 64) * DIMC + h * DQK;
  const u16* qlbase = qlo + ((size_t)b * n_l + (size_t)g * GS + p * 64) * DIMC + h * DQK;
  const u16* khbase = khi + (size_t)b * n_l * DIMC + h * DQK;
  const u16* klbase = klo + (size_t)b * n_l * DIMC + h * DQK;

  // ---- phase A: sim via MFMA (3-product split), acc over 2 d-halves ----
  int qt  = wave >> 1;                    // q-tile 0..3
  int ktb = (wave & 1) * 8;               // key-tile base 0 or 8
  f32x4 acc[8];
#pragma unroll
  for (int i = 0; i < 8; ++i) acc[i] = (f32x4){0.f, 0.f, 0.f, 0.f};

#pragma unroll
  for (int dp = 0; dp < 2; ++dp) {
    if (dp) __syncthreads();              // previous half's frags consumed
    int d0 = dp * 32;
    // stage K window hi/lo: wave w rows w*32..w*32+31 (2 instrs of 16 rows)
#pragma unroll
    for (int ii = 0; ii < 2; ++ii) {
      int row = wave * 32 + ii * 16 + (lane >> 2);
      int pp = g * GS + row;
      int src = (pp < n_l) ? pp : (2 * n_l - 1 - pp);
      const u16* gH = khbase + (size_t)src * DIMC + d0 + (lane & 3) * 8;
      const u16* gL = klbase + (size_t)src * DIMC + d0 + (lane & 3) * 8;
      __builtin_amdgcn_global_load_lds(
          (const __attribute__((address_space(1))) void*)gH,
          (__attribute__((address_space(3))) void*)&Khi_s[(wave * 32 + ii * 16) * 32],
          16, 0, 0);
      __builtin_amdgcn_global_load_lds(
          (const __attribute__((address_space(1))) void*)gL,
          (__attribute__((address_space(3))) void*)&Klo_s[(wave * 32 + ii * 16) * 32],
          16, 0, 0);
    }
    // stage Q hi (waves 0..3) / lo (waves 4..7): 16 rows per instr
    if (wave < 4) {
      int row = wave * 16 + (lane >> 2);
      const u16* gH = qhbase + (size_t)row * DIMC + d0 + (lane & 3) * 8;
      __builtin_amdgcn_global_load_lds(
          (const __attribute__((address_space(1))) void*)gH,
          (__attribute__((address_space(3))) void*)&Qhi_s[(wave * 16) * 32],
          16, 0, 0);
    } else {
      int row = (wave - 4) * 16 + (lane >> 2);
      const u16* gL = qlbase + (size_t)row * DIMC + d0 + (lane & 3) * 8;
      __builtin_amdgcn_global_load_lds(
          (const __attribute__((address_space(1))) void*)gL,
          (__attribute__((address_space(3))) void*)&Qlo_s[((wave - 4) * 16) * 32],
          16, 0, 0);
    }
    __syncthreads();

    int fr = lane & 15;
    int kf = (lane >> 4) * 8;
    bf16x8 bqh = *reinterpret_cast<const bf16x8*>(&Qhi_s[(qt * 16 + fr) * 32 + kf]);
    bf16x8 bql = *reinterpret_cast<const bf16x8*>(&Qlo_s[(qt * 16 + fr) * 32 + kf]);
#pragma unroll
    for (int kt = 0; kt < 8; ++kt) {
      bf16x8 akh = *reinterpret_cast<const bf16x8*>(&Khi_s[((ktb + kt) * 16 + fr) * 32 + kf]);
      bf16x8 akl = *reinterpret_cast<const bf16x8*>(&Klo_s[((ktb + kt) * 16 + fr) * 32 + kf]);
      acc[kt] = __builtin_amdgcn_mfma_f32_16x16x32_bf16(akh, bqh, acc[kt], 0, 0, 0);
      acc[kt] = __builtin_amdgcn_mfma_f32_16x16x32_bf16(akh, bql, acc[kt], 0, 0, 0);
      acc[kt] = __builtin_amdgcn_mfma_f32_16x16x32_bf16(akl, bqh, acc[kt], 0, 0, 0);
    }
  }
  __syncthreads();   // staging LDS dead; S_lds may overwrite

  int kp = keepArr[b * ng + g];
  float beta = 0.f, wgt = 0.f;
  int plo_ = 0, phi_ = 0;
  if (lvl > 0) {
    beta = 1.f / (1.f + expf(-betaL[lvl]));
    float pos = ((float)g + 0.5f) * ((float)prev_ng / (float)ng) - 0.5f;
    float fl = floorf(pos);
    plo_ = (int)fl;
    if (plo_ < 0) plo_ = 0;
    if (plo_ > prev_ng - 1) plo_ = prev_ng - 1;
    phi_ = plo_ + 1; if (phi_ > prev_ng - 1) phi_ = prev_ng - 1;
    wgt = fminf(fmaxf(pos - fl, 0.f), 1.f);
  }
  u64 lmask = (1ull << lane) - 1ull;

  // ---- S halves -> ballot top-k -> softmax -> prior; retain packed bf16 ----
  unsigned atp[8][2];
#pragma unroll
  for (int half = 0; half < 2; ++half) {
    // S-write: waves 0..3 for half 0 (q 0..31), waves 4..7 for half 1
    if ((wave >> 2) == half) {
      int ql = ((wave >> 1) & 1) * 16 + (lane & 15);   // q-local within half
#pragma unroll
      for (int kt = 0; kt < 8; ++kt) {
        int key = (ktb + kt) * 16 + (lane >> 4) * 4;
        *reinterpret_cast<f32x4*>(&S_lds[ql * 264 + key]) = acc[kt];
      }
    }
    __syncthreads();
#pragma unroll
    for (int j = 0; j < 4; ++j) {
      int lrow = wave * 4 + j;            // 0..31 within half
      int i = p * 64 + half * 32 + lrow;  // row within 128-row group
      f32x4 s4 = *reinterpret_cast<const f32x4*>(&S_lds[lrow * 264 + lane * 4]);
      float sv[4];
      unsigned um[4];
#pragma unroll
      for (int e = 0; e < 4; ++e) {
        sv[e] = s4[e] * 0.125f;
        unsigned u = __float_as_uint(sv[e]);
        um[e] = (u & 0x80000000u) ? ~u : (u | 0x80000000u);
      }
      unsigned T = 0u;
      for (int bit = 31; bit >= 0; --bit) {
        unsigned T2 = T | (1u << bit);
        int c = __popcll(__ballot(um[0] >= T2)) + __popcll(__ballot(um[1] >= T2))
              + __popcll(__ballot(um[2] >= T2)) + __popcll(__ballot(um[3] >= T2));
        if (c >= kp) { T = T2; if (c == kp) break; }
      }
      int c_gt = __popcll(__ballot(um[0] > T)) + __popcll(__ballot(um[1] > T))
               + __popcll(__ballot(um[2] > T)) + __popcll(__ballot(um[3] > T));
      u64 beq[4];
#pragma unroll
      for (int e = 0; e < 4; ++e) beq[e] = __ballot(um[e] == T);
      int trbase = __popcll(beq[0] & lmask) + __popcll(beq[1] & lmask)
                 + __popcll(beq[2] & lmask) + __popcll(beq[3] & lmask);
      int need = kp - c_gt;
      bool msk[4];
      int own = 0;
#pragma unroll
      for (int e = 0; e < 4; ++e) {
        bool eq = (um[e] == T);
        msk[e] = (um[e] > T) || (eq && (trbase + own) < need);
        own += eq ? 1 : 0;
      }
      float m = -3.0e38f;
#pragma unroll
      for (int e = 0; e < 4; ++e) if (msk[e]) m = fmaxf(m, sv[e]);
      m = wave_max64(m);
      float ez[4], zs = 0.f;
#pragma unroll
      for (int e = 0; e < 4; ++e) { ez[e] = msk[e] ? __expf(sv[e] - m) : 0.f; zs += ez[e]; }
      zs = wave_sum64(zs);
      float at[4];
#pragma unroll
      for (int e = 0; e < 4; ++e) at[e] = ez[e] / zs;
      if (lvl > 0) {
        size_t baseLo = ((((size_t)b * prev_ng + plo_) * 8 + h) * GS + i) * WIN + lane * 4;
        size_t baseHi = ((((size_t)b * prev_ng + phi_) * 8 + h) * GS + i) * WIN + lane * 4;
        uint2 rlo = *reinterpret_cast<const uint2*>(prevA + baseLo);
        uint2 rhi = *reinterpret_cast<const uint2*>(prevA + baseHi);
        float pl[4] = { b2f_lo(rlo.x), b2f_hi(rlo.x), b2f_lo(rlo.y), b2f_hi(rlo.y) };
        float ph[4] = { b2f_lo(rhi.x), b2f_hi(rhi.x), b2f_lo(rhi.y), b2f_hi(rhi.y) };
        float pr[4], ps = 0.f;
#pragma unroll
        for (int e = 0; e < 4; ++e) {
          pr[e] = fmaxf((1.f - wgt) * pl[e] + wgt * ph[e], 0.f);
          ps += pr[e];
        }
        ps = wave_sum64(ps) + 1e-9f;
#pragma unroll
        for (int e = 0; e < 4; ++e) at[e] = (1.f - beta) * at[e] + beta * (pr[e] / ps);
      }
      atp[half * 4 + j][0] = (unsigned)f2b(at[0]) | ((unsigned)f2b(at[1]) << 16);
      atp[half * 4 + j][1] = (unsigned)f2b(at[2]) | ((unsigned)f2b(at[3]) << 16);
      if (curA != nullptr) {
        uint2 o = { atp[half * 4 + j][0], atp[half * 4 + j][1] };
        *reinterpret_cast<uint2*>(curA + ((size_t)bgh * GS + i) * WIN + lane * 4) = o;
      }
    }
    __syncthreads();   // S half consumed before next half's write / P_lds
  }

  // ---- PV via MFMA: O(64x64) = P(64x256) @ V(256x64) ----
#pragma unroll
  for (int j = 0; j < 4; ++j) {
    uint2 oA = { atp[j][0], atp[j][1] };
    uint2 oB = { atp[4 + j][0], atp[4 + j][1] };
    *reinterpret_cast<uint2*>(&P_lds[(wave * 4 + j) * 264 + lane * 4]) = oA;
    *reinterpret_cast<uint2*>(&P_lds[(32 + wave * 4 + j) * 264 + lane * 4]) = oB;
  }

  const u16* vbase = vbf + (size_t)b * n_l * DIMC + h * DV;
  int rf   = wave >> 1;                  // q-row frag 0..3
  int cf0  = (wave & 1) * 2;             // dv col frag base {0,2}
  int frow = lane & 15;
  int fk   = (lane >> 4) * 8;
  f32x4 oacc0 = { 0.f, 0.f, 0.f, 0.f };
  f32x4 oacc1 = { 0.f, 0.f, 0.f, 0.f };
  int jlo = t & 15, vd4 = (t >> 4) & 15, jh2 = t >> 8;

#pragma unroll
  for (int jp = 0; jp < 2; ++jp) {
#pragma unroll
    for (int it = 0; it < 4; ++it) {
      int j = (jh2 * 4 + it) * 16 + jlo;           // 0..127
      int pp = g * GS + jp * 128 + j;
      int src = (pp < n_l) ? pp : (2 * n_l - 1 - pp);
      ushort4 vv = *reinterpret_cast<const ushort4*>(vbase + (size_t)src * DIMC + vd4 * 4);
      Vt[(vd4 * 4 + 0) * 136 + j] = vv.x;
      Vt[(vd4 * 4 + 1) * 136 + j] = vv.y;
      Vt[(vd4 * 4 + 2) * 136 + j] = vv.z;
      Vt[(vd4 * 4 + 3) * 136 + j] = vv.w;
    }
    __syncthreads();
    int kb2 = jp * 128;
#pragma unroll
    for (int ks = 0; ks < 4; ++ks) {
      bf16x8 a  = *reinterpret_cast<const bf16x8*>(&P_lds[(rf * 16 + frow) * 264 + kb2 + ks * 32 + fk]);
      bf16x8 b0 = *reinterpret_cast<const bf16x8*>(&Vt[(cf0 * 16 + frow) * 136 + ks * 32 + fk]);
      bf16x8 b1 = *reinterpret_cast<const bf16x8*>(&Vt[((cf0 + 1) * 16 + frow) * 136 + ks * 32 + fk]);
      oacc0 = __builtin_amdgcn_mfma_f32_16x16x32_bf16(a, b0, oacc0, 0, 0, 0);
      oacc1 = __builtin_amdgcn_mfma_f32_16x16x32_bf16(a, b1, oacc1, 0, 0, 0);
    }
    __syncthreads();
  }

  u16* obase = outp + ((size_t)b * n_l + (size_t)g * GS + p * 64 + rf * 16) * DIMC + h * DV;
#pragma unroll
  for (int rr = 0; rr < 4; ++rr) {
    int qrow = (lane >> 4) * 4 + rr;
    obase[(size_t)qrow * DIMC + cf0 * 16 + frow]       = f2b(oacc0[rr]);
    obase[(size_t)qrow * DIMC + (cf0 + 1) * 16 + frow] = f2b(oacc1[rr]);
  }
}

// ---------------------------------------------------------------------------
extern "C" void kernel_launch(void* const* d_in, const int* in_sizes, int n_in,
                              void* d_out, int out_size, void* d_ws, size_t ws_size,
                              hipStream_t stream) {
  (void)in_sizes; (void)n_in; (void)out_size; (void)ws_size;
  const float* x        = (const float*)d_in[0];
  const int*   labels   = (const int*)d_in[1];
  const float* scores   = (const float*)d_in[2];
  const int*   idx_last = (const int*)d_in[3];
  const float* Wq       = (const float*)d_in[4];
  const float* Wk       = (const float*)d_in[5];
  const float* Wv       = (const float*)d_in[6];
  const float* Wp       = (const float*)d_in[7];
  const float* betaL    = (const float*)d_in[8];
  float* out = (float*)d_out;

  char* w = (char*)d_ws;
  size_t off = 0;
  auto take = [&](size_t bytes) -> char* {
    char* p = w + off;
    off += (bytes + 255) & ~(size_t)255;
    return p;
  };
  u16*   qhib   = (u16*)  take(16777216);   // q hi bf16 (max 16384x512)
  u16*   qlob   = (u16*)  take(16777216);   // q lo
  u16*   khib   = (u16*)  take(16777216);   // k hi
  u16*   klob   = (u16*)  take(16777216);   // k lo
  u16*   vbf    = (u16*)  take(16777216);   // v bf16
  u16*   xhi    = (u16*)  take(16777216);   // A hi / attn-out (disjoint lifetimes)
  u16*   xlo    = (u16*)  take(16777216);   // A lo
  u16*   attnA  = (u16*)  take(16777216);   // lvl0 attn bf16
  u16*   attnB  = (u16*)  take(33554432);   // lvl1 attn bf16
  u16*   whiAll = (u16*)  take(6291456);    // 12 x [512][512] bf16 hi
  u16*   wloAll = (u16*)  take(3145728);    // 6  x [512][512] bf16 lo (q,k)
  float* sl     = (float*)take(32768);
  int*   ll     = (int*)  take(32768);
  int*   keepb  = (int*)  take(1024);
  // total ~178 MB

  // all 12 weight transposes+splits, once
  wprep_kernel<<<3072, 256, 0, stream>>>(Wq, Wk, Wv, Wp, whiAll, wloAll);

  for (int lvl = 0; lvl < 3; ++lvl) {
    int scale = (lvl == 0) ? 4 : (lvl == 1) ? 2 : 1;
    int n_l = NTOK / scale;
    int ng  = n_l / GS;
    int M   = 2 * n_l;
    const int* lin; const float* sin_;
    if (scale > 1) {
      int tfeat = 2 * n_l * (DIMC / 4);
      pool_split_kernel<<<(tfeat + 255) / 256, 256, 0, stream>>>(x, scores, xhi, xlo, sl, NTOK, scale);
      pool_label_kernel<<<(2 * n_l + 255) / 256, 256, 0, stream>>>(labels, scores, ll, NTOK, scale);
      lin = ll; sin_ = sl;
    } else {
      asplit_kernel<<<(2 * NTOK * 128) / 256, 256, 0, stream>>>(x, xhi, xlo);
      lin = labels; sin_ = scores;
    }
    keep_kernel<<<(2 * ng + 127) / 128, 128, 0, stream>>>(lin, sin_, keepb, 2 * ng);

    dim3 gq(12, M / 128);
    qkv_gemm_kernel<<<gq, 256, 0, stream>>>(xhi, xlo, whiAll, wloAll,
                                            qhib, qlob, khib, klob, vbf, M, lvl);

    const u16* prev = (lvl == 0) ? nullptr : ((lvl == 1) ? attnA : attnB);
    u16* cur = (lvl == 0) ? attnA : ((lvl == 1) ? attnB : nullptr);
    // attn output reuses xhi (A-side dead after qkv gemm)
    attn_fused_kernel<<<2 * ng * 8 * 2, 512, 0, stream>>>(qhib, qlob, khib, klob,
                                                          vbf, keepb, prev, cur,
                                                          betaL, xhi, lvl, n_l, ng, ng / 2);

    dim3 gp(4, M / 128);
    const u16* wphi = whiAll + (size_t)(9 + lvl) * WSZ;
    if (lvl == 0)
      wp_gemm_kernel<2><<<gp, 256, 0, stream>>>(xhi, wphi, out, idx_last, M, scale, n_l);
    else
      wp_gemm_kernel<3><<<gp, 256, 0, stream>>>(xhi, wphi, out, idx_last, M, scale, n_l);
  }
}

// Round 12
// 557.421 us; speedup vs baseline: 2.4639x; 1.0394x over previous
//
#include <hip/hip_runtime.h>
#include <math.h>

// ---------------------------------------------------------------------------
// LowToHighMultiLevelReconstruction — round 12.
// Changes vs round 11 (attention only):
//  1. LDS 51200 -> 40960 B => 4 blocks/CU (2048 thr = CU max). PV keeps only
//     the active j-half of P in LDS (P_half[64][136], written per-phase from
//     retained atp regs by the owning lanes).
//  2. Unmasked row max == masked max (top element always kept) computed
//     BEFORE the ballot loop — breaks the mask->max dependency (ILP).
//  3. Prior re-normalization reduction skipped (prior rows stored normalized;
//     ps=1 error ~1e-6). GEMMs / layouts otherwise unchanged.
// ---------------------------------------------------------------------------

#define GS   128
#define WIN  256        // 2*GS
#define DQK  64
#define DV   64
#define DIMC 512
#define NTOK 8192
#define WSZ  262144     // 512*512 elements per weight matrix

typedef unsigned long long u64;
typedef unsigned short u16;
typedef __attribute__((ext_vector_type(8))) short bf16x8;
typedef __attribute__((ext_vector_type(4))) float f32x4;

__device__ __forceinline__ u16 f2b(float f) {     // f32 -> bf16 RNE
  unsigned u = __float_as_uint(f);
  u = (u + 0x7fffu + ((u >> 16) & 1u)) >> 16;
  return (u16)u;
}
__device__ __forceinline__ float b2f(u16 h) { return __uint_as_float(((unsigned)h) << 16); }
__device__ __forceinline__ float b2f_lo(unsigned u) { return __uint_as_float(u << 16); }
__device__ __forceinline__ float b2f_hi(unsigned u) { return __uint_as_float(u & 0xffff0000u); }

__device__ __forceinline__ float wave_max64(float v) {
#pragma unroll
  for (int m = 1; m < 64; m <<= 1) v = fmaxf(v, __shfl_xor(v, m, 64));
  return v;
}
__device__ __forceinline__ float wave_sum64(float v) {
#pragma unroll
  for (int m = 1; m < 64; m <<= 1) v += __shfl_xor(v, m, 64);
  return v;
}

// --------------------------------------------- pooling (writes split bf16) --
__global__ void pool_split_kernel(const float* __restrict__ x,
                                  const float* __restrict__ scores,
                                  u16* __restrict__ xhi, u16* __restrict__ xlo,
                                  float* __restrict__ sl, int n, int scale) {
  int npool = n / scale;
  int total = 2 * npool * (DIMC / 4);
  int tid = blockIdx.x * blockDim.x + threadIdx.x;
  if (tid >= total) return;
  int c4 = tid & 127;
  int g  = (tid >> 7) % npool;
  int b  = (tid >> 7) / npool;
  const float* xp = x + ((size_t)b * n + (size_t)g * scale) * DIMC + c4 * 4;
  float ax = 0.f, ay = 0.f, az = 0.f, aw = 0.f, wsum = 0.f, ssum = 0.f;
  for (int s = 0; s < scale; ++s) {
    float sc = scores[(size_t)b * n + (size_t)g * scale + s];
    float w  = fmaxf(sc, 1e-6f);
    float4 xv = *reinterpret_cast<const float4*>(xp + (size_t)s * DIMC);
    ax += xv.x * w; ay += xv.y * w; az += xv.z * w; aw += xv.w * w;
    wsum += w; ssum += sc;
  }
  float o[4] = { ax / wsum, ay / wsum, az / wsum, aw / wsum };
  ushort4 h, l;
  h.x = f2b(o[0]); h.y = f2b(o[1]); h.z = f2b(o[2]); h.w = f2b(o[3]);
  l.x = f2b(o[0] - b2f(h.x)); l.y = f2b(o[1] - b2f(h.y));
  l.z = f2b(o[2] - b2f(h.z)); l.w = f2b(o[3] - b2f(h.w));
  size_t off = ((size_t)b * npool + g) * DIMC + c4 * 4;
  *reinterpret_cast<ushort4*>(xhi + off) = h;
  *reinterpret_cast<ushort4*>(xlo + off) = l;
  if (c4 == 0) sl[(size_t)b * npool + g] = ssum / (float)scale;
}

// --------------------------------------------------- raw x split (lvl 2) ----
__global__ void asplit_kernel(const float* __restrict__ x,
                              u16* __restrict__ xhi, u16* __restrict__ xlo) {
  int tid = blockIdx.x * 256 + threadIdx.x;     // over 2*NTOK*128 float4s
  float4 v = *reinterpret_cast<const float4*>(x + (size_t)tid * 4);
  ushort4 h, l;
  h.x = f2b(v.x); h.y = f2b(v.y); h.z = f2b(v.z); h.w = f2b(v.w);
  l.x = f2b(v.x - b2f(h.x)); l.y = f2b(v.y - b2f(h.y));
  l.z = f2b(v.z - b2f(h.z)); l.w = f2b(v.w - b2f(h.w));
  *reinterpret_cast<ushort4*>(xhi + (size_t)tid * 4) = h;
  *reinterpret_cast<ushort4*>(xlo + (size_t)tid * 4) = l;
}

__global__ void pool_label_kernel(const int* __restrict__ labels,
                                  const float* __restrict__ scores,
                                  int* __restrict__ ll, int n, int scale) {
  int npool = n / scale;
  int tid = blockIdx.x * blockDim.x + threadIdx.x;
  if (tid >= 2 * npool) return;
  int b = tid / npool, g = tid % npool;
  float counts[4] = {0.f, 0.f, 0.f, 0.f};
  float ssum[4]   = {0.f, 0.f, 0.f, 0.f};
  int firstp[4];
  for (int c = 0; c < 4; ++c) firstp[c] = scale;
  for (int s = 0; s < scale; ++s) {
    int   L = labels[(size_t)b * n + (size_t)g * scale + s];
    float S = scores[(size_t)b * n + (size_t)g * scale + s];
    counts[L] += 1.0f;
    ssum[L]   += S;
    if (s < firstp[L]) firstp[L] = s;
  }
  float cmax = fmaxf(fmaxf(counts[0], counts[1]), fmaxf(counts[2], counts[3]));
  float s2[4];
  for (int c = 0; c < 4; ++c) s2[c] = (counts[c] == cmax) ? ssum[c] : -1e9f;
  float smax = fmaxf(fmaxf(s2[0], s2[1]), fmaxf(s2[2], s2[3]));
  int fp[4];
  for (int c = 0; c < 4; ++c) fp[c] = (s2[c] == smax) ? firstp[c] : scale;
  int best = 0, bv = fp[0];
  for (int c = 1; c < 4; ++c) if (fp[c] < bv) { bv = fp[c]; best = c; }
  ll[(size_t)b * npool + g] = best;
}

// ------------------------------------------------------------ keep (focus) --
__global__ void keep_kernel(const int* __restrict__ ll, const float* __restrict__ sl,
                            int* __restrict__ keep, int total) {
  int tid = blockIdx.x * blockDim.x + threadIdx.x;
  if (tid >= total) return;
  const int*   lp = ll + (size_t)tid * GS;
  const float* sp = sl + (size_t)tid * GS;
  float counts[4] = {0.f, 0.f, 0.f, 0.f};
  for (int i = 0; i < GS; ++i) counts[lp[i]] += 1.f;
  int mode = 0; float bv = counts[0];
  for (int c = 1; c < 4; ++c) if (counts[c] > bv) { bv = counts[c]; mode = c; }
  float pm = 0.f, mean = 0.f;
  for (int i = 0; i < GS; ++i) { pm += (lp[i] == mode) ? 1.f : 0.f; mean += sp[i]; }
  float purity = pm / (float)GS;
  mean /= (float)GS;
  float var = 0.f;
  for (int i = 0; i < GS; ++i) { float d = sp[i] - mean; var += d * d; }
  var /= (float)GS;
  float focus = 0.5f + 0.25f * purity - 0.25f * var;
  focus = fminf(fmaxf(focus, 0.25f), 0.75f);
  keep[tid] = (int)ceilf(focus * (float)WIN);
}

// --------------------- ALL weight transpose+split in one launch (12 mats) ---
__global__ __launch_bounds__(256) void wprep_kernel(
    const float* __restrict__ Wq, const float* __restrict__ Wk,
    const float* __restrict__ Wv, const float* __restrict__ Wp,
    u16* __restrict__ whiAll, u16* __restrict__ wloAll) {
  __shared__ float tile[32][33];
  int blk = blockIdx.x;            // 0..3071
  int mat = blk >> 8;              // 0..11
  int sub = blk & 255;
  int kind = mat / 3, lvl = mat % 3;
  const float* W = (kind == 0 ? Wq : kind == 1 ? Wk : kind == 2 ? Wv : Wp)
                   + (size_t)lvl * WSZ;
  u16* bthi = whiAll + (size_t)mat * WSZ;
  u16* btlo = (mat < 6) ? (wloAll + (size_t)mat * WSZ) : nullptr;

  int bx = sub & 15;               // n block
  int by = sub >> 4;               // k block
  int tx = threadIdx.x & 31;
  int ty = threadIdx.x >> 5;       // 0..7
#pragma unroll
  for (int i = 0; i < 4; ++i) {
    int kk = ty + i * 8;
    tile[kk][tx] = W[(size_t)(by * 32 + kk) * 512 + bx * 32 + tx];
  }
  __syncthreads();
#pragma unroll
  for (int i = 0; i < 4; ++i) {
    int nn = ty + i * 8;
    float v = tile[tx][nn];        // = W[by*32+tx][bx*32+nn]
    u16 h = f2b(v);
    size_t o = (size_t)(bx * 32 + nn) * 512 + by * 32 + tx;
    bthi[o] = h;
    if (btlo) btlo[o] = f2b(v - b2f(h));
  }
}

// ---------------------------------------------------- fused q/k/v GEMM ------
// grid (12, M/128): sel=blockIdx.x>>2 (0=q split, 1=k split, 2=v hi-only).
// q,k emitted as pre-split bf16 hi/lo; v as bf16 hi.
__global__ __launch_bounds__(256) void qkv_gemm_kernel(
    const u16* __restrict__ Ahi, const u16* __restrict__ Alo,
    const u16* __restrict__ whiAll, const u16* __restrict__ wloAll,
    u16* __restrict__ qhi, u16* __restrict__ qlo,
    u16* __restrict__ khi, u16* __restrict__ klo, u16* __restrict__ vbf,
    int M, int lvl) {
  __shared__ u16 smem[4 * 4096];
  u16* sAhi = smem;
  u16* sBhi = smem + 4096;
  u16* sAlo = smem + 2 * 4096;
  u16* sBlo = smem + 3 * 4096;

  int sel = blockIdx.x >> 2;       // 0=q, 1=k, 2=v
  int cx  = blockIdx.x & 3;
  bool split = (sel < 2);
  const u16* Bh = whiAll + (size_t)(sel * 3 + lvl) * WSZ;
  const u16* Bl = wloAll + (size_t)(sel * 3 + lvl) * WSZ;   // valid only sel<2

  int t = threadIdx.x, lane = t & 63, wave = t >> 6;
  int wr = wave >> 1, wc = wave & 1;
  int row0 = blockIdx.y * 128, col0 = cx * 128;

  int srow = (lane >> 2);
  int schk = (lane & 3) * 8;

  const f32x4 zero = { 0.f, 0.f, 0.f, 0.f };
  f32x4 acc[4][4];
#pragma unroll
  for (int i = 0; i < 4; ++i)
#pragma unroll
    for (int j = 0; j < 4; ++j) acc[i][j] = zero;

  for (int k0 = 0; k0 < 512; k0 += 32) {
#pragma unroll
    for (int j = 0; j < 2; ++j) {
      int r = wave * 32 + j * 16 + srow;
      const u16* gA = Ahi + (size_t)(row0 + r) * 512 + k0 + schk;
      const u16* gB = Bh + (size_t)(col0 + r) * 512 + k0 + schk;
      __builtin_amdgcn_global_load_lds(
          (const __attribute__((address_space(1))) void*)gA,
          (__attribute__((address_space(3))) void*)&sAhi[(wave * 32 + j * 16) * 32],
          16, 0, 0);
      __builtin_amdgcn_global_load_lds(
          (const __attribute__((address_space(1))) void*)gB,
          (__attribute__((address_space(3))) void*)&sBhi[(wave * 32 + j * 16) * 32],
          16, 0, 0);
      if (split) {
        const u16* gAl = Alo + (size_t)(row0 + r) * 512 + k0 + schk;
        const u16* gBl = Bl + (size_t)(col0 + r) * 512 + k0 + schk;
        __builtin_amdgcn_global_load_lds(
            (const __attribute__((address_space(1))) void*)gAl,
            (__attribute__((address_space(3))) void*)&sAlo[(wave * 32 + j * 16) * 32],
            16, 0, 0);
        __builtin_amdgcn_global_load_lds(
            (const __attribute__((address_space(1))) void*)gBl,
            (__attribute__((address_space(3))) void*)&sBlo[(wave * 32 + j * 16) * 32],
            16, 0, 0);
      }
    }
    __syncthreads();

    int fr = lane & 15;
    int kf = (lane >> 4) * 8;
    bf16x8 ah[4], bh[4], al[4], bl[4];
#pragma unroll
    for (int i = 0; i < 4; ++i) {
      ah[i] = *reinterpret_cast<const bf16x8*>(&sAhi[(wr * 64 + i * 16 + fr) * 32 + kf]);
      bh[i] = *reinterpret_cast<const bf16x8*>(&sBhi[(wc * 64 + i * 16 + fr) * 32 + kf]);
      if (split) {
        al[i] = *reinterpret_cast<const bf16x8*>(&sAlo[(wr * 64 + i * 16 + fr) * 32 + kf]);
        bl[i] = *reinterpret_cast<const bf16x8*>(&sBlo[(wc * 64 + i * 16 + fr) * 32 + kf]);
      }
    }
#pragma unroll
    for (int i = 0; i < 4; ++i)
#pragma unroll
      for (int j = 0; j < 4; ++j) {
        acc[i][j] = __builtin_amdgcn_mfma_f32_16x16x32_bf16(ah[i], bh[j], acc[i][j], 0, 0, 0);
        if (split) {
          acc[i][j] = __builtin_amdgcn_mfma_f32_16x16x32_bf16(ah[i], bl[j], acc[i][j], 0, 0, 0);
          acc[i][j] = __builtin_amdgcn_mfma_f32_16x16x32_bf16(al[i], bh[j], acc[i][j], 0, 0, 0);
        }
      }
    __syncthreads();
  }

  int ccol = col0 + wc * 64 + (lane & 15);
  int crow = row0 + wr * 64 + (lane >> 4) * 4;
  if (sel == 2) {
#pragma unroll
    for (int i = 0; i < 4; ++i)
#pragma unroll
      for (int r = 0; r < 4; ++r) {
        int gr = crow + i * 16 + r;
#pragma unroll
        for (int j = 0; j < 4; ++j)
          vbf[(size_t)gr * 512 + ccol + j * 16] = f2b(acc[i][j][r]);
      }
  } else {
    u16* Ch = (sel == 0) ? qhi : khi;
    u16* Cl = (sel == 0) ? qlo : klo;
#pragma unroll
    for (int i = 0; i < 4; ++i)
#pragma unroll
      for (int r = 0; r < 4; ++r) {
        int gr = crow + i * 16 + r;
#pragma unroll
        for (int j = 0; j < 4; ++j) {
          float v = acc[i][j][r];
          u16 hh = f2b(v);
          Ch[(size_t)gr * 512 + ccol + j * 16] = hh;
          Cl[(size_t)gr * 512 + ccol + j * 16] = f2b(v - b2f(hh));
        }
      }
  }
}

// --------------------------------------------------- Wp GEMM (scatter) ------
template<int EMODE>
__global__ __launch_bounds__(256) void wp_gemm_kernel(
    const u16* __restrict__ Ahi, const u16* __restrict__ Bthi,
    float* __restrict__ C, const int* __restrict__ idx,
    int M, int scale, int n_l) {
  __shared__ u16 smem[2 * 4096];
  u16* sAhi = smem;
  u16* sBhi = smem + 4096;

  int t = threadIdx.x, lane = t & 63, wave = t >> 6;
  int wr = wave >> 1, wc = wave & 1;
  int row0 = blockIdx.y * 128, col0 = blockIdx.x * 128;

  int srow = (lane >> 2);
  int schk = (lane & 3) * 8;

  const f32x4 zero = { 0.f, 0.f, 0.f, 0.f };
  f32x4 acc[4][4];
#pragma unroll
  for (int i = 0; i < 4; ++i)
#pragma unroll
    for (int j = 0; j < 4; ++j) acc[i][j] = zero;

  for (int k0 = 0; k0 < 512; k0 += 32) {
#pragma unroll
    for (int j = 0; j < 2; ++j) {
      int r = wave * 32 + j * 16 + srow;
      const u16* gA = Ahi + (size_t)(row0 + r) * 512 + k0 + schk;
      const u16* gB = Bthi + (size_t)(col0 + r) * 512 + k0 + schk;
      __builtin_amdgcn_global_load_lds(
          (const __attribute__((address_space(1))) void*)gA,
          (__attribute__((address_space(3))) void*)&sAhi[(wave * 32 + j * 16) * 32],
          16, 0, 0);
      __builtin_amdgcn_global_load_lds(
          (const __attribute__((address_space(1))) void*)gB,
          (__attribute__((address_space(3))) void*)&sBhi[(wave * 32 + j * 16) * 32],
          16, 0, 0);
    }
    __syncthreads();

    int fr = lane & 15;
    int kf = (lane >> 4) * 8;
    bf16x8 ah[4], bh[4];
#pragma unroll
    for (int i = 0; i < 4; ++i) {
      ah[i] = *reinterpret_cast<const bf16x8*>(&sAhi[(wr * 64 + i * 16 + fr) * 32 + kf]);
      bh[i] = *reinterpret_cast<const bf16x8*>(&sBhi[(wc * 64 + i * 16 + fr) * 32 + kf]);
    }
#pragma unroll
    for (int i = 0; i < 4; ++i)
#pragma unroll
      for (int j = 0; j < 4; ++j)
        acc[i][j] = __builtin_amdgcn_mfma_f32_16x16x32_bf16(ah[i], bh[j], acc[i][j], 0, 0, 0);
    __syncthreads();
  }

  int ccol = col0 + wc * 64 + (lane & 15);
  int crow = row0 + wr * 64 + (lane >> 4) * 4;
#pragma unroll
  for (int i = 0; i < 4; ++i) {
#pragma unroll
    for (int r = 0; r < 4; ++r) {
      int gr = crow + i * 16 + r;
      int bb = gr / n_l, rr = gr - bb * n_l;
      for (int s = 0; s < scale; ++s) {
        int dst = idx[(size_t)bb * NTOK + (size_t)rr * scale + s];
        float* p = C + ((size_t)bb * NTOK + dst) * 512 + ccol;
        if (EMODE == 3) {
#pragma unroll
          for (int j = 0; j < 4; ++j) p[j * 16] += acc[i][j][r];
        } else {
#pragma unroll
          for (int j = 0; j < 4; ++j) p[j * 16] = acc[i][j][r];
        }
      }
    }
  }
}

// ----------------------------------------------- fused windowed attention ---
// TWO blocks (512 thr, 8 waves) per (b,g,h), each owns 64 q-rows (p=bid&1).
// LDS 40960 B -> 4 blocks/CU (2048 thr = CU max).
// Phase A: sim via split-bf16 MFMA (K/Q hi/lo staged per d-half).
// S -> LDS f32 [32][264] in two q-halves -> ballot top-k (early exit) ->
// softmax (unmasked max == masked max, computed early for ILP) -> prior mix
// (prior rows pre-normalized; re-normalizing reduction skipped, err ~1e-6).
// Phase B: PV via MFMA with per-j-half P (P_half[64][136]) + Vt[64][136].
__global__ __launch_bounds__(512) void attn_fused_kernel(
    const u16* __restrict__ qhi, const u16* __restrict__ qlo,
    const u16* __restrict__ khi, const u16* __restrict__ klo,
    const u16* __restrict__ vbf, const int* __restrict__ keepArr,
    const u16* __restrict__ prevA, u16* __restrict__ curA,
    const float* __restrict__ betaL, u16* __restrict__ outp,
    int lvl, int n_l, int ng, int prev_ng) {
  __shared__ u64 smem8[5120];             // 40960 B
  u16*   Khi_s  = (u16*)smem8;            // [256][32] @0     (phase A stage)
  u16*   Klo_s  = Khi_s + 256 * 32;       // @16384
  u16*   Qhi_s  = Klo_s + 256 * 32;       // [64][32] @32768
  u16*   Qlo_s  = Qhi_s + 64 * 32;        // @36864 (..40960)
  float* S_lds  = (float*)smem8;          // [32][264] f32 @0..33792
  u16*   P_half = (u16*)smem8;            // [64][136] @0..17408   (phase B)
  u16*   Vt     = P_half + 64 * 136;      // [64][136] @17408..34816

  int t = threadIdx.x;
  int lane = t & 63, wave = t >> 6;
  int bid = blockIdx.x;
  int p   = bid & 1;
  int h   = (bid >> 1) & 7;
  int gl  = bid >> 4;
  int g   = gl % ng;
  int b   = gl / ng;
  int bgh = bid >> 1;                     // (b,g,h) index for attn state

  const u16* qhbase = qhi + ((size_t)b * n_l + (size_t)g * GS + p * 64) * DIMC + h * DQK;
  const u16* qlbase = qlo + ((size_t)b * n_l + (size_t)g * GS + p * 64) * DIMC + h * DQK;
  const u16* khbase = khi + (size_t)b * n_l * DIMC + h * DQK;
  const u16* klbase = klo + (size_t)b * n_l * DIMC + h * DQK;

  // ---- phase A: sim via MFMA (3-product split), acc over 2 d-halves ----
  int qt  = wave >> 1;                    // q-tile 0..3
  int ktb = (wave & 1) * 8;               // key-tile base 0 or 8
  f32x4 acc[8];
#pragma unroll
  for (int i = 0; i < 8; ++i) acc[i] = (f32x4){0.f, 0.f, 0.f, 0.f};

#pragma unroll
  for (int dp = 0; dp < 2; ++dp) {
    if (dp) __syncthreads();              // previous half's frags consumed
    int d0 = dp * 32;
#pragma unroll
    for (int ii = 0; ii < 2; ++ii) {
      int row = wave * 32 + ii * 16 + (lane >> 2);
      int pp = g * GS + row;
      int src = (pp < n_l) ? pp : (2 * n_l - 1 - pp);
      const u16* gH = khbase + (size_t)src * DIMC + d0 + (lane & 3) * 8;
      const u16* gL = klbase + (size_t)src * DIMC + d0 + (lane & 3) * 8;
      __builtin_amdgcn_global_load_lds(
          (const __attribute__((address_space(1))) void*)gH,
          (__attribute__((address_space(3))) void*)&Khi_s[(wave * 32 + ii * 16) * 32],
          16, 0, 0);
      __builtin_amdgcn_global_load_lds(
          (const __attribute__((address_space(1))) void*)gL,
          (__attribute__((address_space(3))) void*)&Klo_s[(wave * 32 + ii * 16) * 32],
          16, 0, 0);
    }
    if (wave < 4) {
      int row = wave * 16 + (lane >> 2);
      const u16* gH = qhbase + (size_t)row * DIMC + d0 + (lane & 3) * 8;
      __builtin_amdgcn_global_load_lds(
          (const __attribute__((address_space(1))) void*)gH,
          (__attribute__((address_space(3))) void*)&Qhi_s[(wave * 16) * 32],
          16, 0, 0);
    } else {
      int row = (wave - 4) * 16 + (lane >> 2);
      const u16* gL = qlbase + (size_t)row * DIMC + d0 + (lane & 3) * 8;
      __builtin_amdgcn_global_load_lds(
          (const __attribute__((address_space(1))) void*)gL,
          (__attribute__((address_space(3))) void*)&Qlo_s[((wave - 4) * 16) * 32],
          16, 0, 0);
    }
    __syncthreads();

    int fr = lane & 15;
    int kf = (lane >> 4) * 8;
    bf16x8 bqh = *reinterpret_cast<const bf16x8*>(&Qhi_s[(qt * 16 + fr) * 32 + kf]);
    bf16x8 bql = *reinterpret_cast<const bf16x8*>(&Qlo_s[(qt * 16 + fr) * 32 + kf]);
#pragma unroll
    for (int kt = 0; kt < 8; ++kt) {
      bf16x8 akh = *reinterpret_cast<const bf16x8*>(&Khi_s[((ktb + kt) * 16 + fr) * 32 + kf]);
      bf16x8 akl = *reinterpret_cast<const bf16x8*>(&Klo_s[((ktb + kt) * 16 + fr) * 32 + kf]);
      acc[kt] = __builtin_amdgcn_mfma_f32_16x16x32_bf16(akh, bqh, acc[kt], 0, 0, 0);
      acc[kt] = __builtin_amdgcn_mfma_f32_16x16x32_bf16(akh, bql, acc[kt], 0, 0, 0);
      acc[kt] = __builtin_amdgcn_mfma_f32_16x16x32_bf16(akl, bqh, acc[kt], 0, 0, 0);
    }
  }
  __syncthreads();   // staging LDS dead; S_lds may overwrite

  int kp = keepArr[b * ng + g];
  float beta = 0.f, wgt = 0.f;
  int plo_ = 0, phi_ = 0;
  if (lvl > 0) {
    beta = 1.f / (1.f + expf(-betaL[lvl]));
    float pos = ((float)g + 0.5f) * ((float)prev_ng / (float)ng) - 0.5f;
    float fl = floorf(pos);
    plo_ = (int)fl;
    if (plo_ < 0) plo_ = 0;
    if (plo_ > prev_ng - 1) plo_ = prev_ng - 1;
    phi_ = plo_ + 1; if (phi_ > prev_ng - 1) phi_ = prev_ng - 1;
    wgt = fminf(fmaxf(pos - fl, 0.f), 1.f);
  }
  u64 lmask = (1ull << lane) - 1ull;

  // ---- S halves -> ballot top-k -> softmax -> prior; retain packed bf16 ----
  unsigned atp[8][2];
#pragma unroll
  for (int half = 0; half < 2; ++half) {
    if ((wave >> 2) == half) {
      int ql = ((wave >> 1) & 1) * 16 + (lane & 15);   // q-local within half
#pragma unroll
      for (int kt = 0; kt < 8; ++kt) {
        int key = (ktb + kt) * 16 + (lane >> 4) * 4;
        *reinterpret_cast<f32x4*>(&S_lds[ql * 264 + key]) = acc[kt];
      }
    }
    __syncthreads();
#pragma unroll
    for (int j = 0; j < 4; ++j) {
      int lrow = wave * 4 + j;            // 0..31 within half
      int i = p * 64 + half * 32 + lrow;  // row within 128-row group
      f32x4 s4 = *reinterpret_cast<const f32x4*>(&S_lds[lrow * 264 + lane * 4]);
      float sv[4];
      unsigned um[4];
#pragma unroll
      for (int e = 0; e < 4; ++e) {
        sv[e] = s4[e] * 0.125f;
        unsigned u = __float_as_uint(sv[e]);
        um[e] = (u & 0x80000000u) ? ~u : (u | 0x80000000u);
      }
      // unmasked row max == masked max (top element always kept, kp>=128).
      // Computed BEFORE the ballot chain so its shuffle latency overlaps.
      float m = wave_max64(fmaxf(fmaxf(sv[0], sv[1]), fmaxf(sv[2], sv[3])));
      unsigned T = 0u;
      for (int bit = 31; bit >= 0; --bit) {
        unsigned T2 = T | (1u << bit);
        int c = __popcll(__ballot(um[0] >= T2)) + __popcll(__ballot(um[1] >= T2))
              + __popcll(__ballot(um[2] >= T2)) + __popcll(__ballot(um[3] >= T2));
        if (c >= kp) { T = T2; if (c == kp) break; }
      }
      int c_gt = __popcll(__ballot(um[0] > T)) + __popcll(__ballot(um[1] > T))
               + __popcll(__ballot(um[2] > T)) + __popcll(__ballot(um[3] > T));
      u64 beq[4];
#pragma unroll
      for (int e = 0; e < 4; ++e) beq[e] = __ballot(um[e] == T);
      int trbase = __popcll(beq[0] & lmask) + __popcll(beq[1] & lmask)
                 + __popcll(beq[2] & lmask) + __popcll(beq[3] & lmask);
      int need = kp - c_gt;
      bool msk[4];
      int own = 0;
#pragma unroll
      for (int e = 0; e < 4; ++e) {
        bool eq = (um[e] == T);
        msk[e] = (um[e] > T) || (eq && (trbase + own) < need);
        own += eq ? 1 : 0;
      }
      float ez[4], zs = 0.f;
#pragma unroll
      for (int e = 0; e < 4; ++e) { ez[e] = msk[e] ? __expf(sv[e] - m) : 0.f; zs += ez[e]; }
      zs = wave_sum64(zs);
      float at[4];
#pragma unroll
      for (int e = 0; e < 4; ++e) at[e] = ez[e] / zs;
      if (lvl > 0) {
        size_t baseLo = ((((size_t)b * prev_ng + plo_) * 8 + h) * GS + i) * WIN + lane * 4;
        size_t baseHi = ((((size_t)b * prev_ng + phi_) * 8 + h) * GS + i) * WIN + lane * 4;
        uint2 rlo = *reinterpret_cast<const uint2*>(prevA + baseLo);
        uint2 rhi = *reinterpret_cast<const uint2*>(prevA + baseHi);
        float pl[4] = { b2f_lo(rlo.x), b2f_hi(rlo.x), b2f_lo(rlo.y), b2f_hi(rlo.y) };
        float ph[4] = { b2f_lo(rhi.x), b2f_hi(rhi.x), b2f_lo(rhi.y), b2f_hi(rhi.y) };
        // prior rows are stored normalized (sum = 1 + O(bf16 rounding));
        // skip the re-normalizing wave reduction: |err| ~ beta*pr*5e-4 ~ 1e-6
#pragma unroll
        for (int e = 0; e < 4; ++e) {
          float pr = fmaxf((1.f - wgt) * pl[e] + wgt * ph[e], 0.f);
          at[e] = (1.f - beta) * at[e] + beta * pr;
        }
      }
      atp[half * 4 + j][0] = (unsigned)f2b(at[0]) | ((unsigned)f2b(at[1]) << 16);
      atp[half * 4 + j][1] = (unsigned)f2b(at[2]) | ((unsigned)f2b(at[3]) << 16);
      if (curA != nullptr) {
        uint2 o = { atp[half * 4 + j][0], atp[half * 4 + j][1] };
        *reinterpret_cast<uint2*>(curA + ((size_t)bgh * GS + i) * WIN + lane * 4) = o;
      }
    }
    __syncthreads();   // S half consumed before next half's write / P_half
  }

  // ---- PV via MFMA: O(64x64) = P(64x256) @ V(256x64), per-j-half P ----
  const u16* vbase = vbf + (size_t)b * n_l * DIMC + h * DV;
  int rf   = wave >> 1;                  // q-row frag 0..3
  int cf0  = (wave & 1) * 2;             // dv col frag base {0,2}
  int frow = lane & 15;
  int fk   = (lane >> 4) * 8;
  f32x4 oacc0 = { 0.f, 0.f, 0.f, 0.f };
  f32x4 oacc1 = { 0.f, 0.f, 0.f, 0.f };
  int jlo = t & 15, vd4 = (t >> 4) & 15, jh2 = t >> 8;

#pragma unroll
  for (int jp = 0; jp < 2; ++jp) {
    // stage Vt half (transposed V)
#pragma unroll
    for (int it = 0; it < 4; ++it) {
      int j = (jh2 * 4 + it) * 16 + jlo;           // 0..127
      int pp = g * GS + jp * 128 + j;
      int src = (pp < n_l) ? pp : (2 * n_l - 1 - pp);
      ushort4 vv = *reinterpret_cast<const ushort4*>(vbase + (size_t)src * DIMC + vd4 * 4);
      Vt[(vd4 * 4 + 0) * 136 + j] = vv.x;
      Vt[(vd4 * 4 + 1) * 136 + j] = vv.y;
      Vt[(vd4 * 4 + 2) * 136 + j] = vv.z;
      Vt[(vd4 * 4 + 3) * 136 + j] = vv.w;
    }
    // write this half's P from retained regs (lanes owning these keys)
    if ((lane >> 5) == jp) {
      int kl = (lane & 31) * 4;          // local key base within half
#pragma unroll
      for (int j = 0; j < 4; ++j) {
        uint2 oA = { atp[j][0], atp[j][1] };
        uint2 oB = { atp[4 + j][0], atp[4 + j][1] };
        *reinterpret_cast<uint2*>(&P_half[(wave * 4 + j) * 136 + kl]) = oA;
        *reinterpret_cast<uint2*>(&P_half[(32 + wave * 4 + j) * 136 + kl]) = oB;
      }
    }
    __syncthreads();
#pragma unroll
    for (int ks = 0; ks < 4; ++ks) {
      bf16x8 a  = *reinterpret_cast<const bf16x8*>(&P_half[(rf * 16 + frow) * 136 + ks * 32 + fk]);
      bf16x8 b0 = *reinterpret_cast<const bf16x8*>(&Vt[(cf0 * 16 + frow) * 136 + ks * 32 + fk]);
      bf16x8 b1 = *reinterpret_cast<const bf16x8*>(&Vt[((cf0 + 1) * 16 + frow) * 136 + ks * 32 + fk]);
      oacc0 = __builtin_amdgcn_mfma_f32_16x16x32_bf16(a, b0, oacc0, 0, 0, 0);
      oacc1 = __builtin_amdgcn_mfma_f32_16x16x32_bf16(a, b1, oacc1, 0, 0, 0);
    }
    __syncthreads();
  }

  u16* obase = outp + ((size_t)b * n_l + (size_t)g * GS + p * 64 + rf * 16) * DIMC + h * DV;
#pragma unroll
  for (int rr = 0; rr < 4; ++rr) {
    int qrow = (lane >> 4) * 4 + rr;
    obase[(size_t)qrow * DIMC + cf0 * 16 + frow]       = f2b(oacc0[rr]);
    obase[(size_t)qrow * DIMC + (cf0 + 1) * 16 + frow] = f2b(oacc1[rr]);
  }
}

// ---------------------------------------------------------------------------
extern "C" void kernel_launch(void* const* d_in, const int* in_sizes, int n_in,
                              void* d_out, int out_size, void* d_ws, size_t ws_size,
                              hipStream_t stream) {
  (void)in_sizes; (void)n_in; (void)out_size; (void)ws_size;
  const float* x        = (const float*)d_in[0];
  const int*   labels   = (const int*)d_in[1];
  const float* scores   = (const float*)d_in[2];
  const int*   idx_last = (const int*)d_in[3];
  const float* Wq       = (const float*)d_in[4];
  const float* Wk       = (const float*)d_in[5];
  const float* Wv       = (const float*)d_in[6];
  const float* Wp       = (const float*)d_in[7];
  const float* betaL    = (const float*)d_in[8];
  float* out = (float*)d_out;

  char* w = (char*)d_ws;
  size_t off = 0;
  auto take = [&](size_t bytes) -> char* {
    char* p = w + off;
    off += (bytes + 255) & ~(size_t)255;
    return p;
  };
  u16*   qhib   = (u16*)  take(16777216);   // q hi bf16 (max 16384x512)
  u16*   qlob   = (u16*)  take(16777216);   // q lo
  u16*   khib   = (u16*)  take(16777216);   // k hi
  u16*   klob   = (u16*)  take(16777216);   // k lo
  u16*   vbf    = (u16*)  take(16777216);   // v bf16
  u16*   xhi    = (u16*)  take(16777216);   // A hi / attn-out (disjoint lifetimes)
  u16*   xlo    = (u16*)  take(16777216);   // A lo
  u16*   attnA  = (u16*)  take(16777216);   // lvl0 attn bf16
  u16*   attnB  = (u16*)  take(33554432);   // lvl1 attn bf16
  u16*   whiAll = (u16*)  take(6291456);    // 12 x [512][512] bf16 hi
  u16*   wloAll = (u16*)  take(3145728);    // 6  x [512][512] bf16 lo (q,k)
  float* sl     = (float*)take(32768);
  int*   ll     = (int*)  take(32768);
  int*   keepb  = (int*)  take(1024);
  // total ~178 MB

  // all 12 weight transposes+splits, once
  wprep_kernel<<<3072, 256, 0, stream>>>(Wq, Wk, Wv, Wp, whiAll, wloAll);

  for (int lvl = 0; lvl < 3; ++lvl) {
    int scale = (lvl == 0) ? 4 : (lvl == 1) ? 2 : 1;
    int n_l = NTOK / scale;
    int ng  = n_l / GS;
    int M   = 2 * n_l;
    const int* lin; const float* sin_;
    if (scale > 1) {
      int tfeat = 2 * n_l * (DIMC / 4);
      pool_split_kernel<<<(tfeat + 255) / 256, 256, 0, stream>>>(x, scores, xhi, xlo, sl, NTOK, scale);
      pool_label_kernel<<<(2 * n_l + 255) / 256, 256, 0, stream>>>(labels, scores, ll, NTOK, scale);
      lin = ll; sin_ = sl;
    } else {
      asplit_kernel<<<(2 * NTOK * 128) / 256, 256, 0, stream>>>(x, xhi, xlo);
      lin = labels; sin_ = scores;
    }
    keep_kernel<<<(2 * ng + 127) / 128, 128, 0, stream>>>(lin, sin_, keepb, 2 * ng);

    dim3 gq(12, M / 128);
    qkv_gemm_kernel<<<gq, 256, 0, stream>>>(xhi, xlo, whiAll, wloAll,
                                            qhib, qlob, khib, klob, vbf, M, lvl);

    const u16* prev = (lvl == 0) ? nullptr : ((lvl == 1) ? attnA : attnB);
    u16* cur = (lvl == 0) ? attnA : ((lvl == 1) ? attnB : nullptr);
    // attn output reuses xhi (A-side dead after qkv gemm)
    attn_fused_kernel<<<2 * ng * 8 * 2, 512, 0, stream>>>(qhib, qlob, khib, klob,
                                                          vbf, keepb, prev, cur,
                                                          betaL, xhi, lvl, n_l, ng, ng / 2);

    dim3 gp(4, M / 128);
    const u16* wphi = whiAll + (size_t)(9 + lvl) * WSZ;
    if (lvl == 0)
      wp_gemm_kernel<2><<<gp, 256, 0, stream>>>(xhi, wphi, out, idx_last, M, scale, n_l);
    else
      wp_gemm_kernel<3><<<gp, 256, 0, stream>>>(xhi, wphi, out, idx_last, M, scale, n_l);
  }
}